// Round 7
// baseline (1792.450 us; speedup 1.0000x reference)
//
#include <hip/hip_runtime.h>
#include <cstdint>

typedef float f32x4 __attribute__((ext_vector_type(4)));
typedef unsigned int u32;

constexpr int Lc = 4096, Dc = 64, Mc = 266;
constexpr float NORM = 0.35355339059327373f;   // 64^-0.25
constexpr float EPSc = 1e-4f;

// ---- ALL scratch in d_out (8,388,608 floats). d_ws unused. ----
// partial : [8][32][18720] f32 @ fidx 0..4,792,319   (dead after kc)
// blockmax: 2048 f32 @ fidx 7,785,472 (b=1 rows 3507-3508)
// ctx     : per bh, 18720 f32 stripe-packed in b=1 rows 3511..4095, cols (bh&15)*64..+63
// all scratch rows (b=1, 3456+) are overwritten with true output by ke (last kernel)
constexpr size_t BMAX = 7785472;

__device__ __forceinline__ size_t ctx_fidx(int bh, int p){
  int q = ((bh >> 4) * 18720) + p;
  return (size_t)4194304 + (size_t)(3511 + (q >> 6)) * 1024
       + (size_t)((bh & 15) * 64) + (size_t)(q & 63);
}
__device__ __forceinline__ bool mget(const void* mp, int mode, int idx){
  if (mode == 0) return ((const unsigned char*)mp)[idx] != 0;
  if (mode == 1) return ((const int*)mp)[idx] != 0;
  return ((const float*)mp)[idx] != 0.f;
}

// ---------------- ka: per-block max of dd_k -> blockmax[wg] ----------------
__global__ __launch_bounds__(256) void ka(const float* kk, const float* P, float* dout){
  __shared__ float sK[64 * 65];
  __shared__ float sred[256];
  int wg = blockIdx.x, bh = wg >> 6, l0 = (wg & 63) << 6, t = threadIdx.x;
  const float4* src = (const float4*)(kk + ((size_t)bh * Lc + l0) * Dc);
  for (int p = 0; p < 4; ++p){
    int idx = p * 256 + t, row = idx >> 4, c4 = idx & 15;
    float4 v = src[idx];
    float* d1 = sK + row * 65 + c4 * 4;
    d1[0] = v.x * NORM; d1[1] = v.y * NORM; d1[2] = v.z * NORM; d1[3] = v.w * NORM;
  }
  __syncthreads();
  int l = t & 63, w = t >> 6;
  float vmax = -1e30f;
  for (int j = 0; j < 72; ++j){
    int m = w + 4 * j;
    if (m < Mc){
      const float* Pr = P + (size_t)m * 64;
      float dot = 0.f;
      #pragma unroll
      for (int d = 0; d < 64; ++d) dot += sK[l * 65 + d] * Pr[d];
      vmax = fmaxf(vmax, dot);
    }
  }
  sred[t] = vmax; __syncthreads();
  for (int s = 128; s > 0; s >>= 1){
    if (t < s) sred[t] = fmaxf(sred[t], sred[t + s]);
    __syncthreads();
  }
  if (t == 0) dout[BMAX + wg] = sred[0];
}

// ---------------- kb: kp + partial ctx = kp^T.[v] and ksum ----------------
__global__ __launch_bounds__(256) void kb(const float* kk, const float* vv, const void* mask,
                                          const float* P, float* dout){
  __shared__ float sK[64 * 65];
  __shared__ float sV[64 * 68];
  __shared__ float sQ[48 * 68];
  __shared__ float sred[256];
  int wg = blockIdx.x;
  int bh = wg / 48, r = wg % 48, part = r / 6, mc = r % 6;
  int b = bh >> 4;
  int t = threadIdx.x, l = t & 63, w = t >> 6;
  u32 w0 = *(const u32*)mask;
  int mode = (w0 == 0x01010101u) ? 0 : ((w0 == 0x3F800000u) ? 2 : 1);
  // redundant kmax reduction from 2048 block maxes
  float bm = -1e30f;
  for (int i = 0; i < 8; ++i) bm = fmaxf(bm, dout[BMAX + t + 256 * i]);
  sred[t] = bm; __syncthreads();
  for (int s = 128; s > 0; s >>= 1){
    if (t < s) sred[t] = fmaxf(sred[t], sred[t + s]);
    __syncthreads();
  }
  float kmax = sred[0];
  float acc[12];
  #pragma unroll
  for (int j = 0; j < 12; ++j) acc[j] = 0.f;
  float kss = 0.f;
  for (int s8 = 0; s8 < 8; ++s8){
    int l0 = part * 512 + s8 * 64;
    __syncthreads();
    const float4* ks4 = (const float4*)(kk + ((size_t)bh * Lc + l0) * Dc);
    const float4* vs4 = (const float4*)(vv + ((size_t)bh * Lc + l0) * Dc);
    for (int p = 0; p < 4; ++p){
      int idx = p * 256 + t, row = idx >> 4, c4 = idx & 15;
      float4 v = ks4[idx];
      float* d1 = sK + row * 65 + c4 * 4;
      d1[0] = v.x * NORM; d1[1] = v.y * NORM; d1[2] = v.z * NORM; d1[3] = v.w * NORM;
      float4 u = vs4[idx];
      float kf = mget(mask, mode, b * Lc + l0 + row) ? 1.f : 0.f;
      float* d2 = sV + row * 68 + c4 * 4;
      d2[0] = u.x * kf; d2[1] = u.y * kf; d2[2] = u.z * kf; d2[3] = u.w * kf;
    }
    __syncthreads();
    float dg = 0.f;
    #pragma unroll
    for (int d = 0; d < 64; ++d){ float x = sK[l * 65 + d]; dg += x * x; }
    dg *= 0.5f;
    for (int j = 0; j < 12; ++j){
      int mt = w * 12 + j, mg = mc * 48 + mt;
      float kp = 0.f;
      if (mg < Mc){
        const float* Pr = P + (size_t)mg * 64;
        float dot = 0.f;
        #pragma unroll
        for (int d = 0; d < 64; ++d) dot += sK[l * 65 + d] * Pr[d];
        float arg = fminf(dot - dg - kmax, 8.f);
        kp = __expf(arg) + EPSc;
      }
      sQ[mt * 68 + l] = kp;
    }
    __syncthreads();
    // accumulate: thread = (mgroup=w, d=t&63)
    for (int ll = 0; ll < 64; ++ll){
      float sv = sV[ll * 68 + l];
      #pragma unroll
      for (int j = 0; j < 12; ++j) acc[j] += sQ[(w * 12 + j) * 68 + ll] * sv;
    }
    if (t < 48){
      #pragma unroll
      for (int ll = 0; ll < 64; ++ll) kss += sQ[t * 68 + ll];
    }
  }
  size_t pbase = ((size_t)part * 32 + bh) * 18720;
  #pragma unroll
  for (int j = 0; j < 12; ++j){
    int mg = mc * 48 + w * 12 + j;
    dout[pbase + (size_t)l * 288 + mg] = acc[j];
  }
  if (t < 48) dout[pbase + 18432 + mc * 48 + t] = kss;
}

// ---------------- kc: reduce 8 partials -> stripe-packed ctx ----------------
__global__ __launch_bounds__(256) void kc(float* dout){
  int tid = blockIdx.x * 256 + threadIdx.x;   // 0..149759 = 32 * 4680
  int bh = tid / 4680, r4 = tid % 4680;
  int p = r4 * 4, m = p % 288;
  f32x4 s = {0.f, 0.f, 0.f, 0.f};
  if (m < 272){
    for (int p8 = 0; p8 < 8; ++p8)
      s += *(const f32x4*)(dout + ((size_t)p8 * 32 + bh) * 18720 + p);
  }
  *(f32x4*)(dout + ctx_fidx(bh, p)) = s;
}

// ---------------- kd: out tiles not overlapping scratch rows ----------------
__global__ __launch_bounds__(256) void kd(const float* q, const float* P, float* dout){
  __shared__ float ubuf[6400];     // q-tile [64][65] -> ctx chunk [64][96] -> sOut [64][68]
  __shared__ float sQp[96 * 68];
  __shared__ float sks[288];
  __shared__ float sred[256];
  __shared__ float srm[64];
  __shared__ float sden[64];
  int wg = blockIdx.x, bh = wg >> 6, lt = wg & 63;
  if (bh >= 16 && lt >= 54) return;            // scratch-overlap tiles -> ke
  int l0 = lt << 6, t = threadIdx.x, l = t & 63, w = t >> 6;
  const float4* src = (const float4*)(q + ((size_t)bh * Lc + l0) * Dc);
  for (int p = 0; p < 4; ++p){
    int idx = p * 256 + t, row = idx >> 4, c4 = idx & 15;
    float4 v = src[idx];
    float* d1 = ubuf + row * 65 + c4 * 4;
    d1[0] = v.x * NORM; d1[1] = v.y * NORM; d1[2] = v.z * NORM; d1[3] = v.w * NORM;
  }
  if (t < 72) *(f32x4*)(sks + t * 4) = *(const f32x4*)(dout + ctx_fidx(bh, 18432 + t * 4));
  __syncthreads();
  float dgl = 0.f;
  #pragma unroll
  for (int d = 0; d < 64; ++d){ float x = ubuf[l * 65 + d]; dgl += x * x; }
  dgl *= 0.5f;
  float dd[72];
  float pm = -1e30f;
  #pragma unroll
  for (int j = 0; j < 72; ++j){
    int m = w + 4 * j;
    float dot = 0.f;
    if (m < Mc){
      const float* Pr = P + (size_t)m * 64;
      #pragma unroll
      for (int d = 0; d < 64; ++d) dot += ubuf[l * 65 + d] * Pr[d];
      pm = fmaxf(pm, dot);
    }
    dd[j] = dot;
  }
  sred[l * 4 + w] = pm; __syncthreads();
  if (t < 64) srm[t] = fmaxf(fmaxf(sred[t*4], sred[t*4+1]), fmaxf(sred[t*4+2], sred[t*4+3]));
  __syncthreads();
  float rml = srm[l];
  float den = 0.f;
  float out[16];
  #pragma unroll
  for (int jq = 0; jq < 16; ++jq) out[jq] = 0.f;
  for (int c = 0; c < 3; ++c){
    __syncthreads();   // prior readers of sQp/ubuf done
    #pragma unroll
    for (int jj = 0; jj < 24; ++jj){
      int j = 24 * c + jj, m = w + 4 * j, ml = w + 4 * jj;
      float qp = 0.f;
      if (m < Mc){
        float arg = fminf(dd[j] - dgl - rml, 8.f);
        qp = __expf(arg) + EPSc;
        den += qp * sks[m];
      }
      sQp[ml * 68 + l] = qp;
    }
    for (int p = 0; p < 6; ++p){
      int i4 = p * 256 + t, d = i4 / 24, mq4 = i4 % 24;
      f32x4 cv = *(const f32x4*)(dout + ctx_fidx(bh, d * 288 + 96 * c + mq4 * 4));
      float* dc = ubuf + d * 96 + mq4 * 4;
      dc[0] = cv[0]; dc[1] = cv[1]; dc[2] = cv[2]; dc[3] = cv[3];
    }
    __syncthreads();
    for (int mq = 0; mq < 96; ++mq){
      float qv = sQp[mq * 68 + l];
      #pragma unroll
      for (int jq = 0; jq < 16; ++jq) out[jq] += qv * ubuf[(w * 16 + jq) * 96 + mq];
    }
  }
  __syncthreads();
  sred[l * 4 + w] = den; __syncthreads();
  if (t < 64) sden[t] = sred[t*4] + sred[t*4+1] + sred[t*4+2] + sred[t*4+3];
  __syncthreads();
  float dval = sden[l];
  float di = (dval > 1e-30f) ? 1.f / dval : -1.f;
  #pragma unroll
  for (int jq = 0; jq < 16; ++jq){
    float o = (di > 0.f) ? out[jq] * di : 3.0f;       // sentinel 3.0 = denom path
    if (!(o == o && fabsf(o) < 1e30f)) o = 9.0f;      // sentinel 9.0 = non-finite
    ubuf[l * 68 + w * 16 + jq] = o;
  }
  __syncthreads();
  int b = bh >> 4, hh = bh & 15;
  for (int p = 0; p < 4; ++p){
    int i4 = p * 256 + t, row = i4 >> 4, c4 = i4 & 15;
    float4 ov;
    ov.x = ubuf[row*68 + c4*4]; ov.y = ubuf[row*68 + c4*4 + 1];
    ov.z = ubuf[row*68 + c4*4 + 2]; ov.w = ubuf[row*68 + c4*4 + 3];
    *(float4*)(dout + ((size_t)b * Lc + l0 + row) * 1024 + hh * 64 + c4 * 4) = ov;
  }
}

// ---------------- ke: 16 blocks x 1024 thr, the 10 scratch-overlap tiles per b=1 head ----------------
__global__ __launch_bounds__(1024) void ke(const float* q, const float* P, float* dout){
  __shared__ float ubuf[6400];
  __shared__ float sQp[96 * 68];
  __shared__ float sks[288];
  __shared__ float sred[1024];
  __shared__ float srm[64];
  __shared__ float sden[64];
  int hh = blockIdx.x, bh = 16 + hh;
  int t = threadIdx.x, l = t & 63, w = t >> 6;   // w in 0..15
  if (t < 72) *(f32x4*)(sks + t * 4) = *(const f32x4*)(dout + ctx_fidx(bh, 18432 + t * 4));
  float stash[40];
  #pragma unroll
  for (int ti = 0; ti < 10; ++ti){
    int l0 = (54 + ti) * 64;
    __syncthreads();
    const float4* src = (const float4*)(q + ((size_t)bh * Lc + l0) * Dc);
    { int idx = t, row = idx >> 4, c4 = idx & 15;
      float4 v = src[idx];
      float* d1 = ubuf + row * 65 + c4 * 4;
      d1[0] = v.x * NORM; d1[1] = v.y * NORM; d1[2] = v.z * NORM; d1[3] = v.w * NORM; }
    __syncthreads();
    float dgl = 0.f;
    #pragma unroll
    for (int d = 0; d < 64; ++d){ float x = ubuf[l * 65 + d]; dgl += x * x; }
    dgl *= 0.5f;
    float dd[18];
    float pm = -1e30f;
    #pragma unroll
    for (int j = 0; j < 18; ++j){
      int m = w + 16 * j;
      float dot = 0.f;
      if (m < Mc){
        const float* Pr = P + (size_t)m * 64;
        #pragma unroll
        for (int d = 0; d < 64; ++d) dot += ubuf[l * 65 + d] * Pr[d];
        pm = fmaxf(pm, dot);
      }
      dd[j] = dot;
    }
    sred[l * 16 + w] = pm; __syncthreads();
    if (t < 64){
      float mx = -1e30f;
      #pragma unroll
      for (int i = 0; i < 16; ++i) mx = fmaxf(mx, sred[t * 16 + i]);
      srm[t] = mx;
    }
    __syncthreads();
    float rml = srm[l];
    float den = 0.f;
    float out[4];
    #pragma unroll
    for (int jq = 0; jq < 4; ++jq) out[jq] = 0.f;
    for (int c = 0; c < 3; ++c){
      __syncthreads();
      #pragma unroll
      for (int jj = 0; jj < 6; ++jj){
        int j = 6 * c + jj, m = w + 16 * j, ml = w + 16 * jj;
        float qp = 0.f;
        if (m < Mc){
          float arg = fminf(dd[j] - dgl - rml, 8.f);
          qp = __expf(arg) + EPSc;
          den += qp * sks[m];
        }
        sQp[ml * 68 + l] = qp;
      }
      for (int p = 0; p < 2; ++p){
        int i4 = p * 1024 + t;
        if (i4 < 1536){
          int d = i4 / 24, mq4 = i4 % 24;
          f32x4 cv = *(const f32x4*)(dout + ctx_fidx(bh, d * 288 + 96 * c + mq4 * 4));
          float* dc = ubuf + d * 96 + mq4 * 4;
          dc[0] = cv[0]; dc[1] = cv[1]; dc[2] = cv[2]; dc[3] = cv[3];
        }
      }
      __syncthreads();
      for (int mq = 0; mq < 96; ++mq){
        float qv = sQp[mq * 68 + l];
        #pragma unroll
        for (int jq = 0; jq < 4; ++jq) out[jq] += qv * ubuf[(w * 4 + jq) * 96 + mq];
      }
    }
    __syncthreads();
    sred[l * 16 + w] = den; __syncthreads();
    if (t < 64){
      float sm = 0.f;
      #pragma unroll
      for (int i = 0; i < 16; ++i) sm += sred[t * 16 + i];
      sden[t] = sm;
    }
    __syncthreads();
    float dval = sden[l];
    float di = (dval > 1e-30f) ? 1.f / dval : -1.f;
    #pragma unroll
    for (int jq = 0; jq < 4; ++jq){
      float o = (di > 0.f) ? out[jq] * di : 3.0f;
      if (!(o == o && fabsf(o) < 1e30f)) o = 9.0f;
      stash[ti * 4 + jq] = o;
    }
  }
  // all ctx/sks reads complete for this block; now overwrite scratch rows with true output
  #pragma unroll
  for (int ti = 0; ti < 10; ++ti){
    __syncthreads();
    #pragma unroll
    for (int jq = 0; jq < 4; ++jq) ubuf[l * 68 + w * 4 + jq] = stash[ti * 4 + jq];
    __syncthreads();
    int row = t >> 4, c4 = t & 15;
    float4 ov;
    ov.x = ubuf[row*68 + c4*4]; ov.y = ubuf[row*68 + c4*4 + 1];
    ov.z = ubuf[row*68 + c4*4 + 2]; ov.w = ubuf[row*68 + c4*4 + 3];
    *(float4*)(dout + ((size_t)1 * Lc + (54 + ti) * 64 + row) * 1024 + hh * 64 + c4 * 4) = ov;
  }
}

extern "C" void kernel_launch(void* const* d_in, const int* in_sizes, int n_in,
                              void* d_out, int out_size, void* d_ws, size_t ws_size,
                              hipStream_t stream){
  const float* q    = (const float*)d_in[0];
  const float* kk   = (const float*)d_in[1];
  const float* vv   = (const float*)d_in[2];
  const void*  mask = d_in[3];
  const float* P    = (const float*)d_in[4];
  float* dout = (float*)d_out;
  hipLaunchKernelGGL(ka, dim3(2048), dim3(256),  0, stream, kk, P, dout);
  hipLaunchKernelGGL(kb, dim3(1536), dim3(256),  0, stream, kk, vv, mask, P, dout);
  hipLaunchKernelGGL(kc, dim3(585),  dim3(256),  0, stream, dout);
  hipLaunchKernelGGL(kd, dim3(2048), dim3(256),  0, stream, q, P, dout);
  hipLaunchKernelGGL(ke, dim3(16),   dim3(1024), 0, stream, q, P, dout);
}

// Round 8
// 1011.176 us; speedup vs baseline: 1.7726x; 1.7726x over previous
//
#include <hip/hip_runtime.h>
#include <cstdint>

#define DEV static __device__ __forceinline__

typedef float f32x4 __attribute__((ext_vector_type(4)));
typedef __bf16 bf16x8 __attribute__((ext_vector_type(8)));
typedef unsigned short u16;
typedef unsigned int u32;

constexpr int Lc = 4096, Dc = 64, Mc = 266;
constexpr float NORM = 0.35355339059327373f;   // 64^-0.25
constexpr float EPSc = 1e-4f;

// ---- ALL scratch in d_out (8,388,608 floats). d_ws unused. ----
// partial : [8][32][18720] f32 @ fidx 0..4,792,319   (dead after kc)
// blockmax: 2048 f32 @ fidx 7,785,472 (b=1 rows 3507-3508)
// ctx     : per bh, 18720 f32 stripe-packed in b=1 rows 3511.., cols (bh&15)*64..+63
// scratch rows (b=1, 3456+) overwritten with true output by ke (last kernel)
constexpr size_t BMAX = 7785472;

DEV size_t ctx_fidx(int bh, int p){
  int q = ((bh >> 4) * 18720) + p;
  return (size_t)4194304 + (size_t)(3511 + (q >> 6)) * 1024
       + (size_t)((bh & 15) * 64) + (size_t)(q & 63);
}
DEV bool mget(const void* mp, int mode, int idx){
  if (mode == 0) return ((const unsigned char*)mp)[idx] != 0;
  if (mode == 1) return ((const int*)mp)[idx] != 0;
  return ((const float*)mp)[idx] != 0.f;
}
DEV u16 f2b(float f){ u32 u = __float_as_uint(f); return (u16)((u + 0x7FFFu + ((u>>16)&1u)) >> 16); }
DEV float b2f(u16 h){ return __uint_as_float(((u32)h) << 16); }
DEV f32x4 mfma16(bf16x8 a, bf16x8 b, f32x4 c){ return __builtin_amdgcn_mfma_f32_16x16x32_bf16(a, b, c, 0, 0, 0); }
DEV void mkfrag(float4 a, float4 b, bf16x8& fh, bf16x8& fl){
  union { u16 u[8]; bf16x8 v; } H, L;
  float x[8] = {a.x,a.y,a.z,a.w,b.x,b.y,b.z,b.w};
  #pragma unroll
  for (int j=0;j<8;++j){ u16 h = f2b(x[j]); H.u[j] = h; L.u[j] = f2b(x[j] - b2f(h)); }
  fh = H.v; fl = L.v;
}

// ---------------- ka: per-block max of dd_k via MFMA -> blockmax[wg] ----------------
__global__ __launch_bounds__(256) void ka(const float* kk, const float* P, float* dout){
  __shared__ float sred[4];
  int wg = blockIdx.x, bh = wg >> 6, l0 = (wg & 63) << 6, t = threadIdx.x;
  int wv = t >> 6, lane = t & 63, hg = lane >> 4, li = lane & 15;
  const float* krow = kk + ((size_t)bh * Lc + l0 + wv*16 + li) * Dc;
  float4 qa = *(const float4*)(krow + hg*8);
  float4 qb = *(const float4*)(krow + hg*8 + 4);
  float4 qc = *(const float4*)(krow + 32 + hg*8);
  float4 qd = *(const float4*)(krow + 32 + hg*8 + 4);
  qa.x*=NORM; qa.y*=NORM; qa.z*=NORM; qa.w*=NORM;
  qb.x*=NORM; qb.y*=NORM; qb.z*=NORM; qb.w*=NORM;
  qc.x*=NORM; qc.y*=NORM; qc.z*=NORM; qc.w*=NORM;
  qd.x*=NORM; qd.y*=NORM; qd.z*=NORM; qd.w*=NORM;
  bf16x8 qh0,ql0,qh1,ql1;
  mkfrag(qa,qb,qh0,ql0); mkfrag(qc,qd,qh1,ql1);
  float vmax = -1e30f;
  #pragma unroll
  for (int mf=0; mf<18; ++mf){
    int mrow = mf*16 + li;
    float4 pa,pb,pc,pd;
    if (mrow < Mc){
      const float* Pr = P + (size_t)mrow * 64;
      pa = *(const float4*)(Pr + hg*8); pb = *(const float4*)(Pr + hg*8 + 4);
      pc = *(const float4*)(Pr + 32 + hg*8); pd = *(const float4*)(Pr + 32 + hg*8 + 4);
    } else { pa = pb = pc = pd = make_float4(0.f,0.f,0.f,0.f); }
    bf16x8 ph0,pl0,ph1,pl1;
    mkfrag(pa,pb,ph0,pl0); mkfrag(pc,pd,ph1,pl1);
    f32x4 x = {0.f,0.f,0.f,0.f};
    x = mfma16(ph0, qh0, x); x = mfma16(ph1, qh1, x);
    x = mfma16(ph0, ql0, x); x = mfma16(ph1, ql1, x);
    x = mfma16(pl0, qh0, x); x = mfma16(pl1, qh1, x);
    #pragma unroll
    for (int i=0;i<4;++i){
      int m = mf*16 + hg*4 + i;
      if (m < Mc) vmax = fmaxf(vmax, x[i]);
    }
  }
  vmax = fmaxf(vmax, __shfl_xor(vmax, 1));
  vmax = fmaxf(vmax, __shfl_xor(vmax, 2));
  vmax = fmaxf(vmax, __shfl_xor(vmax, 4));
  vmax = fmaxf(vmax, __shfl_xor(vmax, 8));
  vmax = fmaxf(vmax, __shfl_xor(vmax, 16));
  vmax = fmaxf(vmax, __shfl_xor(vmax, 32));
  if (lane == 0) sred[wv] = vmax;
  __syncthreads();
  if (t == 0) dout[BMAX + wg] = fmaxf(fmaxf(sred[0],sred[1]), fmaxf(sred[2],sred[3]));
}

// ---------------- kb: kp + partial ctx = kp^T.[v] and ksum (UNCHANGED, proven) ----------------
__global__ __launch_bounds__(256) void kb(const float* kk, const float* vv, const void* mask,
                                          const float* P, float* dout){
  __shared__ float sK[64 * 65];
  __shared__ float sV[64 * 68];
  __shared__ float sQ[48 * 68];
  __shared__ float sred[256];
  int wg = blockIdx.x;
  int bh = wg / 48, r = wg % 48, part = r / 6, mc = r % 6;
  int b = bh >> 4;
  int t = threadIdx.x, l = t & 63, w = t >> 6;
  u32 w0 = *(const u32*)mask;
  int mode = (w0 == 0x01010101u) ? 0 : ((w0 == 0x3F800000u) ? 2 : 1);
  float bm = -1e30f;
  for (int i = 0; i < 8; ++i) bm = fmaxf(bm, dout[BMAX + t + 256 * i]);
  sred[t] = bm; __syncthreads();
  for (int s = 128; s > 0; s >>= 1){
    if (t < s) sred[t] = fmaxf(sred[t], sred[t + s]);
    __syncthreads();
  }
  float kmax = sred[0];
  float acc[12];
  #pragma unroll
  for (int j = 0; j < 12; ++j) acc[j] = 0.f;
  float kss = 0.f;
  for (int s8 = 0; s8 < 8; ++s8){
    int l0 = part * 512 + s8 * 64;
    __syncthreads();
    const float4* ks4 = (const float4*)(kk + ((size_t)bh * Lc + l0) * Dc);
    const float4* vs4 = (const float4*)(vv + ((size_t)bh * Lc + l0) * Dc);
    for (int p = 0; p < 4; ++p){
      int idx = p * 256 + t, row = idx >> 4, c4 = idx & 15;
      float4 v = ks4[idx];
      float* d1 = sK + row * 65 + c4 * 4;
      d1[0] = v.x * NORM; d1[1] = v.y * NORM; d1[2] = v.z * NORM; d1[3] = v.w * NORM;
      float4 u = vs4[idx];
      float kf = mget(mask, mode, b * Lc + l0 + row) ? 1.f : 0.f;
      float* d2 = sV + row * 68 + c4 * 4;
      d2[0] = u.x * kf; d2[1] = u.y * kf; d2[2] = u.z * kf; d2[3] = u.w * kf;
    }
    __syncthreads();
    float dg = 0.f;
    #pragma unroll
    for (int d = 0; d < 64; ++d){ float x = sK[l * 65 + d]; dg += x * x; }
    dg *= 0.5f;
    for (int j = 0; j < 12; ++j){
      int mt = w * 12 + j, mg = mc * 48 + mt;
      float kp = 0.f;
      if (mg < Mc){
        const float* Pr = P + (size_t)mg * 64;
        float dot = 0.f;
        #pragma unroll
        for (int d = 0; d < 64; ++d) dot += sK[l * 65 + d] * Pr[d];
        float arg = fminf(dot - dg - kmax, 8.f);
        kp = __expf(arg) + EPSc;
      }
      sQ[mt * 68 + l] = kp;
    }
    __syncthreads();
    for (int ll = 0; ll < 64; ++ll){
      float sv = sV[ll * 68 + l];
      #pragma unroll
      for (int j = 0; j < 12; ++j) acc[j] += sQ[(w * 12 + j) * 68 + ll] * sv;
    }
    if (t < 48){
      #pragma unroll
      for (int ll = 0; ll < 64; ++ll) kss += sQ[t * 68 + ll];
    }
  }
  size_t pbase = ((size_t)part * 32 + bh) * 18720;
  #pragma unroll
  for (int j = 0; j < 12; ++j){
    int mg = mc * 48 + w * 12 + j;
    dout[pbase + (size_t)l * 288 + mg] = acc[j];
  }
  if (t < 48) dout[pbase + 18432 + mc * 48 + t] = kss;
}

// ---------------- kc: reduce 8 partials -> stripe-packed ctx (UNCHANGED) ----------------
__global__ __launch_bounds__(256) void kc(float* dout){
  int tid = blockIdx.x * 256 + threadIdx.x;
  int bh = tid / 4680, r4 = tid % 4680;
  int p = r4 * 4, m = p % 288;
  f32x4 s = {0.f, 0.f, 0.f, 0.f};
  if (m < 272){
    for (int p8 = 0; p8 < 8; ++p8)
      s += *(const f32x4*)(dout + ((size_t)p8 * 32 + bh) * 18720 + p);
  }
  *(f32x4*)(dout + ctx_fidx(bh, p)) = s;
}

// ---------------- MFMA tile engine: dd, rowmax, qp, out = qp.ctx.d_inv ----------------
DEV void tile_mfma(const float* q, const float* P, const float* dof,
                   int bh, int l0, int t,
                   float* sQp, const float* sks, float* sden,
                   f32x4 (&acc3)[4]){
  int wv = t >> 6, lane = t & 63, hg = lane >> 4, li = lane & 15;
  // q B-fragments (direct from global: row l = l0+wv*16+li, k-slots hg*8+j per 32-k half)
  const float* qrow = q + ((size_t)bh * Lc + l0 + wv*16 + li) * Dc;
  float4 qa = *(const float4*)(qrow + hg*8);
  float4 qb = *(const float4*)(qrow + hg*8 + 4);
  float4 qc = *(const float4*)(qrow + 32 + hg*8);
  float4 qd = *(const float4*)(qrow + 32 + hg*8 + 4);
  qa.x*=NORM; qa.y*=NORM; qa.z*=NORM; qa.w*=NORM;
  qb.x*=NORM; qb.y*=NORM; qb.z*=NORM; qb.w*=NORM;
  qc.x*=NORM; qc.y*=NORM; qc.z*=NORM; qc.w*=NORM;
  qd.x*=NORM; qd.y*=NORM; qd.z*=NORM; qd.w*=NORM;
  float ssl = qa.x*qa.x+qa.y*qa.y+qa.z*qa.z+qa.w*qa.w
            + qb.x*qb.x+qb.y*qb.y+qb.z*qb.z+qb.w*qb.w
            + qc.x*qc.x+qc.y*qc.y+qc.z*qc.z+qc.w*qc.w
            + qd.x*qd.x+qd.y*qd.y+qd.z*qd.z+qd.w*qd.w;
  ssl += __shfl_xor(ssl, 16); ssl += __shfl_xor(ssl, 32);
  float dg = ssl * 0.5f;
  bf16x8 qh0,ql0,qh1,ql1;
  mkfrag(qa,qb,qh0,ql0); mkfrag(qc,qd,qh1,ql1);
  // dd: D[m-local = hg*4+i][l-local = li] per 16-m fragment, split 3-term x 2 k-halves
  f32x4 dd[18];
  #pragma unroll
  for (int mf=0; mf<18; ++mf){
    int mrow = mf*16 + li;
    float4 pa,pb,pc,pd;
    if (mrow < Mc){
      const float* Pr = P + (size_t)mrow * 64;
      pa = *(const float4*)(Pr + hg*8); pb = *(const float4*)(Pr + hg*8 + 4);
      pc = *(const float4*)(Pr + 32 + hg*8); pd = *(const float4*)(Pr + 32 + hg*8 + 4);
    } else { pa = pb = pc = pd = make_float4(0.f,0.f,0.f,0.f); }
    bf16x8 ph0,pl0,ph1,pl1;
    mkfrag(pa,pb,ph0,pl0); mkfrag(pc,pd,ph1,pl1);
    f32x4 x = {0.f,0.f,0.f,0.f};
    x = mfma16(ph0, qh0, x); x = mfma16(ph1, qh1, x);
    x = mfma16(ph0, ql0, x); x = mfma16(ph1, ql1, x);
    x = mfma16(pl0, qh0, x); x = mfma16(pl1, qh1, x);
    dd[mf] = x;
  }
  // rowmax per l (lane covers its m-quarter for column li; lanes li,li+16,.. partition m)
  float rm = -1e30f;
  #pragma unroll
  for (int mf=0; mf<18; ++mf)
    #pragma unroll
    for (int i=0;i<4;++i){
      int m = mf*16 + hg*4 + i;
      if (m < Mc) rm = fmaxf(rm, dd[mf][i]);
    }
  rm = fmaxf(rm, __shfl_xor(rm, 16));
  rm = fmaxf(rm, __shfl_xor(rm, 32));
  // chunks: qp -> LDS [96][65] f32, then out-GEMM (A3 = qp^T from LDS, B3 = ctx from stripe)
  float den = 0.f;
  #pragma unroll
  for (int df=0; df<4; ++df){ f32x4 z = {0.f,0.f,0.f,0.f}; acc3[df] = z; }
  for (int c=0; c<3; ++c){
    __syncthreads();
    #pragma unroll
    for (int mf6=0; mf6<6; ++mf6){
      int mf = c*6 + mf6;
      #pragma unroll
      for (int i=0;i<4;++i){
        int m = mf*16 + hg*4 + i;
        float qp = 0.f;
        if (m < Mc){
          float arg = fminf(dd[mf][i] - dg - rm, 8.f);
          qp = __expf(arg) + EPSc;
          den += qp * sks[m];
        }
        sQp[(mf6*16 + hg*4 + i)*65 + wv*16 + li] = qp;
      }
    }
    __syncthreads();
    #pragma unroll
    for (int ks=0; ks<3; ++ks){
      int k0 = ks*32;
      float av[8];
      #pragma unroll
      for (int j=0;j<8;++j) av[j] = sQp[(k0 + hg*8 + j)*65 + wv*16 + li];
      union { u16 u[8]; bf16x8 v; } AH, AL;
      #pragma unroll
      for (int j=0;j<8;++j){ u16 h = f2b(av[j]); AH.u[j] = h; AL.u[j] = f2b(av[j] - b2f(h)); }
      #pragma unroll
      for (int df=0; df<4; ++df){
        size_t f = ctx_fidx(bh, (df*16 + li)*288 + c*96 + k0 + hg*8);
        float4 ca = *(const float4*)(dof + f);
        float4 cb = *(const float4*)(dof + f + 4);
        bf16x8 ch, cl;
        mkfrag(ca, cb, ch, cl);
        acc3[df] = mfma16(AH.v, ch, acc3[df]);
        acc3[df] = mfma16(AH.v, cl, acc3[df]);
        acc3[df] = mfma16(AL.v, ch, acc3[df]);
      }
    }
  }
  // denom: lane's partial covers its m-subset for l = wv*16+li
  den += __shfl_xor(den, 16);
  den += __shfl_xor(den, 32);
  if (hg == 0) sden[wv*16 + li] = den;
  __syncthreads();
  #pragma unroll
  for (int i=0;i<4;++i){
    float dv = sden[wv*16 + hg*4 + i];   // output row l = wv*16 + hg*4 + i
    float di = (dv > 1e-30f) ? 1.f/dv : -1.f;
    #pragma unroll
    for (int df=0; df<4; ++df){
      float o = (di > 0.f) ? acc3[df][i]*di : 3.0f;   // sentinel 3.0 = denom path
      if (!(o == o && fabsf(o) < 1e30f)) o = 9.0f;    // sentinel 9.0 = non-finite
      acc3[df][i] = o;
    }
  }
}

// ---------------- kd: all non-scratch-overlap tiles ----------------
__global__ __launch_bounds__(256) void kd(const float* q, const float* P, float* dout){
  __shared__ float sQp[96 * 65];
  __shared__ float sks[288];
  __shared__ float sden[64];
  int wg = blockIdx.x, bh = wg >> 6, lt = wg & 63;
  if (bh >= 16 && lt >= 54) return;            // handled by ke
  int t = threadIdx.x, wv = t >> 6, lane = t & 63, hg = lane >> 4, li = lane & 15;
  if (t < 72) *(f32x4*)(sks + t*4) = *(const f32x4*)(dout + ctx_fidx(bh, 18432 + t*4));
  f32x4 acc3[4];
  tile_mfma(q, P, dout, bh, lt*64, t, sQp, sks, sden, acc3);
  int b = bh >> 4, hh = bh & 15;
  #pragma unroll
  for (int df=0; df<4; ++df)
    #pragma unroll
    for (int i=0;i<4;++i)
      dout[((size_t)b*Lc + lt*64 + wv*16 + hg*4 + i)*1024 + hh*64 + df*16 + li] = acc3[df][i];
}

// ---------------- ke: 16 blocks, 10 scratch-overlap tiles per b=1 head ----------------
// Reads ctx (own head's columns only) during tiles; writes (same columns) after all tiles.
__global__ __launch_bounds__(256) void ke(const float* q, const float* P, float* dout){
  __shared__ float sQp[96 * 65];
  __shared__ float sks[288];
  __shared__ float sden[64];
  int hh = blockIdx.x, bh = 16 + hh;
  int t = threadIdx.x, wv = t >> 6, lane = t & 63, hg = lane >> 4, li = lane & 15;
  if (t < 72) *(f32x4*)(sks + t*4) = *(const f32x4*)(dout + ctx_fidx(bh, 18432 + t*4));
  u32 stash[80];
  #pragma unroll
  for (int ti=0; ti<10; ++ti){
    f32x4 acc3[4];
    tile_mfma(q, P, dout, bh, (54 + ti)*64, t, sQp, sks, sden, acc3);
    #pragma unroll
    for (int df=0; df<4; ++df)
      #pragma unroll
      for (int i2=0; i2<2; ++i2)
        stash[ti*8 + df*2 + i2] = (u32)f2b(acc3[df][i2*2]) | ((u32)f2b(acc3[df][i2*2+1]) << 16);
  }
  __syncthreads();   // all ctx reads complete before overwriting scratch rows
  #pragma unroll
  for (int ti=0; ti<10; ++ti)
    #pragma unroll
    for (int df=0; df<4; ++df)
      #pragma unroll
      for (int i=0;i<4;++i){
        u16 bits = (u16)(stash[ti*8 + df*2 + (i>>1)] >> ((i&1)*16));
        dout[((size_t)Lc + (54+ti)*64 + wv*16 + hg*4 + i)*1024 + hh*64 + df*16 + li] = b2f(bits);
      }
}

extern "C" void kernel_launch(void* const* d_in, const int* in_sizes, int n_in,
                              void* d_out, int out_size, void* d_ws, size_t ws_size,
                              hipStream_t stream){
  const float* q    = (const float*)d_in[0];
  const float* kk   = (const float*)d_in[1];
  const float* vv   = (const float*)d_in[2];
  const void*  mask = d_in[3];
  const float* P    = (const float*)d_in[4];
  float* dout = (float*)d_out;
  hipLaunchKernelGGL(ka, dim3(2048), dim3(256), 0, stream, kk, P, dout);
  hipLaunchKernelGGL(kb, dim3(1536), dim3(256), 0, stream, kk, vv, mask, P, dout);
  hipLaunchKernelGGL(kc, dim3(585),  dim3(256), 0, stream, dout);
  hipLaunchKernelGGL(kd, dim3(2048), dim3(256), 0, stream, q, P, dout);
  hipLaunchKernelGGL(ke, dim3(16),   dim3(256), 0, stream, q, P, dout);
}

// Round 9
// 774.116 us; speedup vs baseline: 2.3155x; 1.3062x over previous
//
#include <hip/hip_runtime.h>
#include <cstdint>

#define DEV static __device__ __forceinline__

typedef float f32x4 __attribute__((ext_vector_type(4)));
typedef __bf16 bf16x8 __attribute__((ext_vector_type(8)));
typedef unsigned short u16;
typedef unsigned int u32;

constexpr int Lc = 4096, Dc = 64, Mc = 266;
constexpr float NORM = 0.35355339059327373f;   // 64^-0.25
constexpr float EPSc = 1e-4f;

// ---- ALL scratch in d_out (8,388,608 floats). d_ws unused. ----
// partial : [8][32][18720] f32 @ fidx 0..4,792,319   (dead after kc)
// blockmax: 2048 f32 @ fidx 7,785,472 (b=1 rows 3507-3508)
// ctx     : per bh, 18720 f32 stripe-packed in b=1 rows 3511..3803, cols (bh&15)*64..+63
// P-split : PH/PL bf16[288*64] @ b=1 rows 3900.. (written by kp0; read by ka/kb only)
// scratch rows (b=1, 3456+) overwritten with true output by ke (last kernel)
constexpr size_t BMAX = 7785472;
constexpr size_t PSPH = 8187904;   // 9216 floats (u16[18432])
constexpr size_t PSPL = 8197120;

DEV size_t ctx_fidx(int bh, int p){
  int q = ((bh >> 4) * 18720) + p;
  return (size_t)4194304 + (size_t)(3511 + (q >> 6)) * 1024
       + (size_t)((bh & 15) * 64) + (size_t)(q & 63);
}
DEV bool mget(const void* mp, int mode, int idx){
  if (mode == 0) return ((const unsigned char*)mp)[idx] != 0;
  if (mode == 1) return ((const int*)mp)[idx] != 0;
  return ((const float*)mp)[idx] != 0.f;
}
DEV u16 f2b(float f){ u32 u = __float_as_uint(f); return (u16)((u + 0x7FFFu + ((u>>16)&1u)) >> 16); }
DEV float b2f(u16 h){ return __uint_as_float(((u32)h) << 16); }
DEV f32x4 mfma16(bf16x8 a, bf16x8 b, f32x4 c){ return __builtin_amdgcn_mfma_f32_16x16x32_bf16(a, b, c, 0, 0, 0); }
DEV void mkfrag(float4 a, float4 b, bf16x8& fh, bf16x8& fl){
  union { u16 u[8]; bf16x8 v; } H, L;
  float x[8] = {a.x,a.y,a.z,a.w,b.x,b.y,b.z,b.w};
  #pragma unroll
  for (int j=0;j<8;++j){ u16 h = f2b(x[j]); H.u[j] = h; L.u[j] = f2b(x[j] - b2f(h)); }
  fh = H.v; fl = L.v;
}
DEV bf16x8 ldb(const u16* p){ return *(const bf16x8*)p; }

// ---------------- kp0: one-time P hi/lo split table (zero-padded to 288 rows) ----------------
__global__ __launch_bounds__(256) void kp0(const float* P, float* dout){
  int idx = blockIdx.x * 256 + threadIdx.x;
  if (idx >= 288 * 64) return;
  int m = idx >> 6;
  float v = (m < Mc) ? P[idx] : 0.f;
  u16 h = f2b(v);
  ((u16*)(dout + PSPH))[idx] = h;
  ((u16*)(dout + PSPL))[idx] = f2b(v - b2f(h));
}

// ---------------- ka: per-block max of dd_k via MFMA (P from split table) ----------------
__global__ __launch_bounds__(256) void ka(const float* kk, float* dout){
  __shared__ float sred[4];
  int wg = blockIdx.x, bh = wg >> 6, l0 = (wg & 63) << 6, t = threadIdx.x;
  int wv = t >> 6, lane = t & 63, hg = lane >> 4, li = lane & 15;
  const u16* PH = (const u16*)(dout + PSPH);
  const u16* PL = (const u16*)(dout + PSPL);
  const float* krow = kk + ((size_t)bh * Lc + l0 + wv*16 + li) * Dc;
  float4 qa = *(const float4*)(krow + hg*8);
  float4 qb = *(const float4*)(krow + hg*8 + 4);
  float4 qc = *(const float4*)(krow + 32 + hg*8);
  float4 qd = *(const float4*)(krow + 32 + hg*8 + 4);
  qa.x*=NORM; qa.y*=NORM; qa.z*=NORM; qa.w*=NORM;
  qb.x*=NORM; qb.y*=NORM; qb.z*=NORM; qb.w*=NORM;
  qc.x*=NORM; qc.y*=NORM; qc.z*=NORM; qc.w*=NORM;
  qd.x*=NORM; qd.y*=NORM; qd.z*=NORM; qd.w*=NORM;
  bf16x8 qh0,ql0,qh1,ql1;
  mkfrag(qa,qb,qh0,ql0); mkfrag(qc,qd,qh1,ql1);
  float vmax = -1e30f;
  #pragma unroll
  for (int mf=0; mf<18; ++mf){
    int mrow = mf*16 + li;
    bf16x8 ph0 = ldb(PH + mrow*64 + hg*8), ph1 = ldb(PH + mrow*64 + 32 + hg*8);
    bf16x8 pl0 = ldb(PL + mrow*64 + hg*8), pl1 = ldb(PL + mrow*64 + 32 + hg*8);
    f32x4 x = {0.f,0.f,0.f,0.f};
    x = mfma16(ph0, qh0, x); x = mfma16(ph1, qh1, x);
    x = mfma16(ph0, ql0, x); x = mfma16(ph1, ql1, x);
    x = mfma16(pl0, qh0, x); x = mfma16(pl1, qh1, x);
    #pragma unroll
    for (int i=0;i<4;++i){
      int m = mf*16 + hg*4 + i;
      if (m < Mc) vmax = fmaxf(vmax, x[i]);
    }
  }
  vmax = fmaxf(vmax, __shfl_xor(vmax, 1));
  vmax = fmaxf(vmax, __shfl_xor(vmax, 2));
  vmax = fmaxf(vmax, __shfl_xor(vmax, 4));
  vmax = fmaxf(vmax, __shfl_xor(vmax, 8));
  vmax = fmaxf(vmax, __shfl_xor(vmax, 16));
  vmax = fmaxf(vmax, __shfl_xor(vmax, 32));
  if (lane == 0) sred[wv] = vmax;
  __syncthreads();
  if (t == 0) dout[BMAX + wg] = fmaxf(fmaxf(sred[0],sred[1]), fmaxf(sred[2],sred[3]));
}

// ---------------- kb: MFMA kp + partial ctx = kp^T.[v|1] (ksum via ones column) ----------------
__global__ __launch_bounds__(256) void kb(const float* kk, const float* vv, const void* mask,
                                          float* dout){
  __shared__ u16 sKH[96*72];   // kp hi  [m-local][l], stride 72 (16B-aligned rows)
  __shared__ u16 sKL[96*72];
  __shared__ u16 sVH[80*72];   // v^T hi [d][l]; rows 64..79: ones column block (row 64 = 1)
  __shared__ u16 sVL[80*72];
  __shared__ float sred[256];
  int wg = blockIdx.x;               // 256 = 32 bh x 8 part
  int bh = wg >> 3, part = wg & 7;
  int b = bh >> 4;
  int t = threadIdx.x, wv = t >> 6, lane = t & 63, hg = lane >> 4, li = lane & 15;
  u32 w0 = *(const u32*)mask;
  int mode = (w0 == 0x01010101u) ? 0 : ((w0 == 0x3F800000u) ? 2 : 1);
  // kmax: redundant reduction over 2048 block maxes
  float bm = -1e30f;
  for (int i = 0; i < 8; ++i) bm = fmaxf(bm, dout[BMAX + t + 256 * i]);
  sred[t] = bm; __syncthreads();
  for (int s = 128; s > 0; s >>= 1){
    if (t < s) sred[t] = fmaxf(sred[t], sred[t + s]);
    __syncthreads();
  }
  float kmax = sred[0];
  // ones block rows 64..79 (row 64 = 1.0 -> ksum output at d=64)
  for (int idx = t; idx < 16*72; idx += 256){
    int r = idx / 72, c = idx % 72;
    sVH[(64 + r)*72 + c] = (r == 0) ? (u16)0x3F80 : (u16)0;
    sVL[(64 + r)*72 + c] = 0;
  }
  const u16* PH = (const u16*)(dout + PSPH);
  const u16* PL = (const u16*)(dout + PSPL);
  f32x4 acc[3][8];
  #pragma unroll
  for (int c=0;c<3;++c)
    #pragma unroll
    for (int j=0;j<8;++j){ f32x4 z = {0.f,0.f,0.f,0.f}; acc[c][j] = z; }
  for (int s8 = 0; s8 < 8; ++s8){
    int l0 = part*512 + s8*64;
    __syncthreads();                 // previous tile's GEMM reads done
    // stage v^T split (rows 0..63)
    const float4* vs4 = (const float4*)(vv + ((size_t)bh*Lc + l0)*Dc);
    #pragma unroll
    for (int p=0;p<4;++p){
      int idx = p*256 + t, row = idx >> 4, c4 = idx & 15;
      float4 u = vs4[idx];
      float kf = mget(mask, mode, b*Lc + l0 + row) ? 1.f : 0.f;
      #pragma unroll
      for (int ii=0;ii<4;++ii){
        int d = c4*4 + ii;
        float x = (&u.x)[ii] * kf;
        u16 h = f2b(x);
        sVH[d*72 + row] = h;
        sVL[d*72 + row] = f2b(x - b2f(h));
      }
    }
    // own k-row fragments + diag
    const float* krow = kk + ((size_t)bh*Lc + l0 + wv*16 + li)*Dc;
    float4 qa = *(const float4*)(krow + hg*8);
    float4 qb = *(const float4*)(krow + hg*8 + 4);
    float4 qc = *(const float4*)(krow + 32 + hg*8);
    float4 qd = *(const float4*)(krow + 32 + hg*8 + 4);
    qa.x*=NORM; qa.y*=NORM; qa.z*=NORM; qa.w*=NORM;
    qb.x*=NORM; qb.y*=NORM; qb.z*=NORM; qb.w*=NORM;
    qc.x*=NORM; qc.y*=NORM; qc.z*=NORM; qc.w*=NORM;
    qd.x*=NORM; qd.y*=NORM; qd.z*=NORM; qd.w*=NORM;
    float ssl = qa.x*qa.x+qa.y*qa.y+qa.z*qa.z+qa.w*qa.w
              + qb.x*qb.x+qb.y*qb.y+qb.z*qb.z+qb.w*qb.w
              + qc.x*qc.x+qc.y*qc.y+qc.z*qc.z+qc.w*qc.w
              + qd.x*qd.x+qd.y*qd.y+qd.z*qd.z+qd.w*qd.w;
    ssl += __shfl_xor(ssl, 16); ssl += __shfl_xor(ssl, 32);
    float dg = ssl * 0.5f;
    bf16x8 kh0,kl0,kh1,kl1;
    mkfrag(qa,qb,kh0,kl0); mkfrag(qc,qd,kh1,kl1);
    // 3 chunks of 6 m-fragments (96 m each)
    for (int ch = 0; ch < 3; ++ch){
      if (ch > 0) __syncthreads();   // previous chunk's A-reads done
      #pragma unroll
      for (int mf6 = 0; mf6 < 6; ++mf6){
        int mf = ch*6 + mf6;
        int mrow = mf*16 + li;
        bf16x8 ph0 = ldb(PH + mrow*64 + hg*8), ph1 = ldb(PH + mrow*64 + 32 + hg*8);
        bf16x8 pl0 = ldb(PL + mrow*64 + hg*8), pl1 = ldb(PL + mrow*64 + 32 + hg*8);
        f32x4 x = {0.f,0.f,0.f,0.f};
        x = mfma16(ph0, kh0, x); x = mfma16(ph1, kh1, x);
        x = mfma16(ph0, kl0, x); x = mfma16(ph1, kl1, x);
        x = mfma16(pl0, kh0, x); x = mfma16(pl1, kh1, x);
        #pragma unroll
        for (int i=0;i<4;++i){
          int m = mf*16 + hg*4 + i;
          float kp = 0.f;
          if (m < Mc){
            float arg = fminf(x[i] - dg - kmax, 8.f);
            kp = __expf(arg) + EPSc;
          }
          u16 h = f2b(kp);
          int r = mf6*16 + hg*4 + i;
          sKH[r*72 + wv*16 + li] = h;
          sKL[r*72 + wv*16 + li] = f2b(kp - b2f(h));
        }
      }
      __syncthreads();               // kp chunk (and, for ch==0, sVT) staged
      // GEMM: pairs p = wv + 4j over 6 mfl x 5 df = 30 pairs
      #pragma unroll
      for (int j = 0; j < 8; ++j){
        int p = wv + 4*j;
        if (p < 30){
          int mfl = p / 5, df = p % 5;
          const u16* ar = sKH + (mfl*16 + li)*72 + hg*8;
          const u16* al = sKL + (mfl*16 + li)*72 + hg*8;
          bf16x8 ah0 = ldb(ar), ah1 = ldb(ar + 32);
          bf16x8 al0 = ldb(al), al1 = ldb(al + 32);
          const u16* br = sVH + (df*16 + li)*72 + hg*8;
          const u16* bl = sVL + (df*16 + li)*72 + hg*8;
          bf16x8 bh0 = ldb(br), bh1 = ldb(br + 32);
          bf16x8 bl0 = ldb(bl), bl1 = ldb(bl + 32);
          f32x4 a = acc[ch][j];
          a = mfma16(ah0, bh0, a); a = mfma16(ah1, bh1, a);
          a = mfma16(ah0, bl0, a); a = mfma16(ah1, bl1, a);
          a = mfma16(al0, bh0, a); a = mfma16(al1, bh1, a);
          acc[ch][j] = a;
        }
      }
    }
  }
  // write partials: D[m = mf*16+hg*4+i][d = df*16+li]; df==4 -> ksum row (d=64, li==0 only)
  size_t pbase = ((size_t)part*32 + bh) * 18720;
  #pragma unroll
  for (int ch = 0; ch < 3; ++ch)
    #pragma unroll
    for (int j = 0; j < 8; ++j){
      int p = wv + 4*j;
      if (p < 30){
        int mfl = p / 5, df = p % 5, mf = ch*6 + mfl;
        #pragma unroll
        for (int i=0;i<4;++i){
          int m = mf*16 + hg*4 + i;
          if (df < 4) dout[pbase + (size_t)(df*16 + li)*288 + m] = acc[ch][j][i];
          else if (li == 0) dout[pbase + 18432 + m] = acc[ch][j][i];
        }
      }
    }
}

// ---------------- kc: reduce 8 partials -> stripe-packed ctx (UNCHANGED) ----------------
__global__ __launch_bounds__(256) void kc(float* dout){
  int tid = blockIdx.x * 256 + threadIdx.x;
  int bh = tid / 4680, r4 = tid % 4680;
  int p = r4 * 4, m = p % 288;
  f32x4 s = {0.f, 0.f, 0.f, 0.f};
  if (m < 272){
    for (int p8 = 0; p8 < 8; ++p8)
      s += *(const f32x4*)(dout + ((size_t)p8 * 32 + bh) * 18720 + p);
  }
  *(f32x4*)(dout + ctx_fidx(bh, p)) = s;
}

// ---------------- MFMA tile engine (UNCHANGED from R8) ----------------
DEV void tile_mfma(const float* q, const float* P, const float* dof,
                   int bh, int l0, int t,
                   float* sQp, const float* sks, float* sden,
                   f32x4 (&acc3)[4]){
  int wv = t >> 6, lane = t & 63, hg = lane >> 4, li = lane & 15;
  const float* qrow = q + ((size_t)bh * Lc + l0 + wv*16 + li) * Dc;
  float4 qa = *(const float4*)(qrow + hg*8);
  float4 qb = *(const float4*)(qrow + hg*8 + 4);
  float4 qc = *(const float4*)(qrow + 32 + hg*8);
  float4 qd = *(const float4*)(qrow + 32 + hg*8 + 4);
  qa.x*=NORM; qa.y*=NORM; qa.z*=NORM; qa.w*=NORM;
  qb.x*=NORM; qb.y*=NORM; qb.z*=NORM; qb.w*=NORM;
  qc.x*=NORM; qc.y*=NORM; qc.z*=NORM; qc.w*=NORM;
  qd.x*=NORM; qd.y*=NORM; qd.z*=NORM; qd.w*=NORM;
  float ssl = qa.x*qa.x+qa.y*qa.y+qa.z*qa.z+qa.w*qa.w
            + qb.x*qb.x+qb.y*qb.y+qb.z*qb.z+qb.w*qb.w
            + qc.x*qc.x+qc.y*qc.y+qc.z*qc.z+qc.w*qc.w
            + qd.x*qd.x+qd.y*qd.y+qd.z*qd.z+qd.w*qd.w;
  ssl += __shfl_xor(ssl, 16); ssl += __shfl_xor(ssl, 32);
  float dg = ssl * 0.5f;
  bf16x8 qh0,ql0,qh1,ql1;
  mkfrag(qa,qb,qh0,ql0); mkfrag(qc,qd,qh1,ql1);
  f32x4 dd[18];
  #pragma unroll
  for (int mf=0; mf<18; ++mf){
    int mrow = mf*16 + li;
    float4 pa,pb,pc,pd;
    if (mrow < Mc){
      const float* Pr = P + (size_t)mrow * 64;
      pa = *(const float4*)(Pr + hg*8); pb = *(const float4*)(Pr + hg*8 + 4);
      pc = *(const float4*)(Pr + 32 + hg*8); pd = *(const float4*)(Pr + 32 + hg*8 + 4);
    } else { pa = pb = pc = pd = make_float4(0.f,0.f,0.f,0.f); }
    bf16x8 ph0,pl0,ph1,pl1;
    mkfrag(pa,pb,ph0,pl0); mkfrag(pc,pd,ph1,pl1);
    f32x4 x = {0.f,0.f,0.f,0.f};
    x = mfma16(ph0, qh0, x); x = mfma16(ph1, qh1, x);
    x = mfma16(ph0, ql0, x); x = mfma16(ph1, ql1, x);
    x = mfma16(pl0, qh0, x); x = mfma16(pl1, qh1, x);
    dd[mf] = x;
  }
  float rm = -1e30f;
  #pragma unroll
  for (int mf=0; mf<18; ++mf)
    #pragma unroll
    for (int i=0;i<4;++i){
      int m = mf*16 + hg*4 + i;
      if (m < Mc) rm = fmaxf(rm, dd[mf][i]);
    }
  rm = fmaxf(rm, __shfl_xor(rm, 16));
  rm = fmaxf(rm, __shfl_xor(rm, 32));
  float den = 0.f;
  #pragma unroll
  for (int df=0; df<4; ++df){ f32x4 z = {0.f,0.f,0.f,0.f}; acc3[df] = z; }
  for (int c=0; c<3; ++c){
    __syncthreads();
    #pragma unroll
    for (int mf6=0; mf6<6; ++mf6){
      int mf = c*6 + mf6;
      #pragma unroll
      for (int i=0;i<4;++i){
        int m = mf*16 + hg*4 + i;
        float qp = 0.f;
        if (m < Mc){
          float arg = fminf(dd[mf][i] - dg - rm, 8.f);
          qp = __expf(arg) + EPSc;
          den += qp * sks[m];
        }
        sQp[(mf6*16 + hg*4 + i)*65 + wv*16 + li] = qp;
      }
    }
    __syncthreads();
    #pragma unroll
    for (int ks=0; ks<3; ++ks){
      int k0 = ks*32;
      float av[8];
      #pragma unroll
      for (int j=0;j<8;++j) av[j] = sQp[(k0 + hg*8 + j)*65 + wv*16 + li];
      union { u16 u[8]; bf16x8 v; } AH, AL;
      #pragma unroll
      for (int j=0;j<8;++j){ u16 h = f2b(av[j]); AH.u[j] = h; AL.u[j] = f2b(av[j] - b2f(h)); }
      #pragma unroll
      for (int df=0; df<4; ++df){
        size_t f = ctx_fidx(bh, (df*16 + li)*288 + c*96 + k0 + hg*8);
        float4 ca = *(const float4*)(dof + f);
        float4 cb = *(const float4*)(dof + f + 4);
        bf16x8 chv, clv;
        mkfrag(ca, cb, chv, clv);
        acc3[df] = mfma16(AH.v, chv, acc3[df]);
        acc3[df] = mfma16(AH.v, clv, acc3[df]);
        acc3[df] = mfma16(AL.v, chv, acc3[df]);
      }
    }
  }
  den += __shfl_xor(den, 16);
  den += __shfl_xor(den, 32);
  if (hg == 0) sden[wv*16 + li] = den;
  __syncthreads();
  #pragma unroll
  for (int i=0;i<4;++i){
    float dv = sden[wv*16 + hg*4 + i];
    float di = (dv > 1e-30f) ? 1.f/dv : -1.f;
    #pragma unroll
    for (int df=0; df<4; ++df){
      float o = (di > 0.f) ? acc3[df][i]*di : 3.0f;
      if (!(o == o && fabsf(o) < 1e30f)) o = 9.0f;
      acc3[df][i] = o;
    }
  }
}

// ---------------- kd: all non-scratch-overlap tiles (UNCHANGED) ----------------
__global__ __launch_bounds__(256) void kd(const float* q, const float* P, float* dout){
  __shared__ float sQp[96 * 65];
  __shared__ float sks[288];
  __shared__ float sden[64];
  int wg = blockIdx.x, bh = wg >> 6, lt = wg & 63;
  if (bh >= 16 && lt >= 54) return;
  int t = threadIdx.x, wv = t >> 6, lane = t & 63, hg = lane >> 4, li = lane & 15;
  if (t < 72) *(f32x4*)(sks + t*4) = *(const f32x4*)(dout + ctx_fidx(bh, 18432 + t*4));
  f32x4 acc3[4];
  tile_mfma(q, P, dout, bh, lt*64, t, sQp, sks, sden, acc3);
  int b = bh >> 4, hh = bh & 15;
  #pragma unroll
  for (int df=0; df<4; ++df)
    #pragma unroll
    for (int i=0;i<4;++i)
      dout[((size_t)b*Lc + lt*64 + wv*16 + hg*4 + i)*1024 + hh*64 + df*16 + li] = acc3[df][i];
}

// ---------------- ke: 16 blocks, 10 scratch-overlap tiles per b=1 head (UNCHANGED) ----------------
__global__ __launch_bounds__(256) void ke(const float* q, const float* P, float* dout){
  __shared__ float sQp[96 * 65];
  __shared__ float sks[288];
  __shared__ float sden[64];
  int hh = blockIdx.x, bh = 16 + hh;
  int t = threadIdx.x, wv = t >> 6, lane = t & 63, hg = lane >> 4, li = lane & 15;
  if (t < 72) *(f32x4*)(sks + t*4) = *(const f32x4*)(dout + ctx_fidx(bh, 18432 + t*4));
  u32 stash[80];
  #pragma unroll
  for (int ti=0; ti<10; ++ti){
    f32x4 acc3[4];
    tile_mfma(q, P, dout, bh, (54 + ti)*64, t, sQp, sks, sden, acc3);
    #pragma unroll
    for (int df=0; df<4; ++df)
      #pragma unroll
      for (int i2=0; i2<2; ++i2)
        stash[ti*8 + df*2 + i2] = (u32)f2b(acc3[df][i2*2]) | ((u32)f2b(acc3[df][i2*2+1]) << 16);
  }
  __syncthreads();
  #pragma unroll
  for (int ti=0; ti<10; ++ti)
    #pragma unroll
    for (int df=0; df<4; ++df)
      #pragma unroll
      for (int i=0;i<4;++i){
        u16 bits = (u16)(stash[ti*8 + df*2 + (i>>1)] >> ((i&1)*16));
        dout[((size_t)Lc + (54+ti)*64 + wv*16 + hg*4 + i)*1024 + hh*64 + df*16 + li] = b2f(bits);
      }
}

extern "C" void kernel_launch(void* const* d_in, const int* in_sizes, int n_in,
                              void* d_out, int out_size, void* d_ws, size_t ws_size,
                              hipStream_t stream){
  const float* q    = (const float*)d_in[0];
  const float* kk   = (const float*)d_in[1];
  const float* vv   = (const float*)d_in[2];
  const void*  mask = d_in[3];
  const float* P    = (const float*)d_in[4];
  float* dout = (float*)d_out;
  hipLaunchKernelGGL(kp0, dim3(72),   dim3(256), 0, stream, P, dout);
  hipLaunchKernelGGL(ka,  dim3(2048), dim3(256), 0, stream, kk, dout);
  hipLaunchKernelGGL(kb,  dim3(256),  dim3(256), 0, stream, kk, vv, mask, dout);
  hipLaunchKernelGGL(kc,  dim3(585),  dim3(256), 0, stream, dout);
  hipLaunchKernelGGL(kd,  dim3(2048), dim3(256), 0, stream, q, P, dout);
  hipLaunchKernelGGL(ke,  dim3(16),   dim3(256), 0, stream, q, P, dout);
}

// Round 11
// 545.002 us; speedup vs baseline: 3.2889x; 1.4204x over previous
//
#include <hip/hip_runtime.h>
#include <cstdint>

#define DEV static __device__ __forceinline__

typedef float f32x4 __attribute__((ext_vector_type(4)));
typedef __bf16 bf16x8 __attribute__((ext_vector_type(8)));
typedef unsigned short u16;
typedef unsigned int u32;

constexpr int Lc = 4096, Dc = 64, Mc = 266;
constexpr float NORM = 0.35355339059327373f;   // 64^-0.25
constexpr float EPSc = 1e-4f;

// ---- scratch DAG layout (all in d_out; d_ws unused) ----
// partial  : fidx 0..4,792,319 (b0 all + b1 rows 0..583)   W:kb R:kc1, dead at kd
// b1 tail tops    (rows 3456+64t+[0..31])  : ctx of b0 heads (stripe h), W:kc1 R:kd,kf_b0, dead at kg
//   + P-split rows 4037..4054, blockmax rows 4056..4057 (spare tops of tile 9)
// b1 tail bottoms (rows 3456+64t+[32..63]) : ctx-b1 staging W:kc1 R:kc2; then temp W:kf_b1 R:kg
// b0 tail tops    : ctx of b1 heads, W:kc2 R:kd,kf_b1, dead at kf_b0
constexpr size_t B1   = 4194304;
constexpr size_t PSPH = B1 + 4037ull*1024;   // u16[18432] = 9 rows
constexpr size_t PSPL = PSPH + 9216;         // 9 rows
constexpr size_t BMAX = B1 + 4056ull*1024;   // 2048 f32

// which: 0 = b1 tops (ctx b0-heads); 1 = b0 tops (ctx b1-heads); 2 = b1 bottoms (staging)
DEV size_t sc_fidx(int which, int h, int j){
  int tri = j >> 6, ti = tri >> 5, r = tri & 31, c = j & 63;
  size_t row = 3456 + (size_t)ti*64 + r + ((which == 2) ? 32 : 0);
  size_t base = (which == 1) ? 0 : B1;
  return base + row*1024 + (size_t)h*64 + c;
}
DEV size_t ctx_fidx(int bh, int j){ return sc_fidx(bh < 16 ? 0 : 1, bh & 15, j); }

DEV bool mget(const void* mp, int mode, int idx){
  if (mode == 0) return ((const unsigned char*)mp)[idx] != 0;
  if (mode == 1) return ((const int*)mp)[idx] != 0;
  return ((const float*)mp)[idx] != 0.f;
}
DEV u16 f2b(float f){ u32 u = __float_as_uint(f); return (u16)((u + 0x7FFFu + ((u>>16)&1u)) >> 16); }
DEV float b2f(u16 h){ return __uint_as_float(((u32)h) << 16); }
DEV f32x4 mfma16(bf16x8 a, bf16x8 b, f32x4 c){ return __builtin_amdgcn_mfma_f32_16x16x32_bf16(a, b, c, 0, 0, 0); }
DEV void mkfrag(float4 a, float4 b, bf16x8& fh, bf16x8& fl){
  union { u16 u[8]; bf16x8 v; } H, L;
  float x[8] = {a.x,a.y,a.z,a.w,b.x,b.y,b.z,b.w};
  #pragma unroll
  for (int j=0;j<8;++j){ u16 h = f2b(x[j]); H.u[j] = h; L.u[j] = f2b(x[j] - b2f(h)); }
  fh = H.v; fl = L.v;
}
DEV bf16x8 ldb(const u16* p){ return *(const bf16x8*)p; }

// ---------------- kp0: P hi/lo split table ----------------
__global__ __launch_bounds__(256) void kp0(const float* P, float* dout){
  int idx = blockIdx.x * 256 + threadIdx.x;
  if (idx >= 288 * 64) return;
  int m = idx >> 6;
  float v = (m < Mc) ? P[idx] : 0.f;
  u16 h = f2b(v);
  ((u16*)(dout + PSPH))[idx] = h;
  ((u16*)(dout + PSPL))[idx] = f2b(v - b2f(h));
}

// ---------------- ka: per-block max of dd_k -> blockmax ----------------
__global__ __launch_bounds__(256) void ka(const float* kk, float* dout){
  __shared__ float sred[4];
  int wg = blockIdx.x, bh = wg >> 6, l0 = (wg & 63) << 6, t = threadIdx.x;
  int wv = t >> 6, lane = t & 63, hg = lane >> 4, li = lane & 15;
  const u16* PH = (const u16*)(dout + PSPH);
  const u16* PL = (const u16*)(dout + PSPL);
  const float* krow = kk + ((size_t)bh * Lc + l0 + wv*16 + li) * Dc;
  float4 qa = *(const float4*)(krow + hg*8);
  float4 qb = *(const float4*)(krow + hg*8 + 4);
  float4 qc = *(const float4*)(krow + 32 + hg*8);
  float4 qd = *(const float4*)(krow + 32 + hg*8 + 4);
  qa.x*=NORM; qa.y*=NORM; qa.z*=NORM; qa.w*=NORM;
  qb.x*=NORM; qb.y*=NORM; qb.z*=NORM; qb.w*=NORM;
  qc.x*=NORM; qc.y*=NORM; qc.z*=NORM; qc.w*=NORM;
  qd.x*=NORM; qd.y*=NORM; qd.z*=NORM; qd.w*=NORM;
  bf16x8 qh0,ql0,qh1,ql1;
  mkfrag(qa,qb,qh0,ql0); mkfrag(qc,qd,qh1,ql1);
  float vmax = -1e30f;
  #pragma unroll
  for (int mf=0; mf<18; ++mf){
    int mrow = mf*16 + li;
    bf16x8 ph0 = ldb(PH + mrow*64 + hg*8), ph1 = ldb(PH + mrow*64 + 32 + hg*8);
    bf16x8 pl0 = ldb(PL + mrow*64 + hg*8), pl1 = ldb(PL + mrow*64 + 32 + hg*8);
    f32x4 x = {0.f,0.f,0.f,0.f};
    x = mfma16(ph0, qh0, x); x = mfma16(ph1, qh1, x);
    x = mfma16(ph0, ql0, x); x = mfma16(ph1, ql1, x);
    x = mfma16(pl0, qh0, x); x = mfma16(pl1, qh1, x);
    #pragma unroll
    for (int i=0;i<4;++i){
      int m = mf*16 + hg*4 + i;
      if (m < Mc) vmax = fmaxf(vmax, x[i]);
    }
  }
  vmax = fmaxf(vmax, __shfl_xor(vmax, 1));
  vmax = fmaxf(vmax, __shfl_xor(vmax, 2));
  vmax = fmaxf(vmax, __shfl_xor(vmax, 4));
  vmax = fmaxf(vmax, __shfl_xor(vmax, 8));
  vmax = fmaxf(vmax, __shfl_xor(vmax, 16));
  vmax = fmaxf(vmax, __shfl_xor(vmax, 32));
  if (lane == 0) sred[wv] = vmax;
  __syncthreads();
  if (t == 0) dout[BMAX + wg] = fmaxf(fmaxf(sred[0],sred[1]), fmaxf(sred[2],sred[3]));
}

// ---------------- kb: MFMA kp + partial ctx = kp^T.[v|1] ----------------
__global__ __launch_bounds__(256) void kb(const float* kk, const float* vv, const void* mask,
                                          float* dout){
  __shared__ u16 sKH[96*72];
  __shared__ u16 sKL[96*72];
  __shared__ u16 sVH[80*72];
  __shared__ u16 sVL[80*72];
  __shared__ float sred[256];
  int wg = blockIdx.x;
  int bh = wg >> 3, part = wg & 7;
  int b = bh >> 4;
  int t = threadIdx.x, wv = t >> 6, lane = t & 63, hg = lane >> 4, li = lane & 15;
  u32 w0 = *(const u32*)mask;
  int mode = (w0 == 0x01010101u) ? 0 : ((w0 == 0x3F800000u) ? 2 : 1);
  float bm = -1e30f;
  for (int i = 0; i < 8; ++i) bm = fmaxf(bm, dout[BMAX + t + 256 * i]);
  sred[t] = bm; __syncthreads();
  for (int s = 128; s > 0; s >>= 1){
    if (t < s) sred[t] = fmaxf(sred[t], sred[t + s]);
    __syncthreads();
  }
  float kmax = sred[0];
  for (int idx = t; idx < 16*72; idx += 256){
    int r = idx / 72, c = idx % 72;
    sVH[(64 + r)*72 + c] = (r == 0) ? (u16)0x3F80 : (u16)0;
    sVL[(64 + r)*72 + c] = 0;
  }
  const u16* PH = (const u16*)(dout + PSPH);
  const u16* PL = (const u16*)(dout + PSPL);
  f32x4 acc[3][8];
  #pragma unroll
  for (int c=0;c<3;++c)
    #pragma unroll
    for (int j=0;j<8;++j){ f32x4 z = {0.f,0.f,0.f,0.f}; acc[c][j] = z; }
  for (int s8 = 0; s8 < 8; ++s8){
    int l0 = part*512 + s8*64;
    __syncthreads();
    const float4* vs4 = (const float4*)(vv + ((size_t)bh*Lc + l0)*Dc);
    #pragma unroll
    for (int p=0;p<4;++p){
      int idx = p*256 + t, row = idx >> 4, c4 = idx & 15;
      float4 u = vs4[idx];
      float kf = mget(mask, mode, b*Lc + l0 + row) ? 1.f : 0.f;
      #pragma unroll
      for (int ii=0;ii<4;++ii){
        int d = c4*4 + ii;
        float x = (&u.x)[ii] * kf;
        u16 h = f2b(x);
        sVH[d*72 + row] = h;
        sVL[d*72 + row] = f2b(x - b2f(h));
      }
    }
    const float* krow = kk + ((size_t)bh*Lc + l0 + wv*16 + li)*Dc;
    float4 qa = *(const float4*)(krow + hg*8);
    float4 qb = *(const float4*)(krow + hg*8 + 4);
    float4 qc = *(const float4*)(krow + 32 + hg*8);
    float4 qd = *(const float4*)(krow + 32 + hg*8 + 4);
    qa.x*=NORM; qa.y*=NORM; qa.z*=NORM; qa.w*=NORM;
    qb.x*=NORM; qb.y*=NORM; qb.z*=NORM; qb.w*=NORM;
    qc.x*=NORM; qc.y*=NORM; qc.z*=NORM; qc.w*=NORM;
    qd.x*=NORM; qd.y*=NORM; qd.z*=NORM; qd.w*=NORM;
    float ssl = qa.x*qa.x+qa.y*qa.y+qa.z*qa.z+qa.w*qa.w
              + qb.x*qb.x+qb.y*qb.y+qb.z*qb.z+qb.w*qb.w
              + qc.x*qc.x+qc.y*qc.y+qc.z*qc.z+qc.w*qc.w
              + qd.x*qd.x+qd.y*qd.y+qd.z*qd.z+qd.w*qd.w;
    ssl += __shfl_xor(ssl, 16); ssl += __shfl_xor(ssl, 32);
    float dg = ssl * 0.5f;
    bf16x8 kh0,kl0,kh1,kl1;
    mkfrag(qa,qb,kh0,kl0); mkfrag(qc,qd,kh1,kl1);
    for (int ch = 0; ch < 3; ++ch){
      if (ch > 0) __syncthreads();
      #pragma unroll
      for (int mf6 = 0; mf6 < 6; ++mf6){
        int mf = ch*6 + mf6;
        int mrow = mf*16 + li;
        bf16x8 ph0 = ldb(PH + mrow*64 + hg*8), ph1 = ldb(PH + mrow*64 + 32 + hg*8);
        bf16x8 pl0 = ldb(PL + mrow*64 + hg*8), pl1 = ldb(PL + mrow*64 + 32 + hg*8);
        f32x4 x = {0.f,0.f,0.f,0.f};
        x = mfma16(ph0, kh0, x); x = mfma16(ph1, kh1, x);
        x = mfma16(ph0, kl0, x); x = mfma16(ph1, kl1, x);
        x = mfma16(pl0, kh0, x); x = mfma16(pl1, kh1, x);
        #pragma unroll
        for (int i=0;i<4;++i){
          int m = mf*16 + hg*4 + i;
          float kp = 0.f;
          if (m < Mc){
            float arg = fminf(x[i] - dg - kmax, 8.f);
            kp = __expf(arg) + EPSc;
          }
          u16 h = f2b(kp);
          int r = mf6*16 + hg*4 + i;
          sKH[r*72 + wv*16 + li] = h;
          sKL[r*72 + wv*16 + li] = f2b(kp - b2f(h));
        }
      }
      __syncthreads();
      #pragma unroll
      for (int j = 0; j < 8; ++j){
        int p = wv + 4*j;
        if (p < 30){
          int mfl = p / 5, df = p % 5;
          const u16* ar = sKH + (mfl*16 + li)*72 + hg*8;
          const u16* al = sKL + (mfl*16 + li)*72 + hg*8;
          bf16x8 ah0 = ldb(ar), ah1 = ldb(ar + 32);
          bf16x8 al0 = ldb(al), al1 = ldb(al + 32);
          const u16* br = sVH + (df*16 + li)*72 + hg*8;
          const u16* bl = sVL + (df*16 + li)*72 + hg*8;
          bf16x8 bh0 = ldb(br), bh1 = ldb(br + 32);
          bf16x8 bl0 = ldb(bl), bl1 = ldb(bl + 32);
          f32x4 a = acc[ch][j];
          a = mfma16(ah0, bh0, a); a = mfma16(ah1, bh1, a);
          a = mfma16(ah0, bl0, a); a = mfma16(ah1, bl1, a);
          a = mfma16(al0, bh0, a); a = mfma16(al1, bh1, a);
          acc[ch][j] = a;
        }
      }
    }
  }
  size_t pbase = ((size_t)part*32 + bh) * 18720;
  #pragma unroll
  for (int ch = 0; ch < 3; ++ch)
    #pragma unroll
    for (int j = 0; j < 8; ++j){
      int p = wv + 4*j;
      if (p < 30){
        int mfl = p / 5, df = p % 5, mf = ch*6 + mfl;
        #pragma unroll
        for (int i=0;i<4;++i){
          int m = mf*16 + hg*4 + i;
          if (df < 4) dout[pbase + (size_t)(df*16 + li)*288 + m] = acc[ch][j][i];
          else if (li == 0) dout[pbase + 18432 + m] = acc[ch][j][i];
        }
      }
    }
}

// ---------------- kc1: reduce partials -> ctx (b0 heads: b1 tops; b1 heads: b1 bottoms staging) ----------------
__global__ __launch_bounds__(256) void kc1(float* dout){
  int tid = blockIdx.x * 256 + threadIdx.x;   // 585*256 = 149,760 = 32*4680 exactly
  int bh = tid / 4680, r4 = tid % 4680;
  int p = r4 * 4, m = p % 288;
  f32x4 s = {0.f, 0.f, 0.f, 0.f};
  if (m < 272){
    for (int p8 = 0; p8 < 8; ++p8)
      s += *(const f32x4*)(dout + ((size_t)p8 * 32 + bh) * 18720 + p);
  }
  *(f32x4*)(dout + sc_fidx(bh < 16 ? 0 : 2, bh & 15, p)) = s;
}

// ---------------- kc2: copy ctx-b1 staging (b1 bottoms) -> b0 tops ----------------
__global__ __launch_bounds__(256) void kc2(float* dout){
  int tid = blockIdx.x * 256 + threadIdx.x;
  if (tid >= 74880) return;                   // 16 heads * 4680 f32x4
  int h = tid / 4680, j = (tid % 4680) * 4;
  f32x4 v = *(const f32x4*)(dout + sc_fidx(2, h, j));
  *(f32x4*)(dout + sc_fidx(1, h, j)) = v;
}

// ---------------- MFMA tile engine (P table + ctx stripes) ----------------
DEV void tile_mfma(const float* q, const float* dof,
                   int bh, int l0, int t,
                   float* sQp, const float* sks, float* sden,
                   f32x4 (&acc3)[4]){
  int wv = t >> 6, lane = t & 63, hg = lane >> 4, li = lane & 15;
  const u16* PH = (const u16*)(dof + PSPH);
  const u16* PL = (const u16*)(dof + PSPL);
  const float* qrow = q + ((size_t)bh * Lc + l0 + wv*16 + li) * Dc;
  float4 qa = *(const float4*)(qrow + hg*8);
  float4 qb = *(const float4*)(qrow + hg*8 + 4);
  float4 qc = *(const float4*)(qrow + 32 + hg*8);
  float4 qd = *(const float4*)(qrow + 32 + hg*8 + 4);
  qa.x*=NORM; qa.y*=NORM; qa.z*=NORM; qa.w*=NORM;
  qb.x*=NORM; qb.y*=NORM; qb.z*=NORM; qb.w*=NORM;
  qc.x*=NORM; qc.y*=NORM; qc.z*=NORM; qc.w*=NORM;
  qd.x*=NORM; qd.y*=NORM; qd.z*=NORM; qd.w*=NORM;
  float ssl = qa.x*qa.x+qa.y*qa.y+qa.z*qa.z+qa.w*qa.w
            + qb.x*qb.x+qb.y*qb.y+qb.z*qb.z+qb.w*qb.w
            + qc.x*qc.x+qc.y*qc.y+qc.z*qc.z+qc.w*qc.w
            + qd.x*qd.x+qd.y*qd.y+qd.z*qd.z+qd.w*qd.w;
  ssl += __shfl_xor(ssl, 16); ssl += __shfl_xor(ssl, 32);
  float dg = ssl * 0.5f;
  bf16x8 qh0,ql0,qh1,ql1;
  mkfrag(qa,qb,qh0,ql0); mkfrag(qc,qd,qh1,ql1);
  f32x4 dd[18];
  #pragma unroll
  for (int mf=0; mf<18; ++mf){
    int mrow = mf*16 + li;
    bf16x8 ph0 = ldb(PH + mrow*64 + hg*8), ph1 = ldb(PH + mrow*64 + 32 + hg*8);
    bf16x8 pl0 = ldb(PL + mrow*64 + hg*8), pl1 = ldb(PL + mrow*64 + 32 + hg*8);
    f32x4 x = {0.f,0.f,0.f,0.f};
    x = mfma16(ph0, qh0, x); x = mfma16(ph1, qh1, x);
    x = mfma16(ph0, ql0, x); x = mfma16(ph1, ql1, x);
    x = mfma16(pl0, qh0, x); x = mfma16(pl1, qh1, x);
    dd[mf] = x;
  }
  float rm = -1e30f;
  #pragma unroll
  for (int mf=0; mf<18; ++mf)
    #pragma unroll
    for (int i=0;i<4;++i){
      int m = mf*16 + hg*4 + i;
      if (m < Mc) rm = fmaxf(rm, dd[mf][i]);
    }
  rm = fmaxf(rm, __shfl_xor(rm, 16));
  rm = fmaxf(rm, __shfl_xor(rm, 32));
  float den = 0.f;
  #pragma unroll
  for (int df=0; df<4; ++df){ f32x4 z = {0.f,0.f,0.f,0.f}; acc3[df] = z; }
  for (int c=0; c<3; ++c){
    __syncthreads();
    #pragma unroll
    for (int mf6=0; mf6<6; ++mf6){
      int mf = c*6 + mf6;
      #pragma unroll
      for (int i=0;i<4;++i){
        int m = mf*16 + hg*4 + i;
        float qp = 0.f;
        if (m < Mc){
          float arg = fminf(dd[mf][i] - dg - rm, 8.f);
          qp = __expf(arg) + EPSc;
          den += qp * sks[m];
        }
        sQp[(mf6*16 + hg*4 + i)*65 + wv*16 + li] = qp;
      }
    }
    __syncthreads();
    #pragma unroll
    for (int ks=0; ks<3; ++ks){
      int k0 = ks*32;
      float av[8];
      #pragma unroll
      for (int j=0;j<8;++j) av[j] = sQp[(k0 + hg*8 + j)*65 + wv*16 + li];
      union { u16 u[8]; bf16x8 v; } AH, AL;
      #pragma unroll
      for (int j=0;j<8;++j){ u16 h = f2b(av[j]); AH.u[j] = h; AL.u[j] = f2b(av[j] - b2f(h)); }
      #pragma unroll
      for (int df=0; df<4; ++df){
        size_t f = ctx_fidx(bh, (df*16 + li)*288 + c*96 + k0 + hg*8);
        float4 ca = *(const float4*)(dof + f);
        float4 cb = *(const float4*)(dof + f + 4);
        bf16x8 chv, clv;
        mkfrag(ca, cb, chv, clv);
        acc3[df] = mfma16(AH.v, chv, acc3[df]);
        acc3[df] = mfma16(AH.v, clv, acc3[df]);
        acc3[df] = mfma16(AL.v, chv, acc3[df]);
      }
    }
  }
  den += __shfl_xor(den, 16);
  den += __shfl_xor(den, 32);
  if (hg == 0) sden[wv*16 + li] = den;
  __syncthreads();
  #pragma unroll
  for (int i=0;i<4;++i){
    float dv = sden[wv*16 + hg*4 + i];
    float di = (dv > 1e-30f) ? 1.f/dv : -1.f;
    #pragma unroll
    for (int df=0; df<4; ++df){
      float o = (di > 0.f) ? acc3[df][i]*di : 3.0f;
      if (!(o == o && fabsf(o) < 1e30f)) o = 9.0f;
      acc3[df][i] = o;
    }
  }
}

// ---------------- kd: all 1728 non-tail tiles ----------------
__global__ __launch_bounds__(256) void kd(const float* q, float* dout){
  __shared__ float sQp[96 * 65];
  __shared__ float sks[288];
  __shared__ float sden[64];
  int wg = blockIdx.x, bh = wg / 54, lt = wg % 54;
  int t = threadIdx.x, wv = t >> 6, lane = t & 63, hg = lane >> 4, li = lane & 15;
  if (t < 72) *(f32x4*)(sks + t*4) = *(const f32x4*)(dout + ctx_fidx(bh, 18432 + t*4));
  f32x4 acc3[4];
  tile_mfma(q, dout, bh, lt*64, t, sQp, sks, sden, acc3);
  int b = bh >> 4, hh = bh & 15;
  #pragma unroll
  for (int df=0; df<4; ++df)
    #pragma unroll
    for (int i=0;i<4;++i)
      dout[((size_t)b*Lc + lt*64 + wv*16 + hg*4 + i)*1024 + hh*64 + df*16 + li] = acc3[df][i];
}

// ---------------- kf_b1: b1 tail tiles -> bf16 temp in own tile's bottom half ----------------
__global__ __launch_bounds__(256) void kf_b1(const float* q, float* dout){
  __shared__ float sQp[96 * 65];
  __shared__ float sks[288];
  __shared__ float sden[64];
  int wg = blockIdx.x, h = wg / 10, ti = wg % 10, bh = 16 + h;
  int t = threadIdx.x, wv = t >> 6, lane = t & 63, hg = lane >> 4, li = lane & 15;
  if (t < 72) *(f32x4*)(sks + t*4) = *(const f32x4*)(dout + ctx_fidx(bh, 18432 + t*4));
  f32x4 acc3[4];
  tile_mfma(q, dout, bh, (54 + ti)*64, t, sQp, sks, sden, acc3);
  u32* tempu = (u32*)dout;
  #pragma unroll
  for (int df=0; df<4; ++df)
    #pragma unroll
    for (int i2=0; i2<2; ++i2){
      int p = wv*8 + hg*2 + i2;   // l-pair index (l = 2p, 2p+1)
      u32 u = (u32)f2b(acc3[df][i2*2]) | ((u32)f2b(acc3[df][i2*2+1]) << 16);
      tempu[B1 + (size_t)(3488 + ti*64 + p)*1024 + h*64 + df*16 + li] = u;
    }
}

// ---------------- kf_b0: b0 tail tiles -> final (reads ctx-b0 in b1 tops) ----------------
__global__ __launch_bounds__(256) void kf_b0(const float* q, float* dout){
  __shared__ float sQp[96 * 65];
  __shared__ float sks[288];
  __shared__ float sden[64];
  int wg = blockIdx.x, h = wg / 10, ti = wg % 10, bh = h;
  int t = threadIdx.x, wv = t >> 6, lane = t & 63, hg = lane >> 4, li = lane & 15;
  if (t < 72) *(f32x4*)(sks + t*4) = *(const f32x4*)(dout + ctx_fidx(bh, 18432 + t*4));
  f32x4 acc3[4];
  tile_mfma(q, dout, bh, (54 + ti)*64, t, sQp, sks, sden, acc3);
  #pragma unroll
  for (int df=0; df<4; ++df)
    #pragma unroll
    for (int i=0;i<4;++i)
      dout[((size_t)(3456 + ti*64 + wv*16 + hg*4 + i))*1024 + h*64 + df*16 + li] = acc3[df][i];
}

// ---------------- kg: per-tile temp -> final (own 64x64 footprint only) ----------------
__global__ __launch_bounds__(256) void kg(float* dout){
  int wg = blockIdx.x, h = wg / 10, ti = wg % 10;
  int t = threadIdx.x;
  const u32* tempu = (const u32*)dout;
  u32 st[8];
  #pragma unroll
  for (int i=0;i<8;++i){
    int idx = t + 256*i;            // 2048 u32: p = idx>>6, dcol = idx&63
    st[i] = tempu[B1 + (size_t)(3488 + ti*64 + (idx>>6))*1024 + h*64 + (idx & 63)];
  }
  __syncthreads();   // all temp reads complete before any final write
  #pragma unroll
  for (int i=0;i<8;++i){
    int idx = t + 256*i, p = idx >> 6, dcol = idx & 63;
    dout[B1 + (size_t)(3456 + ti*64 + 2*p)*1024 + h*64 + dcol]     = b2f((u16)(st[i] & 0xFFFF));
    dout[B1 + (size_t)(3456 + ti*64 + 2*p + 1)*1024 + h*64 + dcol] = b2f((u16)(st[i] >> 16));
  }
}

extern "C" void kernel_launch(void* const* d_in, const int* in_sizes, int n_in,
                              void* d_out, int out_size, void* d_ws, size_t ws_size,
                              hipStream_t stream){
  const float* q    = (const float*)d_in[0];
  const float* kk   = (const float*)d_in[1];
  const float* vv   = (const float*)d_in[2];
  const void*  mask = d_in[3];
  const float* P    = (const float*)d_in[4];
  float* dout = (float*)d_out;
  hipLaunchKernelGGL(kp0,   dim3(72),   dim3(256), 0, stream, P, dout);
  hipLaunchKernelGGL(ka,    dim3(2048), dim3(256), 0, stream, kk, dout);
  hipLaunchKernelGGL(kb,    dim3(256),  dim3(256), 0, stream, kk, vv, mask, dout);
  hipLaunchKernelGGL(kc1,   dim3(585),  dim3(256), 0, stream, dout);
  hipLaunchKernelGGL(kc2,   dim3(293),  dim3(256), 0, stream, dout);
  hipLaunchKernelGGL(kd,    dim3(1728), dim3(256), 0, stream, q, dout);
  hipLaunchKernelGGL(kf_b1, dim3(160),  dim3(256), 0, stream, q, dout);
  hipLaunchKernelGGL(kf_b0, dim3(160),  dim3(256), 0, stream, q, dout);
  hipLaunchKernelGGL(kg,    dim3(160),  dim3(256), 0, stream, dout);
}

// Round 12
// 497.084 us; speedup vs baseline: 3.6059x; 1.0964x over previous
//
#include <hip/hip_runtime.h>
#include <cstdint>

#define DEV static __device__ __forceinline__

typedef float f32x4 __attribute__((ext_vector_type(4)));
typedef __bf16 bf16x8 __attribute__((ext_vector_type(8)));
typedef unsigned short u16;
typedef unsigned int u32;

constexpr int Lc = 4096, Dc = 64, Mc = 266;
constexpr float NORM = 0.35355339059327373f;   // 64^-0.25
constexpr float EPSc = 1e-4f;

// ---- scratch DAG layout (all in d_out; d_ws unused) ----
// partial  : fidx 0..4,792,319 (b0 all + b1 rows 0..583)   W:kb R:kc1, dead at kd
// b1 tail tops    (rows 3456+64t+[0..31])  : ctx of b0 heads, W:kc1 R:kd,kf_b0, dead at kg
//   + P-split rows 4037..4054, blockmax rows 4056..4057
// b1 tail bottoms (rows 3456+64t+[32..63]) : ctx-b1 staging W:kc1 R:kc2; then temp W:kf_b1 R:kg
// b0 tail tops    : ctx of b1 heads, W:kc2 R:kd,kf_b1, dead at kf_b0
constexpr size_t B1   = 4194304;
constexpr size_t PSPH = B1 + 4037ull*1024;
constexpr size_t PSPL = PSPH + 9216;
constexpr size_t BMAX = B1 + 4056ull*1024;

DEV size_t sc_fidx(int which, int h, int j){
  int tri = j >> 6, ti = tri >> 5, r = tri & 31, c = j & 63;
  size_t row = 3456 + (size_t)ti*64 + r + ((which == 2) ? 32 : 0);
  size_t base = (which == 1) ? 0 : B1;
  return base + row*1024 + (size_t)h*64 + c;
}
DEV size_t ctx_fidx(int bh, int j){ return sc_fidx(bh < 16 ? 0 : 1, bh & 15, j); }

DEV bool mget(const void* mp, int mode, int idx){
  if (mode == 0) return ((const unsigned char*)mp)[idx] != 0;
  if (mode == 1) return ((const int*)mp)[idx] != 0;
  return ((const float*)mp)[idx] != 0.f;
}
DEV u16 f2b(float f){ u32 u = __float_as_uint(f); return (u16)((u + 0x7FFFu + ((u>>16)&1u)) >> 16); }
DEV float b2f(u16 h){ return __uint_as_float(((u32)h) << 16); }
DEV f32x4 mfma16(bf16x8 a, bf16x8 b, f32x4 c){ return __builtin_amdgcn_mfma_f32_16x16x32_bf16(a, b, c, 0, 0, 0); }
DEV void mkfrag(float4 a, float4 b, bf16x8& fh, bf16x8& fl){
  union { u16 u[8]; bf16x8 v; } H, L;
  float x[8] = {a.x,a.y,a.z,a.w,b.x,b.y,b.z,b.w};
  #pragma unroll
  for (int j=0;j<8;++j){ u16 h = f2b(x[j]); H.u[j] = h; L.u[j] = f2b(x[j] - b2f(h)); }
  fh = H.v; fl = L.v;
}
DEV bf16x8 ldb(const u16* p){ return *(const bf16x8*)p; }
DEV void unpackB(const u32 w[8], bf16x8& hi, bf16x8& lo){
  union { u32 u[4]; bf16x8 v; } H, L;
  #pragma unroll
  for (int jj=0;jj<4;++jj){
    u32 a = w[2*jj], b = w[2*jj+1];
    H.u[jj] = (a >> 16) | (b & 0xFFFF0000u);
    L.u[jj] = (a & 0xFFFFu) | (b << 16);
  }
  hi = H.v; lo = L.v;
}

// ---------------- kp0: P hi/lo split table ----------------
__global__ __launch_bounds__(256) void kp0(const float* P, float* dout){
  int idx = blockIdx.x * 256 + threadIdx.x;
  if (idx >= 288 * 64) return;
  int m = idx >> 6;
  float v = (m < Mc) ? P[idx] : 0.f;
  u16 h = f2b(v);
  ((u16*)(dout + PSPH))[idx] = h;
  ((u16*)(dout + PSPL))[idx] = f2b(v - b2f(h));
}

// ---------------- ka: per-block max of dd_k -> blockmax ----------------
__global__ __launch_bounds__(256) void ka(const float* kk, float* dout){
  __shared__ float sred[4];
  int wg = blockIdx.x, bh = wg >> 6, l0 = (wg & 63) << 6, t = threadIdx.x;
  int wv = t >> 6, lane = t & 63, hg = lane >> 4, li = lane & 15;
  const u16* PH = (const u16*)(dout + PSPH);
  const u16* PL = (const u16*)(dout + PSPL);
  const float* krow = kk + ((size_t)bh * Lc + l0 + wv*16 + li) * Dc;
  float4 qa = *(const float4*)(krow + hg*8);
  float4 qb = *(const float4*)(krow + hg*8 + 4);
  float4 qc = *(const float4*)(krow + 32 + hg*8);
  float4 qd = *(const float4*)(krow + 32 + hg*8 + 4);
  qa.x*=NORM; qa.y*=NORM; qa.z*=NORM; qa.w*=NORM;
  qb.x*=NORM; qb.y*=NORM; qb.z*=NORM; qb.w*=NORM;
  qc.x*=NORM; qc.y*=NORM; qc.z*=NORM; qc.w*=NORM;
  qd.x*=NORM; qd.y*=NORM; qd.z*=NORM; qd.w*=NORM;
  bf16x8 qh0,ql0,qh1,ql1;
  mkfrag(qa,qb,qh0,ql0); mkfrag(qc,qd,qh1,ql1);
  float vmax = -1e30f;
  #pragma unroll
  for (int mf=0; mf<18; ++mf){
    int mrow = mf*16 + li;
    bf16x8 ph0 = ldb(PH + mrow*64 + hg*8), ph1 = ldb(PH + mrow*64 + 32 + hg*8);
    bf16x8 pl0 = ldb(PL + mrow*64 + hg*8), pl1 = ldb(PL + mrow*64 + 32 + hg*8);
    f32x4 x = {0.f,0.f,0.f,0.f};
    x = mfma16(ph0, qh0, x); x = mfma16(ph1, qh1, x);
    x = mfma16(ph0, ql0, x); x = mfma16(ph1, ql1, x);
    x = mfma16(pl0, qh0, x); x = mfma16(pl1, qh1, x);
    #pragma unroll
    for (int i=0;i<4;++i){
      int m = mf*16 + hg*4 + i;
      if (m < Mc) vmax = fmaxf(vmax, x[i]);
    }
  }
  vmax = fmaxf(vmax, __shfl_xor(vmax, 1));
  vmax = fmaxf(vmax, __shfl_xor(vmax, 2));
  vmax = fmaxf(vmax, __shfl_xor(vmax, 4));
  vmax = fmaxf(vmax, __shfl_xor(vmax, 8));
  vmax = fmaxf(vmax, __shfl_xor(vmax, 16));
  vmax = fmaxf(vmax, __shfl_xor(vmax, 32));
  if (lane == 0) sred[wv] = vmax;
  __syncthreads();
  if (t == 0) dout[BMAX + wg] = fmaxf(fmaxf(sred[0],sred[1]), fmaxf(sred[2],sred[3]));
}

// ---------------- kb v2: m-split, packed-u32 v staging, coalesced partial writes ----------------
__global__ __launch_bounds__(256) void kb(const float* kk, const float* vv, const void* mask,
                                          float* dout){
  __shared__ __align__(16) unsigned char smem[48384];
  __shared__ float sred[256];
  u16* sKH  = (u16*)smem;               // [96][72] kp hi, [m][l]
  u16* sKL  = (u16*)(smem + 13824);     // [96][72] kp lo
  u32* sV32 = (u32*)(smem + 27648);     // [64][81] v packed (hi<<16|lo), [l][d]; col 64 = ones
  float* sT = (float*)smem;             // [65][97] post-loop alias for partial transpose
  int wg = blockIdx.x;
  int bh = wg / 24, r24 = wg % 24, part = r24 / 3, mc = r24 % 3;
  int b = bh >> 4;
  int t = threadIdx.x, wv = t >> 6, lane = t & 63, hg = lane >> 4, li = lane & 15;
  u32 w0 = *(const u32*)mask;
  int mode = (w0 == 0x01010101u) ? 0 : ((w0 == 0x3F800000u) ? 2 : 1);
  // kmax: redundant reduction over 2048 block maxes
  float bm = -1e30f;
  for (int i = 0; i < 8; ++i) bm = fmaxf(bm, dout[BMAX + t + 256 * i]);
  sred[t] = bm; __syncthreads();
  for (int s = 128; s > 0; s >>= 1){
    if (t < s) sred[t] = fmaxf(sred[t], sred[t + s]);
    __syncthreads();
  }
  float kmax = sred[0];
  // ones columns d=64..79 (col 64 = 1.0 -> ksum)
  for (int idx = t; idx < 1024; idx += 256){
    int l = idx >> 4, c = 64 + (idx & 15);
    sV32[l*81 + c] = (c == 64) ? 0x3F800000u : 0u;
  }
  const u16* PH = (const u16*)(dout + PSPH);
  const u16* PL = (const u16*)(dout + PSPL);
  f32x4 acc[8];
  #pragma unroll
  for (int j=0;j<8;++j){ f32x4 z = {0.f,0.f,0.f,0.f}; acc[j] = z; }
  for (int s8 = 0; s8 < 8; ++s8){
    int l0 = part*512 + s8*64;
    __syncthreads();                 // prev GEMM reads done
    // stage v packed [l][d], 2-way-max conflicts
    const float4* vs4 = (const float4*)(vv + ((size_t)bh*Lc + l0)*Dc);
    #pragma unroll
    for (int p=0;p<4;++p){
      int idx = p*256 + t, row = idx >> 4, c4 = idx & 15;
      float4 u = vs4[idx];
      float kf = mget(mask, mode, b*Lc + l0 + row) ? 1.f : 0.f;
      #pragma unroll
      for (int ii=0;ii<4;++ii){
        float x = (&u.x)[ii] * kf;
        u16 h = f2b(x); u16 lo = f2b(x - b2f(h));
        sV32[row*81 + c4*4 + ii] = ((u32)h << 16) | (u32)lo;
      }
    }
    // own k-row fragments + diag
    const float* krow = kk + ((size_t)bh*Lc + l0 + wv*16 + li)*Dc;
    float4 qa = *(const float4*)(krow + hg*8);
    float4 qb = *(const float4*)(krow + hg*8 + 4);
    float4 qc = *(const float4*)(krow + 32 + hg*8);
    float4 qd = *(const float4*)(krow + 32 + hg*8 + 4);
    qa.x*=NORM; qa.y*=NORM; qa.z*=NORM; qa.w*=NORM;
    qb.x*=NORM; qb.y*=NORM; qb.z*=NORM; qb.w*=NORM;
    qc.x*=NORM; qc.y*=NORM; qc.z*=NORM; qc.w*=NORM;
    qd.x*=NORM; qd.y*=NORM; qd.z*=NORM; qd.w*=NORM;
    float ssl = qa.x*qa.x+qa.y*qa.y+qa.z*qa.z+qa.w*qa.w
              + qb.x*qb.x+qb.y*qb.y+qb.z*qb.z+qb.w*qb.w
              + qc.x*qc.x+qc.y*qc.y+qc.z*qc.z+qc.w*qc.w
              + qd.x*qd.x+qd.y*qd.y+qd.z*qd.z+qd.w*qd.w;
    ssl += __shfl_xor(ssl, 16); ssl += __shfl_xor(ssl, 32);
    float dg = ssl * 0.5f;
    bf16x8 kh0,kl0,kh1,kl1;
    mkfrag(qa,qb,kh0,kl0); mkfrag(qc,qd,kh1,kl1);
    // dd for this block's 96 m + kp store
    #pragma unroll
    for (int mf6 = 0; mf6 < 6; ++mf6){
      int mf = mc*6 + mf6;
      int mrow = mf*16 + li;
      bf16x8 ph0 = ldb(PH + mrow*64 + hg*8), ph1 = ldb(PH + mrow*64 + 32 + hg*8);
      bf16x8 pl0 = ldb(PL + mrow*64 + hg*8), pl1 = ldb(PL + mrow*64 + 32 + hg*8);
      f32x4 x = {0.f,0.f,0.f,0.f};
      x = mfma16(ph0, kh0, x); x = mfma16(ph1, kh1, x);
      x = mfma16(ph0, kl0, x); x = mfma16(ph1, kl1, x);
      x = mfma16(pl0, kh0, x); x = mfma16(pl1, kh1, x);
      #pragma unroll
      for (int i=0;i<4;++i){
        int m = mf*16 + hg*4 + i;
        float kp = 0.f;
        if (m < Mc){
          float arg = fminf(x[i] - dg - kmax, 8.f);
          kp = __expf(arg) + EPSc;
        }
        u16 h = f2b(kp);
        int rr = mf6*16 + hg*4 + i;
        sKH[rr*72 + wv*16 + li] = h;
        sKL[rr*72 + wv*16 + li] = f2b(kp - b2f(h));
      }
    }
    __syncthreads();                 // staging complete
    // GEMM: 30 (mfl, df) pairs over 4 waves
    #pragma unroll
    for (int j = 0; j < 8; ++j){
      int p = wv + 4*j;
      if (p < 30){
        int mfl = p / 5, df = p % 5;
        const u16* ar = sKH + (mfl*16 + li)*72 + hg*8;
        const u16* al = sKL + (mfl*16 + li)*72 + hg*8;
        bf16x8 ah0 = ldb(ar), ah1 = ldb(ar + 32);
        bf16x8 al0 = ldb(al), al1 = ldb(al + 32);
        u32 w[8];
        bf16x8 bh0,bl0,bh1,bl1;
        #pragma unroll
        for (int jj=0;jj<8;++jj) w[jj] = sV32[(hg*8 + jj)*81 + df*16 + li];
        unpackB(w, bh0, bl0);
        #pragma unroll
        for (int jj=0;jj<8;++jj) w[jj] = sV32[(32 + hg*8 + jj)*81 + df*16 + li];
        unpackB(w, bh1, bl1);
        f32x4 a = acc[j];
        a = mfma16(ah0, bh0, a); a = mfma16(ah1, bh1, a);
        a = mfma16(ah0, bl0, a); a = mfma16(ah1, bl1, a);
        a = mfma16(al0, bh0, a); a = mfma16(al1, bh1, a);
        acc[j] = a;
      }
    }
  }
  // stage transposed [d][m-local] then write coalesced rows
  __syncthreads();
  #pragma unroll
  for (int j = 0; j < 8; ++j){
    int p = wv + 4*j;
    if (p < 30){
      int mfl = p / 5, df = p % 5;
      #pragma unroll
      for (int i=0;i<4;++i){
        int mloc = mfl*16 + hg*4 + i;
        if (df < 4) sT[(df*16 + li)*97 + mloc] = acc[j][i];
        else if (li == 0) sT[64*97 + mloc] = acc[j][i];
      }
    }
  }
  __syncthreads();
  size_t pbase = ((size_t)part*32 + bh) * 18720;
  for (int idx = t; idx < 1560; idx += 256){
    int row = idx / 24, q = idx % 24;
    float4 v4;
    v4.x = sT[row*97 + q*4];     v4.y = sT[row*97 + q*4 + 1];
    v4.z = sT[row*97 + q*4 + 2]; v4.w = sT[row*97 + q*4 + 3];
    *(float4*)(dout + pbase + (size_t)row*288 + mc*96 + q*4) = v4;
  }
}

// ---------------- kc1: reduce partials -> ctx ----------------
__global__ __launch_bounds__(256) void kc1(float* dout){
  int tid = blockIdx.x * 256 + threadIdx.x;
  int bh = tid / 4680, r4 = tid % 4680;
  int p = r4 * 4, m = p % 288;
  f32x4 s = {0.f, 0.f, 0.f, 0.f};
  if (m < 272){
    for (int p8 = 0; p8 < 8; ++p8)
      s += *(const f32x4*)(dout + ((size_t)p8 * 32 + bh) * 18720 + p);
  }
  *(f32x4*)(dout + sc_fidx(bh < 16 ? 0 : 2, bh & 15, p)) = s;
}

// ---------------- kc2: copy ctx-b1 staging -> b0 tops ----------------
__global__ __launch_bounds__(256) void kc2(float* dout){
  int tid = blockIdx.x * 256 + threadIdx.x;
  if (tid >= 74880) return;
  int h = tid / 4680, j = (tid % 4680) * 4;
  f32x4 v = *(const f32x4*)(dout + sc_fidx(2, h, j));
  *(f32x4*)(dout + sc_fidx(1, h, j)) = v;
}

// ---------------- MFMA tile engine (UNCHANGED from R11) ----------------
DEV void tile_mfma(const float* q, const float* dof,
                   int bh, int l0, int t,
                   float* sQp, const float* sks, float* sden,
                   f32x4 (&acc3)[4]){
  int wv = t >> 6, lane = t & 63, hg = lane >> 4, li = lane & 15;
  const u16* PH = (const u16*)(dof + PSPH);
  const u16* PL = (const u16*)(dof + PSPL);
  const float* qrow = q + ((size_t)bh * Lc + l0 + wv*16 + li) * Dc;
  float4 qa = *(const float4*)(qrow + hg*8);
  float4 qb = *(const float4*)(qrow + hg*8 + 4);
  float4 qc = *(const float4*)(qrow + 32 + hg*8);
  float4 qd = *(const float4*)(qrow + 32 + hg*8 + 4);
  qa.x*=NORM; qa.y*=NORM; qa.z*=NORM; qa.w*=NORM;
  qb.x*=NORM; qb.y*=NORM; qb.z*=NORM; qb.w*=NORM;
  qc.x*=NORM; qc.y*=NORM; qc.z*=NORM; qc.w*=NORM;
  qd.x*=NORM; qd.y*=NORM; qd.z*=NORM; qd.w*=NORM;
  float ssl = qa.x*qa.x+qa.y*qa.y+qa.z*qa.z+qa.w*qa.w
            + qb.x*qb.x+qb.y*qb.y+qb.z*qb.z+qb.w*qb.w
            + qc.x*qc.x+qc.y*qc.y+qc.z*qc.z+qc.w*qc.w
            + qd.x*qd.x+qd.y*qd.y+qd.z*qd.z+qd.w*qd.w;
  ssl += __shfl_xor(ssl, 16); ssl += __shfl_xor(ssl, 32);
  float dg = ssl * 0.5f;
  bf16x8 qh0,ql0,qh1,ql1;
  mkfrag(qa,qb,qh0,ql0); mkfrag(qc,qd,qh1,ql1);
  f32x4 dd[18];
  #pragma unroll
  for (int mf=0; mf<18; ++mf){
    int mrow = mf*16 + li;
    bf16x8 ph0 = ldb(PH + mrow*64 + hg*8), ph1 = ldb(PH + mrow*64 + 32 + hg*8);
    bf16x8 pl0 = ldb(PL + mrow*64 + hg*8), pl1 = ldb(PL + mrow*64 + 32 + hg*8);
    f32x4 x = {0.f,0.f,0.f,0.f};
    x = mfma16(ph0, qh0, x); x = mfma16(ph1, qh1, x);
    x = mfma16(ph0, ql0, x); x = mfma16(ph1, ql1, x);
    x = mfma16(pl0, qh0, x); x = mfma16(pl1, qh1, x);
    dd[mf] = x;
  }
  float rm = -1e30f;
  #pragma unroll
  for (int mf=0; mf<18; ++mf)
    #pragma unroll
    for (int i=0;i<4;++i){
      int m = mf*16 + hg*4 + i;
      if (m < Mc) rm = fmaxf(rm, dd[mf][i]);
    }
  rm = fmaxf(rm, __shfl_xor(rm, 16));
  rm = fmaxf(rm, __shfl_xor(rm, 32));
  float den = 0.f;
  #pragma unroll
  for (int df=0; df<4; ++df){ f32x4 z = {0.f,0.f,0.f,0.f}; acc3[df] = z; }
  for (int c=0; c<3; ++c){
    __syncthreads();
    #pragma unroll
    for (int mf6=0; mf6<6; ++mf6){
      int mf = c*6 + mf6;
      #pragma unroll
      for (int i=0;i<4;++i){
        int m = mf*16 + hg*4 + i;
        float qp = 0.f;
        if (m < Mc){
          float arg = fminf(dd[mf][i] - dg - rm, 8.f);
          qp = __expf(arg) + EPSc;
          den += qp * sks[m];
        }
        sQp[(mf6*16 + hg*4 + i)*65 + wv*16 + li] = qp;
      }
    }
    __syncthreads();
    #pragma unroll
    for (int ks=0; ks<3; ++ks){
      int k0 = ks*32;
      float av[8];
      #pragma unroll
      for (int j=0;j<8;++j) av[j] = sQp[(k0 + hg*8 + j)*65 + wv*16 + li];
      union { u16 u[8]; bf16x8 v; } AH, AL;
      #pragma unroll
      for (int j=0;j<8;++j){ u16 h = f2b(av[j]); AH.u[j] = h; AL.u[j] = f2b(av[j] - b2f(h)); }
      #pragma unroll
      for (int df=0; df<4; ++df){
        size_t f = ctx_fidx(bh, (df*16 + li)*288 + c*96 + k0 + hg*8);
        float4 ca = *(const float4*)(dof + f);
        float4 cb = *(const float4*)(dof + f + 4);
        bf16x8 chv, clv;
        mkfrag(ca, cb, chv, clv);
        acc3[df] = mfma16(AH.v, chv, acc3[df]);
        acc3[df] = mfma16(AH.v, clv, acc3[df]);
        acc3[df] = mfma16(AL.v, chv, acc3[df]);
      }
    }
  }
  den += __shfl_xor(den, 16);
  den += __shfl_xor(den, 32);
  if (hg == 0) sden[wv*16 + li] = den;
  __syncthreads();
  #pragma unroll
  for (int i=0;i<4;++i){
    float dv = sden[wv*16 + hg*4 + i];
    float di = (dv > 1e-30f) ? 1.f/dv : -1.f;
    #pragma unroll
    for (int df=0; df<4; ++df){
      float o = (di > 0.f) ? acc3[df][i]*di : 3.0f;
      if (!(o == o && fabsf(o) < 1e30f)) o = 9.0f;
      acc3[df][i] = o;
    }
  }
}

// ---------------- kd: all 1728 non-tail tiles ----------------
__global__ __launch_bounds__(256) void kd(const float* q, float* dout){
  __shared__ float sQp[96 * 65];
  __shared__ float sks[288];
  __shared__ float sden[64];
  int wg = blockIdx.x, bh = wg / 54, lt = wg % 54;
  int t = threadIdx.x, wv = t >> 6, lane = t & 63, hg = lane >> 4, li = lane & 15;
  if (t < 72) *(f32x4*)(sks + t*4) = *(const f32x4*)(dout + ctx_fidx(bh, 18432 + t*4));
  f32x4 acc3[4];
  tile_mfma(q, dout, bh, lt*64, t, sQp, sks, sden, acc3);
  int b = bh >> 4, hh = bh & 15;
  #pragma unroll
  for (int df=0; df<4; ++df)
    #pragma unroll
    for (int i=0;i<4;++i)
      dout[((size_t)b*Lc + lt*64 + wv*16 + hg*4 + i)*1024 + hh*64 + df*16 + li] = acc3[df][i];
}

// ---------------- kf_b1: b1 tail tiles -> bf16 temp ----------------
__global__ __launch_bounds__(256) void kf_b1(const float* q, float* dout){
  __shared__ float sQp[96 * 65];
  __shared__ float sks[288];
  __shared__ float sden[64];
  int wg = blockIdx.x, h = wg / 10, ti = wg % 10, bh = 16 + h;
  int t = threadIdx.x, wv = t >> 6, lane = t & 63, hg = lane >> 4, li = lane & 15;
  if (t < 72) *(f32x4*)(sks + t*4) = *(const f32x4*)(dout + ctx_fidx(bh, 18432 + t*4));
  f32x4 acc3[4];
  tile_mfma(q, dout, bh, (54 + ti)*64, t, sQp, sks, sden, acc3);
  u32* tempu = (u32*)dout;
  #pragma unroll
  for (int df=0; df<4; ++df)
    #pragma unroll
    for (int i2=0; i2<2; ++i2){
      int p = wv*8 + hg*2 + i2;
      u32 u = (u32)f2b(acc3[df][i2*2]) | ((u32)f2b(acc3[df][i2*2+1]) << 16);
      tempu[B1 + (size_t)(3488 + ti*64 + p)*1024 + h*64 + df*16 + li] = u;
    }
}

// ---------------- kf_b0: b0 tail tiles -> final ----------------
__global__ __launch_bounds__(256) void kf_b0(const float* q, float* dout){
  __shared__ float sQp[96 * 65];
  __shared__ float sks[288];
  __shared__ float sden[64];
  int wg = blockIdx.x, h = wg / 10, ti = wg % 10, bh = h;
  int t = threadIdx.x, wv = t >> 6, lane = t & 63, hg = lane >> 4, li = lane & 15;
  if (t < 72) *(f32x4*)(sks + t*4) = *(const f32x4*)(dout + ctx_fidx(bh, 18432 + t*4));
  f32x4 acc3[4];
  tile_mfma(q, dout, bh, (54 + ti)*64, t, sQp, sks, sden, acc3);
  #pragma unroll
  for (int df=0; df<4; ++df)
    #pragma unroll
    for (int i=0;i<4;++i)
      dout[((size_t)(3456 + ti*64 + wv*16 + hg*4 + i))*1024 + h*64 + df*16 + li] = acc3[df][i];
}

// ---------------- kg: per-tile temp -> final ----------------
__global__ __launch_bounds__(256) void kg(float* dout){
  int wg = blockIdx.x, h = wg / 10, ti = wg % 10;
  int t = threadIdx.x;
  const u32* tempu = (const u32*)dout;
  u32 st[8];
  #pragma unroll
  for (int i=0;i<8;++i){
    int idx = t + 256*i;
    st[i] = tempu[B1 + (size_t)(3488 + ti*64 + (idx>>6))*1024 + h*64 + (idx & 63)];
  }
  __syncthreads();
  #pragma unroll
  for (int i=0;i<8;++i){
    int idx = t + 256*i, p = idx >> 6, dcol = idx & 63;
    dout[B1 + (size_t)(3456 + ti*64 + 2*p)*1024 + h*64 + dcol]     = b2f((u16)(st[i] & 0xFFFF));
    dout[B1 + (size_t)(3456 + ti*64 + 2*p + 1)*1024 + h*64 + dcol] = b2f((u16)(st[i] >> 16));
  }
}

extern "C" void kernel_launch(void* const* d_in, const int* in_sizes, int n_in,
                              void* d_out, int out_size, void* d_ws, size_t ws_size,
                              hipStream_t stream){
  const float* q    = (const float*)d_in[0];
  const float* kk   = (const float*)d_in[1];
  const float* vv   = (const float*)d_in[2];
  const void*  mask = d_in[3];
  const float* P    = (const float*)d_in[4];
  float* dout = (float*)d_out;
  hipLaunchKernelGGL(kp0,   dim3(72),   dim3(256), 0, stream, P, dout);
  hipLaunchKernelGGL(ka,    dim3(2048), dim3(256), 0, stream, kk, dout);
  hipLaunchKernelGGL(kb,    dim3(768),  dim3(256), 0, stream, kk, vv, mask, dout);
  hipLaunchKernelGGL(kc1,   dim3(585),  dim3(256), 0, stream, dout);
  hipLaunchKernelGGL(kc2,   dim3(293),  dim3(256), 0, stream, dout);
  hipLaunchKernelGGL(kd,    dim3(1728), dim3(256), 0, stream, q, dout);
  hipLaunchKernelGGL(kf_b1, dim3(160),  dim3(256), 0, stream, q, dout);
  hipLaunchKernelGGL(kf_b0, dim3(160),  dim3(256), 0, stream, q, dout);
  hipLaunchKernelGGL(kg,    dim3(160),  dim3(256), 0, stream, dout);
}

// Round 13
// 329.301 us; speedup vs baseline: 5.4432x; 1.5095x over previous
//
#include <hip/hip_runtime.h>
#include <cstdint>

#define DEV static __device__ __forceinline__

typedef float f32x4 __attribute__((ext_vector_type(4)));
typedef __bf16 bf16x8 __attribute__((ext_vector_type(8)));
typedef unsigned short u16;
typedef unsigned int u32;

constexpr int Lc = 4096, Dc = 64, Mc = 266;
constexpr float NORM = 0.35355339059327373f;   // 64^-0.25
constexpr float EPSc = 1e-4f;

// ---- scratch DAG layout (all in d_out; d_ws unused) ----
// partial  : fidx 0..4,792,319   W:kb R:kc1, dead at kd
// b1 tail tops    : ctx of b0 heads (swizzled bf16 hi[9216 f-slots]+lo[9216]+ksum f32[288])
//   + P-split rows 4037..4054 (fragment-swizzled), blockmax rows 4056..4057
// b1 tail bottoms : ctx-b1 staging W:kc1 R:kc2; then temp W:kf_b1 R:kg
// b0 tail tops    : ctx of b1 heads, W:kc2 R:kd,kf_b1, dead at kf_b0
constexpr size_t B1   = 4194304;
constexpr size_t PSPH = B1 + 4037ull*1024;
constexpr size_t PSPL = PSPH + 9216;
constexpr size_t BMAX = B1 + 4056ull*1024;

DEV size_t sc_fidx(int which, int h, int j){
  int tri = j >> 6, ti = tri >> 5, r = tri & 31, c = j & 63;
  size_t row = 3456 + (size_t)ti*64 + r + ((which == 2) ? 32 : 0);
  size_t base = (which == 1) ? 0 : B1;
  return base + row*1024 + (size_t)h*64 + c;
}
DEV size_t ctx_fidx(int bh, int j){ return sc_fidx(bh < 16 ? 0 : 1, bh & 15, j); }

DEV bool mget(const void* mp, int mode, int idx){
  if (mode == 0) return ((const unsigned char*)mp)[idx] != 0;
  if (mode == 1) return ((const int*)mp)[idx] != 0;
  return ((const float*)mp)[idx] != 0.f;
}
DEV u16 f2b(float f){ u32 u = __float_as_uint(f); return (u16)((u + 0x7FFFu + ((u>>16)&1u)) >> 16); }
DEV float b2f(u16 h){ return __uint_as_float(((u32)h) << 16); }
DEV f32x4 mfma16(bf16x8 a, bf16x8 b, f32x4 c){ return __builtin_amdgcn_mfma_f32_16x16x32_bf16(a, b, c, 0, 0, 0); }
DEV void mkfrag(float4 a, float4 b, bf16x8& fh, bf16x8& fl){
  union { u16 u[8]; bf16x8 v; } H, L;
  float x[8] = {a.x,a.y,a.z,a.w,b.x,b.y,b.z,b.w};
  #pragma unroll
  for (int j=0;j<8;++j){ u16 h = f2b(x[j]); H.u[j] = h; L.u[j] = f2b(x[j] - b2f(h)); }
  fh = H.v; fl = L.v;
}
DEV bf16x8 ldb(const u16* p){ return *(const bf16x8*)p; }
DEV void unpackB(const u32 w[8], bf16x8& hi, bf16x8& lo){
  union { u32 u[4]; bf16x8 v; } H, L;
  #pragma unroll
  for (int jj=0;jj<4;++jj){
    u32 a = w[2*jj], b = w[2*jj+1];
    H.u[jj] = (a >> 16) | (b & 0xFFFF0000u);
    L.u[jj] = (a & 0xFFFFu) | (b << 16);
  }
  hi = H.v; lo = L.v;
}

// ---------------- kp0: P hi/lo split table, fragment-swizzled ----------------
// u16 index for (m,d): (((m>>4)*8 + (d>>3))*16 + (m&15))*8 + (d&7)
__global__ __launch_bounds__(256) void kp0(const float* P, float* dout){
  int idx = blockIdx.x * 256 + threadIdx.x;
  if (idx >= 288 * 64) return;
  int m = idx >> 6, d = idx & 63;
  float v = (m < Mc) ? P[idx] : 0.f;
  u16 h = f2b(v);
  int i2 = (((m>>4)*8 + (d>>3))*16 + (m&15))*8 + (d&7);
  ((u16*)(dout + PSPH))[i2] = h;
  ((u16*)(dout + PSPL))[i2] = f2b(v - b2f(h));
}

// ---------------- ka: per-block max of dd_k -> blockmax (coalesced P reads) ----------------
__global__ __launch_bounds__(256) void ka(const float* kk, float* dout){
  __shared__ float sred[4];
  int wg = blockIdx.x, bh = wg >> 6, l0 = (wg & 63) << 6, t = threadIdx.x;
  int wv = t >> 6, lane = t & 63, hg = lane >> 4, li = lane & 15;
  const u16* PH = (const u16*)(dout + PSPH);
  const u16* PL = (const u16*)(dout + PSPL);
  const float* krow = kk + ((size_t)bh * Lc + l0 + wv*16 + li) * Dc;
  float4 qa = *(const float4*)(krow + hg*8);
  float4 qb = *(const float4*)(krow + hg*8 + 4);
  float4 qc = *(const float4*)(krow + 32 + hg*8);
  float4 qd = *(const float4*)(krow + 32 + hg*8 + 4);
  qa.x*=NORM; qa.y*=NORM; qa.z*=NORM; qa.w*=NORM;
  qb.x*=NORM; qb.y*=NORM; qb.z*=NORM; qb.w*=NORM;
  qc.x*=NORM; qc.y*=NORM; qc.z*=NORM; qc.w*=NORM;
  qd.x*=NORM; qd.y*=NORM; qd.z*=NORM; qd.w*=NORM;
  bf16x8 qh0,ql0,qh1,ql1;
  mkfrag(qa,qb,qh0,ql0); mkfrag(qc,qd,qh1,ql1);
  float vmax = -1e30f;
  #pragma unroll
  for (int mf=0; mf<18; ++mf){
    int f0 = ((mf*8 + hg)*16 + li)*8, f1 = ((mf*8 + 4 + hg)*16 + li)*8;
    bf16x8 ph0 = ldb(PH + f0), ph1 = ldb(PH + f1);
    bf16x8 pl0 = ldb(PL + f0), pl1 = ldb(PL + f1);
    f32x4 x = {0.f,0.f,0.f,0.f};
    x = mfma16(ph0, qh0, x); x = mfma16(ph1, qh1, x);
    x = mfma16(ph0, ql0, x); x = mfma16(ph1, ql1, x);
    x = mfma16(pl0, qh0, x); x = mfma16(pl1, qh1, x);
    #pragma unroll
    for (int i=0;i<4;++i){
      int m = mf*16 + hg*4 + i;
      if (m < Mc) vmax = fmaxf(vmax, x[i]);
    }
  }
  vmax = fmaxf(vmax, __shfl_xor(vmax, 1));
  vmax = fmaxf(vmax, __shfl_xor(vmax, 2));
  vmax = fmaxf(vmax, __shfl_xor(vmax, 4));
  vmax = fmaxf(vmax, __shfl_xor(vmax, 8));
  vmax = fmaxf(vmax, __shfl_xor(vmax, 16));
  vmax = fmaxf(vmax, __shfl_xor(vmax, 32));
  if (lane == 0) sred[wv] = vmax;
  __syncthreads();
  if (t == 0) dout[BMAX + wg] = fmaxf(fmaxf(sred[0],sred[1]), fmaxf(sred[2],sred[3]));
}

// ---------------- kb: m-split MFMA kp + partial ctx (coalesced P reads) ----------------
__global__ __launch_bounds__(256) void kb(const float* kk, const float* vv, const void* mask,
                                          float* dout){
  __shared__ __align__(16) unsigned char smem[48384];
  __shared__ float sred[256];
  u16* sKH  = (u16*)smem;               // [96][72] kp hi, [m][l]
  u16* sKL  = (u16*)(smem + 13824);     // [96][72] kp lo
  u32* sV32 = (u32*)(smem + 27648);     // [64][81] v packed (hi<<16|lo), [l][d]; col 64 = ones
  float* sT = (float*)smem;             // [65][97] post-loop alias for partial transpose
  int wg = blockIdx.x;
  int bh = wg / 24, r24 = wg % 24, part = r24 / 3, mc = r24 % 3;
  int b = bh >> 4;
  int t = threadIdx.x, wv = t >> 6, lane = t & 63, hg = lane >> 4, li = lane & 15;
  u32 w0 = *(const u32*)mask;
  int mode = (w0 == 0x01010101u) ? 0 : ((w0 == 0x3F800000u) ? 2 : 1);
  float bm = -1e30f;
  for (int i = 0; i < 8; ++i) bm = fmaxf(bm, dout[BMAX + t + 256 * i]);
  sred[t] = bm; __syncthreads();
  for (int s = 128; s > 0; s >>= 1){
    if (t < s) sred[t] = fmaxf(sred[t], sred[t + s]);
    __syncthreads();
  }
  float kmax = sred[0];
  for (int idx = t; idx < 1024; idx += 256){
    int l = idx >> 4, c = 64 + (idx & 15);
    sV32[l*81 + c] = (c == 64) ? 0x3F800000u : 0u;
  }
  const u16* PH = (const u16*)(dout + PSPH);
  const u16* PL = (const u16*)(dout + PSPL);
  f32x4 acc[8];
  #pragma unroll
  for (int j=0;j<8;++j){ f32x4 z = {0.f,0.f,0.f,0.f}; acc[j] = z; }
  for (int s8 = 0; s8 < 8; ++s8){
    int l0 = part*512 + s8*64;
    __syncthreads();
    const float4* vs4 = (const float4*)(vv + ((size_t)bh*Lc + l0)*Dc);
    #pragma unroll
    for (int p=0;p<4;++p){
      int idx = p*256 + t, row = idx >> 4, c4 = idx & 15;
      float4 u = vs4[idx];
      float kf = mget(mask, mode, b*Lc + l0 + row) ? 1.f : 0.f;
      #pragma unroll
      for (int ii=0;ii<4;++ii){
        float x = (&u.x)[ii] * kf;
        u16 h = f2b(x); u16 lo = f2b(x - b2f(h));
        sV32[row*81 + c4*4 + ii] = ((u32)h << 16) | (u32)lo;
      }
    }
    const float* krow = kk + ((size_t)bh*Lc + l0 + wv*16 + li)*Dc;
    float4 qa = *(const float4*)(krow + hg*8);
    float4 qb = *(const float4*)(krow + hg*8 + 4);
    float4 qc = *(const float4*)(krow + 32 + hg*8);
    float4 qd = *(const float4*)(krow + 32 + hg*8 + 4);
    qa.x*=NORM; qa.y*=NORM; qa.z*=NORM; qa.w*=NORM;
    qb.x*=NORM; qb.y*=NORM; qb.z*=NORM; qb.w*=NORM;
    qc.x*=NORM; qc.y*=NORM; qc.z*=NORM; qc.w*=NORM;
    qd.x*=NORM; qd.y*=NORM; qd.z*=NORM; qd.w*=NORM;
    float ssl = qa.x*qa.x+qa.y*qa.y+qa.z*qa.z+qa.w*qa.w
              + qb.x*qb.x+qb.y*qb.y+qb.z*qb.z+qb.w*qb.w
              + qc.x*qc.x+qc.y*qc.y+qc.z*qc.z+qc.w*qc.w
              + qd.x*qd.x+qd.y*qd.y+qd.z*qd.z+qd.w*qd.w;
    ssl += __shfl_xor(ssl, 16); ssl += __shfl_xor(ssl, 32);
    float dg = ssl * 0.5f;
    bf16x8 kh0,kl0,kh1,kl1;
    mkfrag(qa,qb,kh0,kl0); mkfrag(qc,qd,kh1,kl1);
    #pragma unroll
    for (int mf6 = 0; mf6 < 6; ++mf6){
      int mf = mc*6 + mf6;
      int f0 = ((mf*8 + hg)*16 + li)*8, f1 = ((mf*8 + 4 + hg)*16 + li)*8;
      bf16x8 ph0 = ldb(PH + f0), ph1 = ldb(PH + f1);
      bf16x8 pl0 = ldb(PL + f0), pl1 = ldb(PL + f1);
      f32x4 x = {0.f,0.f,0.f,0.f};
      x = mfma16(ph0, kh0, x); x = mfma16(ph1, kh1, x);
      x = mfma16(ph0, kl0, x); x = mfma16(ph1, kl1, x);
      x = mfma16(pl0, kh0, x); x = mfma16(pl1, kh1, x);
      #pragma unroll
      for (int i=0;i<4;++i){
        int m = mf*16 + hg*4 + i;
        float kp = 0.f;
        if (m < Mc){
          float arg = fminf(x[i] - dg - kmax, 8.f);
          kp = __expf(arg) + EPSc;
        }
        u16 h = f2b(kp);
        int rr = mf6*16 + hg*4 + i;
        sKH[rr*72 + wv*16 + li] = h;
        sKL[rr*72 + wv*16 + li] = f2b(kp - b2f(h));
      }
    }
    __syncthreads();
    #pragma unroll
    for (int j = 0; j < 8; ++j){
      int p = wv + 4*j;
      if (p < 30){
        int mfl = p / 5, df = p % 5;
        const u16* ar = sKH + (mfl*16 + li)*72 + hg*8;
        const u16* al = sKL + (mfl*16 + li)*72 + hg*8;
        bf16x8 ah0 = ldb(ar), ah1 = ldb(ar + 32);
        bf16x8 al0 = ldb(al), al1 = ldb(al + 32);
        u32 w[8];
        bf16x8 bh0,bl0,bh1,bl1;
        #pragma unroll
        for (int jj=0;jj<8;++jj) w[jj] = sV32[(hg*8 + jj)*81 + df*16 + li];
        unpackB(w, bh0, bl0);
        #pragma unroll
        for (int jj=0;jj<8;++jj) w[jj] = sV32[(32 + hg*8 + jj)*81 + df*16 + li];
        unpackB(w, bh1, bl1);
        f32x4 a = acc[j];
        a = mfma16(ah0, bh0, a); a = mfma16(ah1, bh1, a);
        a = mfma16(ah0, bl0, a); a = mfma16(ah1, bl1, a);
        a = mfma16(al0, bh0, a); a = mfma16(al1, bh1, a);
        acc[j] = a;
      }
    }
  }
  __syncthreads();
  #pragma unroll
  for (int j = 0; j < 8; ++j){
    int p = wv + 4*j;
    if (p < 30){
      int mfl = p / 5, df = p % 5;
      #pragma unroll
      for (int i=0;i<4;++i){
        int mloc = mfl*16 + hg*4 + i;
        if (df < 4) sT[(df*16 + li)*97 + mloc] = acc[j][i];
        else if (li == 0) sT[64*97 + mloc] = acc[j][i];
      }
    }
  }
  __syncthreads();
  size_t pbase = ((size_t)part*32 + bh) * 18720;
  for (int idx = t; idx < 1560; idx += 256){
    int row = idx / 24, q = idx % 24;
    float4 v4;
    v4.x = sT[row*97 + q*4];     v4.y = sT[row*97 + q*4 + 1];
    v4.z = sT[row*97 + q*4 + 2]; v4.w = sT[row*97 + q*4 + 3];
    *(float4*)(dout + pbase + (size_t)row*288 + mc*96 + q*4) = v4;
  }
}

// ---------------- kc1: reduce partials -> swizzled bf16 ctx (+ f32 ksum) ----------------
__global__ __launch_bounds__(256) void kc1(float* dout){
  int tid = blockIdx.x * 256 + threadIdx.x;
  int bh = tid / 4680, r4 = tid % 4680;
  int p = r4 * 4;
  int d = p / 288, m = p % 288;
  int which = (bh < 16) ? 0 : 2, h = bh & 15;
  if (d == 64){
    f32x4 s = {0.f,0.f,0.f,0.f};
    for (int p8 = 0; p8 < 8; ++p8)
      s += *(const f32x4*)(dout + ((size_t)p8 * 32 + bh) * 18720 + p);
    *(f32x4*)(dout + sc_fidx(which, h, p)) = s;
    return;
  }
  f32x4 s = {0.f,0.f,0.f,0.f};
  if (m < 272){
    for (int p8 = 0; p8 < 8; ++p8)
      s += *(const f32x4*)(dout + ((size_t)p8 * 32 + bh) * 18720 + p);
  }
  int c = m/96, r = m%96, ks = r>>5, hgs = (r&31)>>3, e = m&7;
  int df = d>>4, li = d&15;
  int i2 = ((((c*3+ks)*4+df)*4+hgs)*16+li)*8 + e;
  int jH = i2 >> 1;
  u16 h0=f2b(s[0]), h1=f2b(s[1]), h2=f2b(s[2]), h3=f2b(s[3]);
  u16 l0=f2b(s[0]-b2f(h0)), l1=f2b(s[1]-b2f(h1)), l2=f2b(s[2]-b2f(h2)), l3=f2b(s[3]-b2f(h3));
  uint2 H; H.x = (u32)h0 | ((u32)h1<<16); H.y = (u32)h2 | ((u32)h3<<16);
  uint2 L; L.x = (u32)l0 | ((u32)l1<<16); L.y = (u32)l2 | ((u32)l3<<16);
  *(uint2*)(dout + sc_fidx(which, h, jH)) = H;
  *(uint2*)(dout + sc_fidx(which, h, 9216 + jH)) = L;
}

// ---------------- kc2: copy ctx-b1 staging -> b0 tops (bit copy) ----------------
__global__ __launch_bounds__(256) void kc2(float* dout){
  int tid = blockIdx.x * 256 + threadIdx.x;
  if (tid >= 74880) return;
  int h = tid / 4680, j = (tid % 4680) * 4;
  f32x4 v = *(const f32x4*)(dout + sc_fidx(2, h, j));
  *(f32x4*)(dout + sc_fidx(1, h, j)) = v;
}

// ---------------- MFMA tile engine (coalesced P + pre-split swizzled ctx) ----------------
DEV void tile_mfma(const float* q, const float* dof,
                   int bh, int l0, int t,
                   float* sQp, const float* sks, float* sden,
                   f32x4 (&acc3)[4]){
  int wv = t >> 6, lane = t & 63, hg = lane >> 4, li = lane & 15;
  const u16* PH = (const u16*)(dof + PSPH);
  const u16* PL = (const u16*)(dof + PSPL);
  const float* qrow = q + ((size_t)bh * Lc + l0 + wv*16 + li) * Dc;
  float4 qa = *(const float4*)(qrow + hg*8);
  float4 qb = *(const float4*)(qrow + hg*8 + 4);
  float4 qc = *(const float4*)(qrow + 32 + hg*8);
  float4 qd = *(const float4*)(qrow + 32 + hg*8 + 4);
  qa.x*=NORM; qa.y*=NORM; qa.z*=NORM; qa.w*=NORM;
  qb.x*=NORM; qb.y*=NORM; qb.z*=NORM; qb.w*=NORM;
  qc.x*=NORM; qc.y*=NORM; qc.z*=NORM; qc.w*=NORM;
  qd.x*=NORM; qd.y*=NORM; qd.z*=NORM; qd.w*=NORM;
  float ssl = qa.x*qa.x+qa.y*qa.y+qa.z*qa.z+qa.w*qa.w
            + qb.x*qb.x+qb.y*qb.y+qb.z*qb.z+qb.w*qb.w
            + qc.x*qc.x+qc.y*qc.y+qc.z*qc.z+qc.w*qc.w
            + qd.x*qd.x+qd.y*qd.y+qd.z*qd.z+qd.w*qd.w;
  ssl += __shfl_xor(ssl, 16); ssl += __shfl_xor(ssl, 32);
  float dg = ssl * 0.5f;
  bf16x8 qh0,ql0,qh1,ql1;
  mkfrag(qa,qb,qh0,ql0); mkfrag(qc,qd,qh1,ql1);
  f32x4 dd[18];
  #pragma unroll
  for (int mf=0; mf<18; ++mf){
    int f0 = ((mf*8 + hg)*16 + li)*8, f1 = ((mf*8 + 4 + hg)*16 + li)*8;
    bf16x8 ph0 = ldb(PH + f0), ph1 = ldb(PH + f1);
    bf16x8 pl0 = ldb(PL + f0), pl1 = ldb(PL + f1);
    f32x4 x = {0.f,0.f,0.f,0.f};
    x = mfma16(ph0, qh0, x); x = mfma16(ph1, qh1, x);
    x = mfma16(ph0, ql0, x); x = mfma16(ph1, ql1, x);
    x = mfma16(pl0, qh0, x); x = mfma16(pl1, qh1, x);
    dd[mf] = x;
  }
  float rm = -1e30f;
  #pragma unroll
  for (int mf=0; mf<18; ++mf)
    #pragma unroll
    for (int i=0;i<4;++i){
      int m = mf*16 + hg*4 + i;
      if (m < Mc) rm = fmaxf(rm, dd[mf][i]);
    }
  rm = fmaxf(rm, __shfl_xor(rm, 16));
  rm = fmaxf(rm, __shfl_xor(rm, 32));
  float den = 0.f;
  #pragma unroll
  for (int df=0; df<4; ++df){ f32x4 z = {0.f,0.f,0.f,0.f}; acc3[df] = z; }
  for (int c=0; c<3; ++c){
    __syncthreads();
    #pragma unroll
    for (int mf6=0; mf6<6; ++mf6){
      int mf = c*6 + mf6;
      #pragma unroll
      for (int i=0;i<4;++i){
        int m = mf*16 + hg*4 + i;
        float qp = 0.f;
        if (m < Mc){
          float arg = fminf(dd[mf][i] - dg - rm, 8.f);
          qp = __expf(arg) + EPSc;
          den += qp * sks[m];
        }
        sQp[(mf6*16 + hg*4 + i)*66 + wv*16 + li] = qp;
      }
    }
    __syncthreads();
    #pragma unroll
    for (int ks=0; ks<3; ++ks){
      int k0 = ks*32;
      float av[8];
      #pragma unroll
      for (int j=0;j<8;++j) av[j] = sQp[(k0 + hg*8 + j)*66 + wv*16 + li];
      union { u16 u[8]; bf16x8 v; } AH, AL;
      #pragma unroll
      for (int j=0;j<8;++j){ u16 h = f2b(av[j]); AH.u[j] = h; AL.u[j] = f2b(av[j] - b2f(h)); }
      #pragma unroll
      for (int df=0; df<4; ++df){
        int jf = ((((c*3+ks)*4+df)*4+hg)*16+li)*4;
        bf16x8 chv = ldb((const u16*)(dof + ctx_fidx(bh, jf)));
        bf16x8 clv = ldb((const u16*)(dof + ctx_fidx(bh, 9216 + jf)));
        acc3[df] = mfma16(AH.v, chv, acc3[df]);
        acc3[df] = mfma16(AH.v, clv, acc3[df]);
        acc3[df] = mfma16(AL.v, chv, acc3[df]);
      }
    }
  }
  den += __shfl_xor(den, 16);
  den += __shfl_xor(den, 32);
  if (hg == 0) sden[wv*16 + li] = den;
  __syncthreads();
  #pragma unroll
  for (int i=0;i<4;++i){
    float dv = sden[wv*16 + hg*4 + i];
    float di = (dv > 1e-30f) ? 1.f/dv : -1.f;
    #pragma unroll
    for (int df=0; df<4; ++df){
      float o = (di > 0.f) ? acc3[df][i]*di : 3.0f;
      if (!(o == o && fabsf(o) < 1e30f)) o = 9.0f;
      acc3[df][i] = o;
    }
  }
}

// ---------------- kd: all 1728 non-tail tiles ----------------
__global__ __launch_bounds__(256) void kd(const float* q, float* dout){
  __shared__ float sQp[96 * 66];
  __shared__ float sks[288];
  __shared__ float sden[64];
  int wg = blockIdx.x, bh = wg / 54, lt = wg % 54;
  int t = threadIdx.x, wv = t >> 6, lane = t & 63, hg = lane >> 4, li = lane & 15;
  if (t < 72) *(f32x4*)(sks + t*4) = *(const f32x4*)(dout + ctx_fidx(bh, 18432 + t*4));
  f32x4 acc3[4];
  tile_mfma(q, dout, bh, lt*64, t, sQp, sks, sden, acc3);
  int b = bh >> 4, hh = bh & 15;
  #pragma unroll
  for (int df=0; df<4; ++df)
    #pragma unroll
    for (int i=0;i<4;++i)
      dout[((size_t)b*Lc + lt*64 + wv*16 + hg*4 + i)*1024 + hh*64 + df*16 + li] = acc3[df][i];
}

// ---------------- kf_b1: b1 tail tiles -> bf16 temp ----------------
__global__ __launch_bounds__(256) void kf_b1(const float* q, float* dout){
  __shared__ float sQp[96 * 66];
  __shared__ float sks[288];
  __shared__ float sden[64];
  int wg = blockIdx.x, h = wg / 10, ti = wg % 10, bh = 16 + h;
  int t = threadIdx.x, wv = t >> 6, lane = t & 63, hg = lane >> 4, li = lane & 15;
  if (t < 72) *(f32x4*)(sks + t*4) = *(const f32x4*)(dout + ctx_fidx(bh, 18432 + t*4));
  f32x4 acc3[4];
  tile_mfma(q, dout, bh, (54 + ti)*64, t, sQp, sks, sden, acc3);
  u32* tempu = (u32*)dout;
  #pragma unroll
  for (int df=0; df<4; ++df)
    #pragma unroll
    for (int i2=0; i2<2; ++i2){
      int p = wv*8 + hg*2 + i2;
      u32 u = (u32)f2b(acc3[df][i2*2]) | ((u32)f2b(acc3[df][i2*2+1]) << 16);
      tempu[B1 + (size_t)(3488 + ti*64 + p)*1024 + h*64 + df*16 + li] = u;
    }
}

// ---------------- kf_b0: b0 tail tiles -> final ----------------
__global__ __launch_bounds__(256) void kf_b0(const float* q, float* dout){
  __shared__ float sQp[96 * 66];
  __shared__ float sks[288];
  __shared__ float sden[64];
  int wg = blockIdx.x, h = wg / 10, ti = wg % 10, bh = h;
  int t = threadIdx.x, wv = t >> 6, lane = t & 63, hg = lane >> 4, li = lane & 15;
  if (t < 72) *(f32x4*)(sks + t*4) = *(const f32x4*)(dout + ctx_fidx(bh, 18432 + t*4));
  f32x4 acc3[4];
  tile_mfma(q, dout, bh, (54 + ti)*64, t, sQp, sks, sden, acc3);
  #pragma unroll
  for (int df=0; df<4; ++df)
    #pragma unroll
    for (int i=0;i<4;++i)
      dout[((size_t)(3456 + ti*64 + wv*16 + hg*4 + i))*1024 + h*64 + df*16 + li] = acc3[df][i];
}

// ---------------- kg: per-tile temp -> final ----------------
__global__ __launch_bounds__(256) void kg(float* dout){
  int wg = blockIdx.x, h = wg / 10, ti = wg % 10;
  int t = threadIdx.x;
  const u32* tempu = (const u32*)dout;
  u32 st[8];
  #pragma unroll
  for (int i=0;i<8;++i){
    int idx = t + 256*i;
    st[i] = tempu[B1 + (size_t)(3488 + ti*64 + (idx>>6))*1024 + h*64 + (idx & 63)];
  }
  __syncthreads();
  #pragma unroll
  for (int i=0;i<8;++i){
    int idx = t + 256*i, p = idx >> 6, dcol = idx & 63;
    dout[B1 + (size_t)(3456 + ti*64 + 2*p)*1024 + h*64 + dcol]     = b2f((u16)(st[i] & 0xFFFF));
    dout[B1 + (size_t)(3456 + ti*64 + 2*p + 1)*1024 + h*64 + dcol] = b2f((u16)(st[i] >> 16));
  }
}

extern "C" void kernel_launch(void* const* d_in, const int* in_sizes, int n_in,
                              void* d_out, int out_size, void* d_ws, size_t ws_size,
                              hipStream_t stream){
  const float* q    = (const float*)d_in[0];
  const float* kk   = (const float*)d_in[1];
  const float* vv   = (const float*)d_in[2];
  const void*  mask = d_in[3];
  const float* P    = (const float*)d_in[4];
  float* dout = (float*)d_out;
  hipLaunchKernelGGL(kp0,   dim3(72),   dim3(256), 0, stream, P, dout);
  hipLaunchKernelGGL(ka,    dim3(2048), dim3(256), 0, stream, kk, dout);
  hipLaunchKernelGGL(kb,    dim3(768),  dim3(256), 0, stream, kk, vv, mask, dout);
  hipLaunchKernelGGL(kc1,   dim3(585),  dim3(256), 0, stream, dout);
  hipLaunchKernelGGL(kc2,   dim3(293),  dim3(256), 0, stream, dout);
  hipLaunchKernelGGL(kd,    dim3(1728), dim3(256), 0, stream, q, dout);
  hipLaunchKernelGGL(kf_b1, dim3(160),  dim3(256), 0, stream, q, dout);
  hipLaunchKernelGGL(kf_b0, dim3(160),  dim3(256), 0, stream, q, dout);
  hipLaunchKernelGGL(kg,    dim3(160),  dim3(256), 0, stream, dout);
}

// Round 14
// 286.688 us; speedup vs baseline: 6.2523x; 1.1486x over previous
//
#include <hip/hip_runtime.h>
#include <cstdint>

#define DEV static __device__ __forceinline__

typedef float f32x4 __attribute__((ext_vector_type(4)));
typedef __bf16 bf16x8 __attribute__((ext_vector_type(8)));
typedef unsigned short u16;
typedef unsigned int u32;

constexpr int Lc = 4096, Dc = 64, Mc = 266;
constexpr float NORM = 0.35355339059327373f;   // 64^-0.25
constexpr float EPSc = 1e-4f;

// ---- scratch DAG layout (all in d_out; d_ws unused) ----
// partial  : fidx 0..4,792,319   W:kb R:kc1, dead at kd
// b1 tail tops    : ctx of b0 heads (swizzled bf16 hi[9216 f-slots]+lo[9216]+ksum f32[288])
//   + P-split rows 4037..4054 (fragment-swizzled), blockmax rows 4056..4057
// b1 tail bottoms : ctx-b1 staging W:kc1 R:kc2; then temp W:kf_b1 R:kg
// b0 tail tops    : ctx of b1 heads, W:kc2 R:kd,kf_b1, dead at kf_b0
constexpr size_t B1   = 4194304;
constexpr size_t PSPH = B1 + 4037ull*1024;
constexpr size_t PSPL = PSPH + 9216;
constexpr size_t BMAX = B1 + 4056ull*1024;

DEV size_t sc_fidx(int which, int h, int j){
  int tri = j >> 6, ti = tri >> 5, r = tri & 31, c = j & 63;
  size_t row = 3456 + (size_t)ti*64 + r + ((which == 2) ? 32 : 0);
  size_t base = (which == 1) ? 0 : B1;
  return base + row*1024 + (size_t)h*64 + c;
}
DEV size_t ctx_fidx(int bh, int j){ return sc_fidx(bh < 16 ? 0 : 1, bh & 15, j); }

DEV bool mget(const void* mp, int mode, int idx){
  if (mode == 0) return ((const unsigned char*)mp)[idx] != 0;
  if (mode == 1) return ((const int*)mp)[idx] != 0;
  return ((const float*)mp)[idx] != 0.f;
}
DEV u16 f2b(float f){ u32 u = __float_as_uint(f); return (u16)((u + 0x7FFFu + ((u>>16)&1u)) >> 16); }
DEV float b2f(u16 h){ return __uint_as_float(((u32)h) << 16); }
DEV f32x4 mfma16(bf16x8 a, bf16x8 b, f32x4 c){ return __builtin_amdgcn_mfma_f32_16x16x32_bf16(a, b, c, 0, 0, 0); }
DEV void mkfrag(float4 a, float4 b, bf16x8& fh, bf16x8& fl){
  union { u16 u[8]; bf16x8 v; } H, L;
  float x[8] = {a.x,a.y,a.z,a.w,b.x,b.y,b.z,b.w};
  #pragma unroll
  for (int j=0;j<8;++j){ u16 h = f2b(x[j]); H.u[j] = h; L.u[j] = f2b(x[j] - b2f(h)); }
  fh = H.v; fl = L.v;
}
DEV bf16x8 ldb(const u16* p){ return *(const bf16x8*)p; }

// ---------------- kp0: P hi/lo split table, fragment-swizzled ----------------
__global__ __launch_bounds__(256) void kp0(const float* P, float* dout){
  int idx = blockIdx.x * 256 + threadIdx.x;
  if (idx >= 288 * 64) return;
  int m = idx >> 6, d = idx & 63;
  float v = (m < Mc) ? P[idx] : 0.f;
  u16 h = f2b(v);
  int i2 = (((m>>4)*8 + (d>>3))*16 + (m&15))*8 + (d&7);
  ((u16*)(dout + PSPH))[i2] = h;
  ((u16*)(dout + PSPL))[i2] = f2b(v - b2f(h));
}

// ---------------- ka: per-block max of dd_k -> blockmax ----------------
__global__ __launch_bounds__(256) void ka(const float* kk, float* dout){
  __shared__ float sred[4];
  int wg = blockIdx.x, bh = wg >> 6, l0 = (wg & 63) << 6, t = threadIdx.x;
  int wv = t >> 6, lane = t & 63, hg = lane >> 4, li = lane & 15;
  const u16* PH = (const u16*)(dout + PSPH);
  const u16* PL = (const u16*)(dout + PSPL);
  const float* krow = kk + ((size_t)bh * Lc + l0 + wv*16 + li) * Dc;
  float4 qa = *(const float4*)(krow + hg*8);
  float4 qb = *(const float4*)(krow + hg*8 + 4);
  float4 qc = *(const float4*)(krow + 32 + hg*8);
  float4 qd = *(const float4*)(krow + 32 + hg*8 + 4);
  qa.x*=NORM; qa.y*=NORM; qa.z*=NORM; qa.w*=NORM;
  qb.x*=NORM; qb.y*=NORM; qb.z*=NORM; qb.w*=NORM;
  qc.x*=NORM; qc.y*=NORM; qc.z*=NORM; qc.w*=NORM;
  qd.x*=NORM; qd.y*=NORM; qd.z*=NORM; qd.w*=NORM;
  bf16x8 qh0,ql0,qh1,ql1;
  mkfrag(qa,qb,qh0,ql0); mkfrag(qc,qd,qh1,ql1);
  float vmax = -1e30f;
  #pragma unroll
  for (int mf=0; mf<18; ++mf){
    int f0 = ((mf*8 + hg)*16 + li)*8, f1 = ((mf*8 + 4 + hg)*16 + li)*8;
    bf16x8 ph0 = ldb(PH + f0), ph1 = ldb(PH + f1);
    bf16x8 pl0 = ldb(PL + f0), pl1 = ldb(PL + f1);
    f32x4 x = {0.f,0.f,0.f,0.f};
    x = mfma16(ph0, qh0, x); x = mfma16(ph1, qh1, x);
    x = mfma16(ph0, ql0, x); x = mfma16(ph1, ql1, x);
    x = mfma16(pl0, qh0, x); x = mfma16(pl1, qh1, x);
    #pragma unroll
    for (int i=0;i<4;++i){
      int m = mf*16 + hg*4 + i;
      if (m < Mc) vmax = fmaxf(vmax, x[i]);
    }
  }
  vmax = fmaxf(vmax, __shfl_xor(vmax, 1));
  vmax = fmaxf(vmax, __shfl_xor(vmax, 2));
  vmax = fmaxf(vmax, __shfl_xor(vmax, 4));
  vmax = fmaxf(vmax, __shfl_xor(vmax, 8));
  vmax = fmaxf(vmax, __shfl_xor(vmax, 16));
  vmax = fmaxf(vmax, __shfl_xor(vmax, 32));
  if (lane == 0) sred[wv] = vmax;
  __syncthreads();
  if (t == 0) dout[BMAX + wg] = fmaxf(fmaxf(sred[0],sred[1]), fmaxf(sred[2],sred[3]));
}

// ---------------- kb v3: 6-way m-split (48 m), v hi-only, 6 blocks/CU ----------------
__global__ __launch_bounds__(256) void kb(const float* kk, const float* vv, const void* mask,
                                          float* dout){
  __shared__ __align__(16) unsigned char smem[25344];
  __shared__ float sred[256];
  u16* sKH = (u16*)smem;                // [48][72] kp hi, [m][l]
  u16* sKL = (u16*)(smem + 6912);       // [48][72] kp lo
  u16* sVH = (u16*)(smem + 13824);      // [80][72] v hi, [d][l]; row 64 = ones
  float* sT = (float*)smem;             // [65][49] post-loop alias
  int wg = blockIdx.x;                  // 1536 = 32 bh x 8 part x 6 mc
  int bh = wg / 48, r48 = wg % 48, part = r48 / 6, mc = r48 % 6;
  int b = bh >> 4;
  int t = threadIdx.x, wv = t >> 6, lane = t & 63, hg = lane >> 4, li = lane & 15;
  u32 w0 = *(const u32*)mask;
  int mode = (w0 == 0x01010101u) ? 0 : ((w0 == 0x3F800000u) ? 2 : 1);
  float bm = -1e30f;
  for (int i = 0; i < 8; ++i) bm = fmaxf(bm, dout[BMAX + t + 256 * i]);
  sred[t] = bm; __syncthreads();
  for (int s = 128; s > 0; s >>= 1){
    if (t < s) sred[t] = fmaxf(sred[t], sred[t + s]);
    __syncthreads();
  }
  float kmax = sred[0];
  // ones rows d=64..79 (row 64 = 1.0 -> ksum); never overwritten by staging (d<64)
  for (int idx = t; idx < 16*72; idx += 256){
    int r = idx / 72, c = idx % 72;
    sVH[(64 + r)*72 + c] = (r == 0) ? (u16)0x3F80 : (u16)0;
  }
  const u16* PH = (const u16*)(dout + PSPH);
  const u16* PL = (const u16*)(dout + PSPL);
  f32x4 acc[4];
  #pragma unroll
  for (int j=0;j<4;++j){ f32x4 z = {0.f,0.f,0.f,0.f}; acc[j] = z; }
  for (int s8 = 0; s8 < 8; ++s8){
    int l0 = part*512 + s8*64;
    __syncthreads();
    // stage v hi-only [d][l]
    const float4* vs4 = (const float4*)(vv + ((size_t)bh*Lc + l0)*Dc);
    #pragma unroll
    for (int p=0;p<4;++p){
      int idx = p*256 + t, row = idx >> 4, c4 = idx & 15;
      float4 u = vs4[idx];
      float kf = mget(mask, mode, b*Lc + l0 + row) ? 1.f : 0.f;
      #pragma unroll
      for (int ii=0;ii<4;++ii){
        int d = c4*4 + ii;
        sVH[d*72 + row] = f2b((&u.x)[ii] * kf);
      }
    }
    // own k-row fragments + diag
    const float* krow = kk + ((size_t)bh*Lc + l0 + wv*16 + li)*Dc;
    float4 qa = *(const float4*)(krow + hg*8);
    float4 qb = *(const float4*)(krow + hg*8 + 4);
    float4 qc = *(const float4*)(krow + 32 + hg*8);
    float4 qd = *(const float4*)(krow + 32 + hg*8 + 4);
    qa.x*=NORM; qa.y*=NORM; qa.z*=NORM; qa.w*=NORM;
    qb.x*=NORM; qb.y*=NORM; qb.z*=NORM; qb.w*=NORM;
    qc.x*=NORM; qc.y*=NORM; qc.z*=NORM; qc.w*=NORM;
    qd.x*=NORM; qd.y*=NORM; qd.z*=NORM; qd.w*=NORM;
    float ssl = qa.x*qa.x+qa.y*qa.y+qa.z*qa.z+qa.w*qa.w
              + qb.x*qb.x+qb.y*qb.y+qb.z*qb.z+qb.w*qb.w
              + qc.x*qc.x+qc.y*qc.y+qc.z*qc.z+qc.w*qc.w
              + qd.x*qd.x+qd.y*qd.y+qd.z*qd.z+qd.w*qd.w;
    ssl += __shfl_xor(ssl, 16); ssl += __shfl_xor(ssl, 32);
    float dg = ssl * 0.5f;
    bf16x8 kh0,kl0,kh1,kl1;
    mkfrag(qa,qb,kh0,kl0); mkfrag(qc,qd,kh1,kl1);
    // dd for this block's 48 m + kp store (full 3-term split for precision)
    #pragma unroll
    for (int mf3 = 0; mf3 < 3; ++mf3){
      int mf = mc*3 + mf3;
      int f0 = ((mf*8 + hg)*16 + li)*8, f1 = ((mf*8 + 4 + hg)*16 + li)*8;
      bf16x8 ph0 = ldb(PH + f0), ph1 = ldb(PH + f1);
      bf16x8 pl0 = ldb(PL + f0), pl1 = ldb(PL + f1);
      f32x4 x = {0.f,0.f,0.f,0.f};
      x = mfma16(ph0, kh0, x); x = mfma16(ph1, kh1, x);
      x = mfma16(ph0, kl0, x); x = mfma16(ph1, kl1, x);
      x = mfma16(pl0, kh0, x); x = mfma16(pl1, kh1, x);
      #pragma unroll
      for (int i=0;i<4;++i){
        int m = mf*16 + hg*4 + i;
        float kp = 0.f;
        if (m < Mc){
          float arg = fminf(x[i] - dg - kmax, 8.f);
          kp = __expf(arg) + EPSc;
        }
        u16 h = f2b(kp);
        int rr = mf3*16 + hg*4 + i;
        sKH[rr*72 + wv*16 + li] = h;
        sKL[rr*72 + wv*16 + li] = f2b(kp - b2f(h));
      }
    }
    __syncthreads();
    // GEMM: 15 (mfl, df) pairs over 4 waves, 4 MFMA each (kp hi+lo x v hi)
    #pragma unroll
    for (int j = 0; j < 4; ++j){
      int p = wv + 4*j;
      if (p < 15){
        int mfl = p / 5, df = p % 5;
        const u16* ar = sKH + (mfl*16 + li)*72 + hg*8;
        const u16* al = sKL + (mfl*16 + li)*72 + hg*8;
        bf16x8 ah0 = ldb(ar), ah1 = ldb(ar + 32);
        bf16x8 al0 = ldb(al), al1 = ldb(al + 32);
        const u16* br = sVH + (df*16 + li)*72 + hg*8;
        bf16x8 bh0 = ldb(br), bh1 = ldb(br + 32);
        f32x4 a = acc[j];
        a = mfma16(ah0, bh0, a); a = mfma16(ah1, bh1, a);
        a = mfma16(al0, bh0, a); a = mfma16(al1, bh1, a);
        acc[j] = a;
      }
    }
  }
  // transpose via LDS then coalesced partial write
  __syncthreads();
  #pragma unroll
  for (int j = 0; j < 4; ++j){
    int p = wv + 4*j;
    if (p < 15){
      int mfl = p / 5, df = p % 5;
      #pragma unroll
      for (int i=0;i<4;++i){
        int mloc = mfl*16 + hg*4 + i;
        if (df < 4) sT[(df*16 + li)*49 + mloc] = acc[j][i];
        else if (li == 0) sT[64*49 + mloc] = acc[j][i];
      }
    }
  }
  __syncthreads();
  size_t pbase = ((size_t)part*32 + bh) * 18720;
  for (int idx = t; idx < 780; idx += 256){
    int row = idx / 12, qq = idx % 12;
    float4 v4;
    v4.x = sT[row*49 + qq*4];     v4.y = sT[row*49 + qq*4 + 1];
    v4.z = sT[row*49 + qq*4 + 2]; v4.w = sT[row*49 + qq*4 + 3];
    *(float4*)(dout + pbase + (size_t)row*288 + mc*48 + qq*4) = v4;
  }
}

// ---------------- kc1: reduce partials -> swizzled bf16 ctx (+ f32 ksum) ----------------
__global__ __launch_bounds__(256) void kc1(float* dout){
  int tid = blockIdx.x * 256 + threadIdx.x;
  int bh = tid / 4680, r4 = tid % 4680;
  int p = r4 * 4;
  int d = p / 288, m = p % 288;
  int which = (bh < 16) ? 0 : 2, h = bh & 15;
  if (d == 64){
    f32x4 s = {0.f,0.f,0.f,0.f};
    for (int p8 = 0; p8 < 8; ++p8)
      s += *(const f32x4*)(dout + ((size_t)p8 * 32 + bh) * 18720 + p);
    *(f32x4*)(dout + sc_fidx(which, h, p)) = s;
    return;
  }
  f32x4 s = {0.f,0.f,0.f,0.f};
  if (m < 272){
    for (int p8 = 0; p8 < 8; ++p8)
      s += *(const f32x4*)(dout + ((size_t)p8 * 32 + bh) * 18720 + p);
  }
  int c = m/96, r = m%96, ks = r>>5, hgs = (r&31)>>3, e = m&7;
  int df = d>>4, li = d&15;
  int i2 = ((((c*3+ks)*4+df)*4+hgs)*16+li)*8 + e;
  int jH = i2 >> 1;
  u16 h0=f2b(s[0]), h1=f2b(s[1]), h2=f2b(s[2]), h3=f2b(s[3]);
  u16 l0=f2b(s[0]-b2f(h0)), l1=f2b(s[1]-b2f(h1)), l2=f2b(s[2]-b2f(h2)), l3=f2b(s[3]-b2f(h3));
  uint2 H; H.x = (u32)h0 | ((u32)h1<<16); H.y = (u32)h2 | ((u32)h3<<16);
  uint2 L; L.x = (u32)l0 | ((u32)l1<<16); L.y = (u32)l2 | ((u32)l3<<16);
  *(uint2*)(dout + sc_fidx(which, h, jH)) = H;
  *(uint2*)(dout + sc_fidx(which, h, 9216 + jH)) = L;
}

// ---------------- kc2: copy ctx-b1 staging -> b0 tops (bit copy) ----------------
__global__ __launch_bounds__(256) void kc2(float* dout){
  int tid = blockIdx.x * 256 + threadIdx.x;
  if (tid >= 74880) return;
  int h = tid / 4680, j = (tid % 4680) * 4;
  f32x4 v = *(const f32x4*)(dout + sc_fidx(2, h, j));
  *(f32x4*)(dout + sc_fidx(1, h, j)) = v;
}

// ---------------- MFMA tile engine (coalesced P + pre-split swizzled ctx) ----------------
DEV void tile_mfma(const float* q, const float* dof,
                   int bh, int l0, int t,
                   float* sQp, const float* sks, float* sden,
                   f32x4 (&acc3)[4]){
  int wv = t >> 6, lane = t & 63, hg = lane >> 4, li = lane & 15;
  const u16* PH = (const u16*)(dof + PSPH);
  const u16* PL = (const u16*)(dof + PSPL);
  const float* qrow = q + ((size_t)bh * Lc + l0 + wv*16 + li) * Dc;
  float4 qa = *(const float4*)(qrow + hg*8);
  float4 qb = *(const float4*)(qrow + hg*8 + 4);
  float4 qc = *(const float4*)(qrow + 32 + hg*8);
  float4 qd = *(const float4*)(qrow + 32 + hg*8 + 4);
  qa.x*=NORM; qa.y*=NORM; qa.z*=NORM; qa.w*=NORM;
  qb.x*=NORM; qb.y*=NORM; qb.z*=NORM; qb.w*=NORM;
  qc.x*=NORM; qc.y*=NORM; qc.z*=NORM; qc.w*=NORM;
  qd.x*=NORM; qd.y*=NORM; qd.z*=NORM; qd.w*=NORM;
  float ssl = qa.x*qa.x+qa.y*qa.y+qa.z*qa.z+qa.w*qa.w
            + qb.x*qb.x+qb.y*qb.y+qb.z*qb.z+qb.w*qb.w
            + qc.x*qc.x+qc.y*qc.y+qc.z*qc.z+qc.w*qc.w
            + qd.x*qd.x+qd.y*qd.y+qd.z*qd.z+qd.w*qd.w;
  ssl += __shfl_xor(ssl, 16); ssl += __shfl_xor(ssl, 32);
  float dg = ssl * 0.5f;
  bf16x8 qh0,ql0,qh1,ql1;
  mkfrag(qa,qb,qh0,ql0); mkfrag(qc,qd,qh1,ql1);
  f32x4 dd[18];
  #pragma unroll
  for (int mf=0; mf<18; ++mf){
    int f0 = ((mf*8 + hg)*16 + li)*8, f1 = ((mf*8 + 4 + hg)*16 + li)*8;
    bf16x8 ph0 = ldb(PH + f0), ph1 = ldb(PH + f1);
    bf16x8 pl0 = ldb(PL + f0), pl1 = ldb(PL + f1);
    f32x4 x = {0.f,0.f,0.f,0.f};
    x = mfma16(ph0, qh0, x); x = mfma16(ph1, qh1, x);
    x = mfma16(ph0, ql0, x); x = mfma16(ph1, ql1, x);
    x = mfma16(pl0, qh0, x); x = mfma16(pl1, qh1, x);
    dd[mf] = x;
  }
  float rm = -1e30f;
  #pragma unroll
  for (int mf=0; mf<18; ++mf)
    #pragma unroll
    for (int i=0;i<4;++i){
      int m = mf*16 + hg*4 + i;
      if (m < Mc) rm = fmaxf(rm, dd[mf][i]);
    }
  rm = fmaxf(rm, __shfl_xor(rm, 16));
  rm = fmaxf(rm, __shfl_xor(rm, 32));
  float den = 0.f;
  #pragma unroll
  for (int df=0; df<4; ++df){ f32x4 z = {0.f,0.f,0.f,0.f}; acc3[df] = z; }
  for (int c=0; c<3; ++c){
    __syncthreads();
    #pragma unroll
    for (int mf6=0; mf6<6; ++mf6){
      int mf = c*6 + mf6;
      #pragma unroll
      for (int i=0;i<4;++i){
        int m = mf*16 + hg*4 + i;
        float qp = 0.f;
        if (m < Mc){
          float arg = fminf(dd[mf][i] - dg - rm, 8.f);
          qp = __expf(arg) + EPSc;
          den += qp * sks[m];
        }
        sQp[(mf6*16 + hg*4 + i)*66 + wv*16 + li] = qp;
      }
    }
    __syncthreads();
    #pragma unroll
    for (int ks=0; ks<3; ++ks){
      int k0 = ks*32;
      float av[8];
      #pragma unroll
      for (int j=0;j<8;++j) av[j] = sQp[(k0 + hg*8 + j)*66 + wv*16 + li];
      union { u16 u[8]; bf16x8 v; } AH, AL;
      #pragma unroll
      for (int j=0;j<8;++j){ u16 h = f2b(av[j]); AH.u[j] = h; AL.u[j] = f2b(av[j] - b2f(h)); }
      #pragma unroll
      for (int df=0; df<4; ++df){
        int jf = ((((c*3+ks)*4+df)*4+hg)*16+li)*4;
        bf16x8 chv = ldb((const u16*)(dof + ctx_fidx(bh, jf)));
        bf16x8 clv = ldb((const u16*)(dof + ctx_fidx(bh, 9216 + jf)));
        acc3[df] = mfma16(AH.v, chv, acc3[df]);
        acc3[df] = mfma16(AH.v, clv, acc3[df]);
        acc3[df] = mfma16(AL.v, chv, acc3[df]);
      }
    }
  }
  den += __shfl_xor(den, 16);
  den += __shfl_xor(den, 32);
  if (hg == 0) sden[wv*16 + li] = den;
  __syncthreads();
  #pragma unroll
  for (int i=0;i<4;++i){
    float dv = sden[wv*16 + hg*4 + i];
    float di = (dv > 1e-30f) ? 1.f/dv : -1.f;
    #pragma unroll
    for (int df=0; df<4; ++df){
      float o = (di > 0.f) ? acc3[df][i]*di : 3.0f;
      if (!(o == o && fabsf(o) < 1e30f)) o = 9.0f;
      acc3[df][i] = o;
    }
  }
}

// ---------------- kd: all 1728 non-tail tiles ----------------
__global__ __launch_bounds__(256) void kd(const float* q, float* dout){
  __shared__ float sQp[96 * 66];
  __shared__ float sks[288];
  __shared__ float sden[64];
  int wg = blockIdx.x, bh = wg / 54, lt = wg % 54;
  int t = threadIdx.x, wv = t >> 6, lane = t & 63, hg = lane >> 4, li = lane & 15;
  if (t < 72) *(f32x4*)(sks + t*4) = *(const f32x4*)(dout + ctx_fidx(bh, 18432 + t*4));
  f32x4 acc3[4];
  tile_mfma(q, dout, bh, lt*64, t, sQp, sks, sden, acc3);
  int b = bh >> 4, hh = bh & 15;
  #pragma unroll
  for (int df=0; df<4; ++df)
    #pragma unroll
    for (int i=0;i<4;++i)
      dout[((size_t)b*Lc + lt*64 + wv*16 + hg*4 + i)*1024 + hh*64 + df*16 + li] = acc3[df][i];
}

// ---------------- kf_b1: b1 tail tiles -> bf16 temp ----------------
__global__ __launch_bounds__(256) void kf_b1(const float* q, float* dout){
  __shared__ float sQp[96 * 66];
  __shared__ float sks[288];
  __shared__ float sden[64];
  int wg = blockIdx.x, h = wg / 10, ti = wg % 10, bh = 16 + h;
  int t = threadIdx.x, wv = t >> 6, lane = t & 63, hg = lane >> 4, li = lane & 15;
  if (t < 72) *(f32x4*)(sks + t*4) = *(const f32x4*)(dout + ctx_fidx(bh, 18432 + t*4));
  f32x4 acc3[4];
  tile_mfma(q, dout, bh, (54 + ti)*64, t, sQp, sks, sden, acc3);
  u32* tempu = (u32*)dout;
  #pragma unroll
  for (int df=0; df<4; ++df)
    #pragma unroll
    for (int i2=0; i2<2; ++i2){
      int p = wv*8 + hg*2 + i2;
      u32 u = (u32)f2b(acc3[df][i2*2]) | ((u32)f2b(acc3[df][i2*2+1]) << 16);
      tempu[B1 + (size_t)(3488 + ti*64 + p)*1024 + h*64 + df*16 + li] = u;
    }
}

// ---------------- kf_b0: b0 tail tiles -> final ----------------
__global__ __launch_bounds__(256) void kf_b0(const float* q, float* dout){
  __shared__ float sQp[96 * 66];
  __shared__ float sks[288];
  __shared__ float sden[64];
  int wg = blockIdx.x, h = wg / 10, ti = wg % 10, bh = h;
  int t = threadIdx.x, wv = t >> 6, lane = t & 63, hg = lane >> 4, li = lane & 15;
  if (t < 72) *(f32x4*)(sks + t*4) = *(const f32x4*)(dout + ctx_fidx(bh, 18432 + t*4));
  f32x4 acc3[4];
  tile_mfma(q, dout, bh, (54 + ti)*64, t, sQp, sks, sden, acc3);
  #pragma unroll
  for (int df=0; df<4; ++df)
    #pragma unroll
    for (int i=0;i<4;++i)
      dout[((size_t)(3456 + ti*64 + wv*16 + hg*4 + i))*1024 + h*64 + df*16 + li] = acc3[df][i];
}

// ---------------- kg: per-tile temp -> final ----------------
__global__ __launch_bounds__(256) void kg(float* dout){
  int wg = blockIdx.x, h = wg / 10, ti = wg % 10;
  int t = threadIdx.x;
  const u32* tempu = (const u32*)dout;
  u32 st[8];
  #pragma unroll
  for (int i=0;i<8;++i){
    int idx = t + 256*i;
    st[i] = tempu[B1 + (size_t)(3488 + ti*64 + (idx>>6))*1024 + h*64 + (idx & 63)];
  }
  __syncthreads();
  #pragma unroll
  for (int i=0;i<8;++i){
    int idx = t + 256*i, p = idx >> 6, dcol = idx & 63;
    dout[B1 + (size_t)(3456 + ti*64 + 2*p)*1024 + h*64 + dcol]     = b2f((u16)(st[i] & 0xFFFF));
    dout[B1 + (size_t)(3456 + ti*64 + 2*p + 1)*1024 + h*64 + dcol] = b2f((u16)(st[i] >> 16));
  }
}

extern "C" void kernel_launch(void* const* d_in, const int* in_sizes, int n_in,
                              void* d_out, int out_size, void* d_ws, size_t ws_size,
                              hipStream_t stream){
  const float* q    = (const float*)d_in[0];
  const float* kk   = (const float*)d_in[1];
  const float* vv   = (const float*)d_in[2];
  const void*  mask = d_in[3];
  const float* P    = (const float*)d_in[4];
  float* dout = (float*)d_out;
  hipLaunchKernelGGL(kp0,   dim3(72),   dim3(256), 0, stream, P, dout);
  hipLaunchKernelGGL(ka,    dim3(2048), dim3(256), 0, stream, kk, dout);
  hipLaunchKernelGGL(kb,    dim3(1536), dim3(256), 0, stream, kk, vv, mask, dout);
  hipLaunchKernelGGL(kc1,   dim3(585),  dim3(256), 0, stream, dout);
  hipLaunchKernelGGL(kc2,   dim3(293),  dim3(256), 0, stream, dout);
  hipLaunchKernelGGL(kd,    dim3(1728), dim3(256), 0, stream, q, dout);
  hipLaunchKernelGGL(kf_b1, dim3(160),  dim3(256), 0, stream, q, dout);
  hipLaunchKernelGGL(kf_b0, dim3(160),  dim3(256), 0, stream, q, dout);
  hipLaunchKernelGGL(kg,    dim3(160),  dim3(256), 0, stream, dout);
}

// Round 15
// 279.626 us; speedup vs baseline: 6.4102x; 1.0253x over previous
//
#include <hip/hip_runtime.h>
#include <cstdint>

#define DEV static __device__ __forceinline__

typedef float f32x4 __attribute__((ext_vector_type(4)));
typedef __bf16 bf16x8 __attribute__((ext_vector_type(8)));
typedef unsigned short u16;
typedef unsigned int u32;

constexpr int Lc = 4096, Dc = 64, Mc = 266;
constexpr float NORM = 0.35355339059327373f;   // 64^-0.25
constexpr float EPSc = 1e-4f;

// ---- scratch DAG layout (all in d_out; d_ws unused) ----
// partial  : fidx 0..4,792,319   W:kb R:kc1, dead at kd
// b1 tail tops    : ctx of b0 heads (swizzled bf16 hi[9216 f-slots]+lo[9216]+ksum f32[288])
//   + P-split rows 4037..4054 (fragment-swizzled), blockmax rows 4056..4057
// b1 tail bottoms : ctx-b1 staging W:kc1 R:kc2; then temp W:kf_b1 R:kg
// b0 tail tops    : ctx of b1 heads, W:kc2 R:kd,kf_b1, dead at kf_b0
constexpr size_t B1   = 4194304;
constexpr size_t PSPH = B1 + 4037ull*1024;
constexpr size_t PSPL = PSPH + 9216;
constexpr size_t BMAX = B1 + 4056ull*1024;

DEV size_t sc_fidx(int which, int h, int j){
  int tri = j >> 6, ti = tri >> 5, r = tri & 31, c = j & 63;
  size_t row = 3456 + (size_t)ti*64 + r + ((which == 2) ? 32 : 0);
  size_t base = (which == 1) ? 0 : B1;
  return base + row*1024 + (size_t)h*64 + c;
}
DEV size_t ctx_fidx(int bh, int j){ return sc_fidx(bh < 16 ? 0 : 1, bh & 15, j); }

DEV bool mget(const void* mp, int mode, int idx){
  if (mode == 0) return ((const unsigned char*)mp)[idx] != 0;
  if (mode == 1) return ((const int*)mp)[idx] != 0;
  return ((const float*)mp)[idx] != 0.f;
}
DEV u16 f2b(float f){ u32 u = __float_as_uint(f); return (u16)((u + 0x7FFFu + ((u>>16)&1u)) >> 16); }
DEV float b2f(u16 h){ return __uint_as_float(((u32)h) << 16); }
DEV f32x4 mfma16(bf16x8 a, bf16x8 b, f32x4 c){ return __builtin_amdgcn_mfma_f32_16x16x32_bf16(a, b, c, 0, 0, 0); }
DEV void mkfrag(float4 a, float4 b, bf16x8& fh, bf16x8& fl){
  union { u16 u[8]; bf16x8 v; } H, L;
  float x[8] = {a.x,a.y,a.z,a.w,b.x,b.y,b.z,b.w};
  #pragma unroll
  for (int j=0;j<8;++j){ u16 h = f2b(x[j]); H.u[j] = h; L.u[j] = f2b(x[j] - b2f(h)); }
  fh = H.v; fl = L.v;
}
DEV bf16x8 ldb(const u16* p){ return *(const bf16x8*)p; }

// ---------------- kp0: P hi/lo split table, fragment-swizzled ----------------
__global__ __launch_bounds__(256) void kp0(const float* P, float* dout){
  int idx = blockIdx.x * 256 + threadIdx.x;
  if (idx >= 288 * 64) return;
  int m = idx >> 6, d = idx & 63;
  float v = (m < Mc) ? P[idx] : 0.f;
  u16 h = f2b(v);
  int i2 = (((m>>4)*8 + (d>>3))*16 + (m&15))*8 + (d&7);
  ((u16*)(dout + PSPH))[i2] = h;
  ((u16*)(dout + PSPL))[i2] = f2b(v - b2f(h));
}

// ---------------- ka: per-block max of dd_k -> blockmax ----------------
__global__ __launch_bounds__(256) void ka(const float* kk, float* dout){
  __shared__ float sred[4];
  int wg = blockIdx.x, bh = wg >> 6, l0 = (wg & 63) << 6, t = threadIdx.x;
  int wv = t >> 6, lane = t & 63, hg = lane >> 4, li = lane & 15;
  const u16* PH = (const u16*)(dout + PSPH);
  const u16* PL = (const u16*)(dout + PSPL);
  const float* krow = kk + ((size_t)bh * Lc + l0 + wv*16 + li) * Dc;
  float4 qa = *(const float4*)(krow + hg*8);
  float4 qb = *(const float4*)(krow + hg*8 + 4);
  float4 qc = *(const float4*)(krow + 32 + hg*8);
  float4 qd = *(const float4*)(krow + 32 + hg*8 + 4);
  qa.x*=NORM; qa.y*=NORM; qa.z*=NORM; qa.w*=NORM;
  qb.x*=NORM; qb.y*=NORM; qb.z*=NORM; qb.w*=NORM;
  qc.x*=NORM; qc.y*=NORM; qc.z*=NORM; qc.w*=NORM;
  qd.x*=NORM; qd.y*=NORM; qd.z*=NORM; qd.w*=NORM;
  bf16x8 qh0,ql0,qh1,ql1;
  mkfrag(qa,qb,qh0,ql0); mkfrag(qc,qd,qh1,ql1);
  float vmax = -1e30f;
  #pragma unroll
  for (int mf=0; mf<18; ++mf){
    int f0 = ((mf*8 + hg)*16 + li)*8, f1 = ((mf*8 + 4 + hg)*16 + li)*8;
    bf16x8 ph0 = ldb(PH + f0), ph1 = ldb(PH + f1);
    bf16x8 pl0 = ldb(PL + f0), pl1 = ldb(PL + f1);
    f32x4 x = {0.f,0.f,0.f,0.f};
    x = mfma16(ph0, qh0, x); x = mfma16(ph1, qh1, x);
    x = mfma16(ph0, ql0, x); x = mfma16(ph1, ql1, x);
    x = mfma16(pl0, qh0, x); x = mfma16(pl1, qh1, x);
    #pragma unroll
    for (int i=0;i<4;++i){
      int m = mf*16 + hg*4 + i;
      if (m < Mc) vmax = fmaxf(vmax, x[i]);
    }
  }
  vmax = fmaxf(vmax, __shfl_xor(vmax, 1));
  vmax = fmaxf(vmax, __shfl_xor(vmax, 2));
  vmax = fmaxf(vmax, __shfl_xor(vmax, 4));
  vmax = fmaxf(vmax, __shfl_xor(vmax, 8));
  vmax = fmaxf(vmax, __shfl_xor(vmax, 16));
  vmax = fmaxf(vmax, __shfl_xor(vmax, 32));
  if (lane == 0) sred[wv] = vmax;
  __syncthreads();
  if (t == 0) dout[BMAX + wg] = fmaxf(fmaxf(sred[0],sred[1]), fmaxf(sred[2],sred[3]));
}

// ---------------- kb v4: kp-hi-only GEMM, swizzled sVH, 8 blocks/CU ----------------
__global__ __launch_bounds__(256) void kb(const float* kk, const float* vv, const void* mask,
                                          float* dout){
  __shared__ __align__(16) unsigned char smem[18432];
  __shared__ float sred[256];
  u16* sKH = (u16*)smem;                // [48][72] kp hi, [m][l]
  u16* sVH = (u16*)(smem + 6912);       // [80][72] v hi, [d][l^sw]; rows 64.. = ones block
  float* sT = (float*)smem;             // [65][49] post-loop alias
  int wg = blockIdx.x;                  // 1536 = 32 bh x 8 part x 6 mc
  int bh = wg / 48, r48 = wg % 48, part = r48 / 6, mc = r48 % 6;
  int b = bh >> 4;
  int t = threadIdx.x, wv = t >> 6, lane = t & 63, hg = lane >> 4, li = lane & 15;
  u32 w0 = *(const u32*)mask;
  int mode = (w0 == 0x01010101u) ? 0 : ((w0 == 0x3F800000u) ? 2 : 1);
  float bm = -1e30f;
  for (int i = 0; i < 8; ++i) bm = fmaxf(bm, dout[BMAX + t + 256 * i]);
  sred[t] = bm; __syncthreads();
  for (int s = 128; s > 0; s >>= 1){
    if (t < s) sred[t] = fmaxf(sred[t], sred[t + s]);
    __syncthreads();
  }
  float kmax = sred[0];
  // ones rows d=64..79 (row 64 = 1.0 -> ksum); row-uniform so swizzle-free init is fine
  for (int idx = t; idx < 16*72; idx += 256){
    int r = idx / 72, c = idx % 72;
    sVH[(64 + r)*72 + c] = (r == 0) ? (u16)0x3F80 : (u16)0;
  }
  const u16* PH = (const u16*)(dout + PSPH);
  const u16* PL = (const u16*)(dout + PSPL);
  f32x4 acc[4];
  #pragma unroll
  for (int j=0;j<4;++j){ f32x4 z = {0.f,0.f,0.f,0.f}; acc[j] = z; }
  for (int s8 = 0; s8 < 8; ++s8){
    int l0 = part*512 + s8*64;
    __syncthreads();
    // stage v hi-only [d][l^sw], sw = ((d>>2)&3)<<3  -> ~2-way bank conflicts
    const float4* vs4 = (const float4*)(vv + ((size_t)bh*Lc + l0)*Dc);
    #pragma unroll
    for (int p=0;p<4;++p){
      int idx = p*256 + t, row = idx >> 4, c4 = idx & 15;
      float4 u = vs4[idx];
      float kf = mget(mask, mode, b*Lc + l0 + row) ? 1.f : 0.f;
      int rs = row ^ ((c4&3)<<3);
      #pragma unroll
      for (int ii=0;ii<4;++ii){
        int d = c4*4 + ii;
        sVH[d*72 + rs] = f2b((&u.x)[ii] * kf);
      }
    }
    // own k-row fragments + diag
    const float* krow = kk + ((size_t)bh*Lc + l0 + wv*16 + li)*Dc;
    float4 qa = *(const float4*)(krow + hg*8);
    float4 qb = *(const float4*)(krow + hg*8 + 4);
    float4 qc = *(const float4*)(krow + 32 + hg*8);
    float4 qd = *(const float4*)(krow + 32 + hg*8 + 4);
    qa.x*=NORM; qa.y*=NORM; qa.z*=NORM; qa.w*=NORM;
    qb.x*=NORM; qb.y*=NORM; qb.z*=NORM; qb.w*=NORM;
    qc.x*=NORM; qc.y*=NORM; qc.z*=NORM; qc.w*=NORM;
    qd.x*=NORM; qd.y*=NORM; qd.z*=NORM; qd.w*=NORM;
    float ssl = qa.x*qa.x+qa.y*qa.y+qa.z*qa.z+qa.w*qa.w
              + qb.x*qb.x+qb.y*qb.y+qb.z*qb.z+qb.w*qb.w
              + qc.x*qc.x+qc.y*qc.y+qc.z*qc.z+qc.w*qc.w
              + qd.x*qd.x+qd.y*qd.y+qd.z*qd.z+qd.w*qd.w;
    ssl += __shfl_xor(ssl, 16); ssl += __shfl_xor(ssl, 32);
    float dg = ssl * 0.5f;
    bf16x8 kh0,kl0,kh1,kl1;
    mkfrag(qa,qb,kh0,kl0); mkfrag(qc,qd,kh1,kl1);
    // dd for this block's 48 m (full 3-term split) + kp-hi store
    #pragma unroll
    for (int mf3 = 0; mf3 < 3; ++mf3){
      int mf = mc*3 + mf3;
      int f0 = ((mf*8 + hg)*16 + li)*8, f1 = ((mf*8 + 4 + hg)*16 + li)*8;
      bf16x8 ph0 = ldb(PH + f0), ph1 = ldb(PH + f1);
      bf16x8 pl0 = ldb(PL + f0), pl1 = ldb(PL + f1);
      f32x4 x = {0.f,0.f,0.f,0.f};
      x = mfma16(ph0, kh0, x); x = mfma16(ph1, kh1, x);
      x = mfma16(ph0, kl0, x); x = mfma16(ph1, kl1, x);
      x = mfma16(pl0, kh0, x); x = mfma16(pl1, kh1, x);
      #pragma unroll
      for (int i=0;i<4;++i){
        int m = mf*16 + hg*4 + i;
        float kp = 0.f;
        if (m < Mc){
          float arg = fminf(x[i] - dg - kmax, 8.f);
          kp = __expf(arg) + EPSc;
        }
        int rr = mf3*16 + hg*4 + i;
        sKH[rr*72 + wv*16 + li] = f2b(kp);
      }
    }
    __syncthreads();
    // GEMM: 15 (mfl, df) pairs over 4 waves, 2 MFMA each (kp hi x v hi)
    #pragma unroll
    for (int j = 0; j < 4; ++j){
      int p = wv + 4*j;
      if (p < 15){
        int mfl = p / 5, df = p % 5;
        const u16* ar = sKH + (mfl*16 + li)*72 + hg*8;
        bf16x8 ah0 = ldb(ar), ah1 = ldb(ar + 32);
        int d = df*16 + li, sw = (d>>2)&3;
        const u16* br = sVH + d*72 + ((hg^sw)<<3);
        bf16x8 bh0 = ldb(br), bh1 = ldb(br + 32);
        f32x4 a = acc[j];
        a = mfma16(ah0, bh0, a); a = mfma16(ah1, bh1, a);
        acc[j] = a;
      }
    }
  }
  // transpose via LDS then coalesced partial write
  __syncthreads();
  #pragma unroll
  for (int j = 0; j < 4; ++j){
    int p = wv + 4*j;
    if (p < 15){
      int mfl = p / 5, df = p % 5;
      #pragma unroll
      for (int i=0;i<4;++i){
        int mloc = mfl*16 + hg*4 + i;
        if (df < 4) sT[(df*16 + li)*49 + mloc] = acc[j][i];
        else if (li == 0) sT[64*49 + mloc] = acc[j][i];
      }
    }
  }
  __syncthreads();
  size_t pbase = ((size_t)part*32 + bh) * 18720;
  for (int idx = t; idx < 780; idx += 256){
    int row = idx / 12, qq = idx % 12;
    float4 v4;
    v4.x = sT[row*49 + qq*4];     v4.y = sT[row*49 + qq*4 + 1];
    v4.z = sT[row*49 + qq*4 + 2]; v4.w = sT[row*49 + qq*4 + 3];
    *(float4*)(dout + pbase + (size_t)row*288 + mc*48 + qq*4) = v4;
  }
}

// ---------------- kc1: reduce partials -> swizzled bf16 ctx (+ f32 ksum) ----------------
__global__ __launch_bounds__(256) void kc1(float* dout){
  int tid = blockIdx.x * 256 + threadIdx.x;
  int bh = tid / 4680, r4 = tid % 4680;
  int p = r4 * 4;
  int d = p / 288, m = p % 288;
  int which = (bh < 16) ? 0 : 2, h = bh & 15;
  if (d == 64){
    f32x4 s = {0.f,0.f,0.f,0.f};
    for (int p8 = 0; p8 < 8; ++p8)
      s += *(const f32x4*)(dout + ((size_t)p8 * 32 + bh) * 18720 + p);
    *(f32x4*)(dout + sc_fidx(which, h, p)) = s;
    return;
  }
  f32x4 s = {0.f,0.f,0.f,0.f};
  if (m < 272){
    for (int p8 = 0; p8 < 8; ++p8)
      s += *(const f32x4*)(dout + ((size_t)p8 * 32 + bh) * 18720 + p);
  }
  int c = m/96, r = m%96, ks = r>>5, hgs = (r&31)>>3, e = m&7;
  int df = d>>4, li = d&15;
  int i2 = ((((c*3+ks)*4+df)*4+hgs)*16+li)*8 + e;
  int jH = i2 >> 1;
  u16 h0=f2b(s[0]), h1=f2b(s[1]), h2=f2b(s[2]), h3=f2b(s[3]);
  u16 l0=f2b(s[0]-b2f(h0)), l1=f2b(s[1]-b2f(h1)), l2=f2b(s[2]-b2f(h2)), l3=f2b(s[3]-b2f(h3));
  uint2 H; H.x = (u32)h0 | ((u32)h1<<16); H.y = (u32)h2 | ((u32)h3<<16);
  uint2 L; L.x = (u32)l0 | ((u32)l1<<16); L.y = (u32)l2 | ((u32)l3<<16);
  *(uint2*)(dout + sc_fidx(which, h, jH)) = H;
  *(uint2*)(dout + sc_fidx(which, h, 9216 + jH)) = L;
}

// ---------------- kc2: copy ctx-b1 staging -> b0 tops (bit copy) ----------------
__global__ __launch_bounds__(256) void kc2(float* dout){
  int tid = blockIdx.x * 256 + threadIdx.x;
  if (tid >= 74880) return;
  int h = tid / 4680, j = (tid % 4680) * 4;
  f32x4 v = *(const f32x4*)(dout + sc_fidx(2, h, j));
  *(f32x4*)(dout + sc_fidx(1, h, j)) = v;
}

// ---------------- MFMA tile engine (coalesced P + pre-split swizzled ctx) ----------------
DEV void tile_mfma(const float* q, const float* dof,
                   int bh, int l0, int t,
                   float* sQp, const float* sks, float* sden,
                   f32x4 (&acc3)[4]){
  int wv = t >> 6, lane = t & 63, hg = lane >> 4, li = lane & 15;
  const u16* PH = (const u16*)(dof + PSPH);
  const u16* PL = (const u16*)(dof + PSPL);
  const float* qrow = q + ((size_t)bh * Lc + l0 + wv*16 + li) * Dc;
  float4 qa = *(const float4*)(qrow + hg*8);
  float4 qb = *(const float4*)(qrow + hg*8 + 4);
  float4 qc = *(const float4*)(qrow + 32 + hg*8);
  float4 qd = *(const float4*)(qrow + 32 + hg*8 + 4);
  qa.x*=NORM; qa.y*=NORM; qa.z*=NORM; qa.w*=NORM;
  qb.x*=NORM; qb.y*=NORM; qb.z*=NORM; qb.w*=NORM;
  qc.x*=NORM; qc.y*=NORM; qc.z*=NORM; qc.w*=NORM;
  qd.x*=NORM; qd.y*=NORM; qd.z*=NORM; qd.w*=NORM;
  float ssl = qa.x*qa.x+qa.y*qa.y+qa.z*qa.z+qa.w*qa.w
            + qb.x*qb.x+qb.y*qb.y+qb.z*qb.z+qb.w*qb.w
            + qc.x*qc.x+qc.y*qc.y+qc.z*qc.z+qc.w*qc.w
            + qd.x*qd.x+qd.y*qd.y+qd.z*qd.z+qd.w*qd.w;
  ssl += __shfl_xor(ssl, 16); ssl += __shfl_xor(ssl, 32);
  float dg = ssl * 0.5f;
  bf16x8 qh0,ql0,qh1,ql1;
  mkfrag(qa,qb,qh0,ql0); mkfrag(qc,qd,qh1,ql1);
  f32x4 dd[18];
  #pragma unroll
  for (int mf=0; mf<18; ++mf){
    int f0 = ((mf*8 + hg)*16 + li)*8, f1 = ((mf*8 + 4 + hg)*16 + li)*8;
    bf16x8 ph0 = ldb(PH + f0), ph1 = ldb(PH + f1);
    bf16x8 pl0 = ldb(PL + f0), pl1 = ldb(PL + f1);
    f32x4 x = {0.f,0.f,0.f,0.f};
    x = mfma16(ph0, qh0, x); x = mfma16(ph1, qh1, x);
    x = mfma16(ph0, ql0, x); x = mfma16(ph1, ql1, x);
    x = mfma16(pl0, qh0, x); x = mfma16(pl1, qh1, x);
    dd[mf] = x;
  }
  float rm = -1e30f;
  #pragma unroll
  for (int mf=0; mf<18; ++mf)
    #pragma unroll
    for (int i=0;i<4;++i){
      int m = mf*16 + hg*4 + i;
      if (m < Mc) rm = fmaxf(rm, dd[mf][i]);
    }
  rm = fmaxf(rm, __shfl_xor(rm, 16));
  rm = fmaxf(rm, __shfl_xor(rm, 32));
  float den = 0.f;
  #pragma unroll
  for (int df=0; df<4; ++df){ f32x4 z = {0.f,0.f,0.f,0.f}; acc3[df] = z; }
  for (int c=0; c<3; ++c){
    __syncthreads();
    #pragma unroll
    for (int mf6=0; mf6<6; ++mf6){
      int mf = c*6 + mf6;
      #pragma unroll
      for (int i=0;i<4;++i){
        int m = mf*16 + hg*4 + i;
        float qp = 0.f;
        if (m < Mc){
          float arg = fminf(dd[mf][i] - dg - rm, 8.f);
          qp = __expf(arg) + EPSc;
          den += qp * sks[m];
        }
        sQp[(mf6*16 + hg*4 + i)*66 + wv*16 + li] = qp;
      }
    }
    __syncthreads();
    #pragma unroll
    for (int ks=0; ks<3; ++ks){
      int k0 = ks*32;
      float av[8];
      #pragma unroll
      for (int j=0;j<8;++j) av[j] = sQp[(k0 + hg*8 + j)*66 + wv*16 + li];
      union { u16 u[8]; bf16x8 v; } AH, AL;
      #pragma unroll
      for (int j=0;j<8;++j){ u16 h = f2b(av[j]); AH.u[j] = h; AL.u[j] = f2b(av[j] - b2f(h)); }
      #pragma unroll
      for (int df=0; df<4; ++df){
        int jf = ((((c*3+ks)*4+df)*4+hg)*16+li)*4;
        bf16x8 chv = ldb((const u16*)(dof + ctx_fidx(bh, jf)));
        bf16x8 clv = ldb((const u16*)(dof + ctx_fidx(bh, 9216 + jf)));
        acc3[df] = mfma16(AH.v, chv, acc3[df]);
        acc3[df] = mfma16(AH.v, clv, acc3[df]);
        acc3[df] = mfma16(AL.v, chv, acc3[df]);
      }
    }
  }
  den += __shfl_xor(den, 16);
  den += __shfl_xor(den, 32);
  if (hg == 0) sden[wv*16 + li] = den;
  __syncthreads();
  #pragma unroll
  for (int i=0;i<4;++i){
    float dv = sden[wv*16 + hg*4 + i];
    float di = (dv > 1e-30f) ? 1.f/dv : -1.f;
    #pragma unroll
    for (int df=0; df<4; ++df){
      float o = (di > 0.f) ? acc3[df][i]*di : 3.0f;
      if (!(o == o && fabsf(o) < 1e30f)) o = 9.0f;
      acc3[df][i] = o;
    }
  }
}

// ---------------- kd: all 1728 non-tail tiles ----------------
__global__ __launch_bounds__(256) void kd(const float* q, float* dout){
  __shared__ float sQp[96 * 66];
  __shared__ float sks[288];
  __shared__ float sden[64];
  int wg = blockIdx.x, bh = wg / 54, lt = wg % 54;
  int t = threadIdx.x, wv = t >> 6, lane = t & 63, hg = lane >> 4, li = lane & 15;
  if (t < 72) *(f32x4*)(sks + t*4) = *(const f32x4*)(dout + ctx_fidx(bh, 18432 + t*4));
  f32x4 acc3[4];
  tile_mfma(q, dout, bh, lt*64, t, sQp, sks, sden, acc3);
  int b = bh >> 4, hh = bh & 15;
  #pragma unroll
  for (int df=0; df<4; ++df)
    #pragma unroll
    for (int i=0;i<4;++i)
      dout[((size_t)b*Lc + lt*64 + wv*16 + hg*4 + i)*1024 + hh*64 + df*16 + li] = acc3[df][i];
}

// ---------------- kf_b1: b1 tail tiles -> bf16 temp ----------------
__global__ __launch_bounds__(256) void kf_b1(const float* q, float* dout){
  __shared__ float sQp[96 * 66];
  __shared__ float sks[288];
  __shared__ float sden[64];
  int wg = blockIdx.x, h = wg / 10, ti = wg % 10, bh = 16 + h;
  int t = threadIdx.x, wv = t >> 6, lane = t & 63, hg = lane >> 4, li = lane & 15;
  if (t < 72) *(f32x4*)(sks + t*4) = *(const f32x4*)(dout + ctx_fidx(bh, 18432 + t*4));
  f32x4 acc3[4];
  tile_mfma(q, dout, bh, (54 + ti)*64, t, sQp, sks, sden, acc3);
  u32* tempu = (u32*)dout;
  #pragma unroll
  for (int df=0; df<4; ++df)
    #pragma unroll
    for (int i2=0; i2<2; ++i2){
      int p = wv*8 + hg*2 + i2;
      u32 u = (u32)f2b(acc3[df][i2*2]) | ((u32)f2b(acc3[df][i2*2+1]) << 16);
      tempu[B1 + (size_t)(3488 + ti*64 + p)*1024 + h*64 + df*16 + li] = u;
    }
}

// ---------------- kf_b0: b0 tail tiles -> final ----------------
__global__ __launch_bounds__(256) void kf_b0(const float* q, float* dout){
  __shared__ float sQp[96 * 66];
  __shared__ float sks[288];
  __shared__ float sden[64];
  int wg = blockIdx.x, h = wg / 10, ti = wg % 10, bh = h;
  int t = threadIdx.x, wv = t >> 6, lane = t & 63, hg = lane >> 4, li = lane & 15;
  if (t < 72) *(f32x4*)(sks + t*4) = *(const f32x4*)(dout + ctx_fidx(bh, 18432 + t*4));
  f32x4 acc3[4];
  tile_mfma(q, dout, bh, (54 + ti)*64, t, sQp, sks, sden, acc3);
  #pragma unroll
  for (int df=0; df<4; ++df)
    #pragma unroll
    for (int i=0;i<4;++i)
      dout[((size_t)(3456 + ti*64 + wv*16 + hg*4 + i))*1024 + h*64 + df*16 + li] = acc3[df][i];
}

// ---------------- kg: per-tile temp -> final ----------------
__global__ __launch_bounds__(256) void kg(float* dout){
  int wg = blockIdx.x, h = wg / 10, ti = wg % 10;
  int t = threadIdx.x;
  const u32* tempu = (const u32*)dout;
  u32 st[8];
  #pragma unroll
  for (int i=0;i<8;++i){
    int idx = t + 256*i;
    st[i] = tempu[B1 + (size_t)(3488 + ti*64 + (idx>>6))*1024 + h*64 + (idx & 63)];
  }
  __syncthreads();
  #pragma unroll
  for (int i=0;i<8;++i){
    int idx = t + 256*i, p = idx >> 6, dcol = idx & 63;
    dout[B1 + (size_t)(3456 + ti*64 + 2*p)*1024 + h*64 + dcol]     = b2f((u16)(st[i] & 0xFFFF));
    dout[B1 + (size_t)(3456 + ti*64 + 2*p + 1)*1024 + h*64 + dcol] = b2f((u16)(st[i] >> 16));
  }
}

extern "C" void kernel_launch(void* const* d_in, const int* in_sizes, int n_in,
                              void* d_out, int out_size, void* d_ws, size_t ws_size,
                              hipStream_t stream){
  const float* q    = (const float*)d_in[0];
  const float* kk   = (const float*)d_in[1];
  const float* vv   = (const float*)d_in[2];
  const void*  mask = d_in[3];
  const float* P    = (const float*)d_in[4];
  float* dout = (float*)d_out;
  hipLaunchKernelGGL(kp0,   dim3(72),   dim3(256), 0, stream, P, dout);
  hipLaunchKernelGGL(ka,    dim3(2048), dim3(256), 0, stream, kk, dout);
  hipLaunchKernelGGL(kb,    dim3(1536), dim3(256), 0, stream, kk, vv, mask, dout);
  hipLaunchKernelGGL(kc1,   dim3(585),  dim3(256), 0, stream, dout);
  hipLaunchKernelGGL(kc2,   dim3(293),  dim3(256), 0, stream, dout);
  hipLaunchKernelGGL(kd,    dim3(1728), dim3(256), 0, stream, q, dout);
  hipLaunchKernelGGL(kf_b1, dim3(160),  dim3(256), 0, stream, q, dout);
  hipLaunchKernelGGL(kf_b0, dim3(160),  dim3(256), 0, stream, q, dout);
  hipLaunchKernelGGL(kg,    dim3(160),  dim3(256), 0, stream, dout);
}

// Round 16
// 196.313 us; speedup vs baseline: 9.1306x; 1.4244x over previous
//
#include <hip/hip_runtime.h>
#include <cstdint>

#define DEV static __device__ __forceinline__

typedef float f32x4 __attribute__((ext_vector_type(4)));
typedef __bf16 bf16x8 __attribute__((ext_vector_type(8)));
typedef unsigned short u16;
typedef unsigned int u32;

constexpr int Lc = 4096, Dc = 64, Mc = 266;
constexpr float NORM = 0.35355339059327373f;   // 64^-0.25
constexpr float EPSc = 1e-4f;

// ---- scratch DAG layout (all in d_out; d_ws unused) ----
constexpr size_t B1   = 4194304;
constexpr size_t PSPH = B1 + 4037ull*1024;
constexpr size_t PSPL = PSPH + 9216;
constexpr size_t BMAX = B1 + 4056ull*1024;

DEV size_t sc_fidx(int which, int h, int j){
  int tri = j >> 6, ti = tri >> 5, r = tri & 31, c = j & 63;
  size_t row = 3456 + (size_t)ti*64 + r + ((which == 2) ? 32 : 0);
  size_t base = (which == 1) ? 0 : B1;
  return base + row*1024 + (size_t)h*64 + c;
}
DEV size_t ctx_fidx(int bh, int j){ return sc_fidx(bh < 16 ? 0 : 1, bh & 15, j); }

DEV bool mget(const void* mp, int mode, int idx){
  if (mode == 0) return ((const unsigned char*)mp)[idx] != 0;
  if (mode == 1) return ((const int*)mp)[idx] != 0;
  return ((const float*)mp)[idx] != 0.f;
}
DEV u16 f2b(float f){ u32 u = __float_as_uint(f); return (u16)((u + 0x7FFFu + ((u>>16)&1u)) >> 16); }
DEV float b2f(u16 h){ return __uint_as_float(((u32)h) << 16); }
DEV f32x4 mfma16(bf16x8 a, bf16x8 b, f32x4 c){ return __builtin_amdgcn_mfma_f32_16x16x32_bf16(a, b, c, 0, 0, 0); }
DEV void mkfrag(float4 a, float4 b, bf16x8& fh, bf16x8& fl){
  union { u16 u[8]; bf16x8 v; } H, L;
  float x[8] = {a.x,a.y,a.z,a.w,b.x,b.y,b.z,b.w};
  #pragma unroll
  for (int j=0;j<8;++j){ u16 h = f2b(x[j]); H.u[j] = h; L.u[j] = f2b(x[j] - b2f(h)); }
  fh = H.v; fl = L.v;
}
DEV bf16x8 ldb(const u16* p){ return *(const bf16x8*)p; }

// ---------------- kp0: P hi/lo split table, fragment-swizzled ----------------
__global__ __launch_bounds__(256) void kp0(const float* P, float* dout){
  int idx = blockIdx.x * 256 + threadIdx.x;
  if (idx >= 288 * 64) return;
  int m = idx >> 6, d = idx & 63;
  float v = (m < Mc) ? P[idx] : 0.f;
  u16 h = f2b(v);
  int i2 = (((m>>4)*8 + (d>>3))*16 + (m&15))*8 + (d&7);
  ((u16*)(dout + PSPH))[i2] = h;
  ((u16*)(dout + PSPL))[i2] = f2b(v - b2f(h));
}

// ---------------- ka: per-block max of dd_k (LDS-staged P chunks) ----------------
__global__ __launch_bounds__(256) void ka(const float* kk, float* dout){
  __shared__ __align__(16) u16 sP[12288];   // PH chunk [6144] + PL chunk [6144]
  __shared__ float sred[4];
  int wg = blockIdx.x, bh = wg >> 6, l0 = (wg & 63) << 6, t = threadIdx.x;
  int wv = t >> 6, lane = t & 63, hg = lane >> 4, li = lane & 15;
  const uint4* PHg = (const uint4*)((const u16*)(dout + PSPH));
  const uint4* PLg = (const uint4*)((const u16*)(dout + PSPL));
  const float* krow = kk + ((size_t)bh * Lc + l0 + wv*16 + li) * Dc;
  float4 qa = *(const float4*)(krow + hg*8);
  float4 qb = *(const float4*)(krow + hg*8 + 4);
  float4 qc = *(const float4*)(krow + 32 + hg*8);
  float4 qd = *(const float4*)(krow + 32 + hg*8 + 4);
  qa.x*=NORM; qa.y*=NORM; qa.z*=NORM; qa.w*=NORM;
  qb.x*=NORM; qb.y*=NORM; qb.z*=NORM; qb.w*=NORM;
  qc.x*=NORM; qc.y*=NORM; qc.z*=NORM; qc.w*=NORM;
  qd.x*=NORM; qd.y*=NORM; qd.z*=NORM; qd.w*=NORM;
  bf16x8 qh0,ql0,qh1,ql1;
  mkfrag(qa,qb,qh0,ql0); mkfrag(qc,qd,qh1,ql1);
  float vmax = -1e30f;
  for (int c=0;c<3;++c){
    __syncthreads();
    #pragma unroll
    for (int i=0;i<3;++i){
      int idx = i*256 + t;
      ((uint4*)sP)[idx]          = PHg[c*768 + idx];
      ((uint4*)(sP + 6144))[idx] = PLg[c*768 + idx];
    }
    __syncthreads();
    #pragma unroll
    for (int lf=0; lf<6; ++lf){
      int b0 = ((lf*8 + hg)*16 + li)*8, b1 = ((lf*8 + 4 + hg)*16 + li)*8;
      bf16x8 ph0 = ldb(sP + b0), ph1 = ldb(sP + b1);
      bf16x8 pl0 = ldb(sP + 6144 + b0), pl1 = ldb(sP + 6144 + b1);
      f32x4 x = {0.f,0.f,0.f,0.f};
      x = mfma16(ph0, qh0, x); x = mfma16(ph1, qh1, x);
      x = mfma16(ph0, ql0, x); x = mfma16(ph1, ql1, x);
      x = mfma16(pl0, qh0, x); x = mfma16(pl1, qh1, x);
      #pragma unroll
      for (int i=0;i<4;++i){
        int m = (c*6 + lf)*16 + hg*4 + i;
        if (m < Mc) vmax = fmaxf(vmax, x[i]);
      }
    }
  }
  vmax = fmaxf(vmax, __shfl_xor(vmax, 1));
  vmax = fmaxf(vmax, __shfl_xor(vmax, 2));
  vmax = fmaxf(vmax, __shfl_xor(vmax, 4));
  vmax = fmaxf(vmax, __shfl_xor(vmax, 8));
  vmax = fmaxf(vmax, __shfl_xor(vmax, 16));
  vmax = fmaxf(vmax, __shfl_xor(vmax, 32));
  if (lane == 0) sred[wv] = vmax;
  __syncthreads();
  if (t == 0) dout[BMAX + wg] = fmaxf(fmaxf(sred[0],sred[1]), fmaxf(sred[2],sred[3]));
}

// ---------------- kb v4 (UNCHANGED from R15) ----------------
__global__ __launch_bounds__(256) void kb(const float* kk, const float* vv, const void* mask,
                                          float* dout){
  __shared__ __align__(16) unsigned char smem[18432];
  __shared__ float sred[256];
  u16* sKH = (u16*)smem;
  u16* sVH = (u16*)(smem + 6912);
  float* sT = (float*)smem;
  int wg = blockIdx.x;
  int bh = wg / 48, r48 = wg % 48, part = r48 / 6, mc = r48 % 6;
  int b = bh >> 4;
  int t = threadIdx.x, wv = t >> 6, lane = t & 63, hg = lane >> 4, li = lane & 15;
  u32 w0 = *(const u32*)mask;
  int mode = (w0 == 0x01010101u) ? 0 : ((w0 == 0x3F800000u) ? 2 : 1);
  float bm = -1e30f;
  for (int i = 0; i < 8; ++i) bm = fmaxf(bm, dout[BMAX + t + 256 * i]);
  sred[t] = bm; __syncthreads();
  for (int s = 128; s > 0; s >>= 1){
    if (t < s) sred[t] = fmaxf(sred[t], sred[t + s]);
    __syncthreads();
  }
  float kmax = sred[0];
  for (int idx = t; idx < 16*72; idx += 256){
    int r = idx / 72, c = idx % 72;
    sVH[(64 + r)*72 + c] = (r == 0) ? (u16)0x3F80 : (u16)0;
  }
  const u16* PH = (const u16*)(dout + PSPH);
  const u16* PL = (const u16*)(dout + PSPL);
  f32x4 acc[4];
  #pragma unroll
  for (int j=0;j<4;++j){ f32x4 z = {0.f,0.f,0.f,0.f}; acc[j] = z; }
  for (int s8 = 0; s8 < 8; ++s8){
    int l0 = part*512 + s8*64;
    __syncthreads();
    const float4* vs4 = (const float4*)(vv + ((size_t)bh*Lc + l0)*Dc);
    #pragma unroll
    for (int p=0;p<4;++p){
      int idx = p*256 + t, row = idx >> 4, c4 = idx & 15;
      float4 u = vs4[idx];
      float kf = mget(mask, mode, b*Lc + l0 + row) ? 1.f : 0.f;
      int rs = row ^ ((c4&3)<<3);
      #pragma unroll
      for (int ii=0;ii<4;++ii){
        int d = c4*4 + ii;
        sVH[d*72 + rs] = f2b((&u.x)[ii] * kf);
      }
    }
    const float* krow = kk + ((size_t)bh*Lc + l0 + wv*16 + li)*Dc;
    float4 qa = *(const float4*)(krow + hg*8);
    float4 qb = *(const float4*)(krow + hg*8 + 4);
    float4 qc = *(const float4*)(krow + 32 + hg*8);
    float4 qd = *(const float4*)(krow + 32 + hg*8 + 4);
    qa.x*=NORM; qa.y*=NORM; qa.z*=NORM; qa.w*=NORM;
    qb.x*=NORM; qb.y*=NORM; qb.z*=NORM; qb.w*=NORM;
    qc.x*=NORM; qc.y*=NORM; qc.z*=NORM; qc.w*=NORM;
    qd.x*=NORM; qd.y*=NORM; qd.z*=NORM; qd.w*=NORM;
    float ssl = qa.x*qa.x+qa.y*qa.y+qa.z*qa.z+qa.w*qa.w
              + qb.x*qb.x+qb.y*qb.y+qb.z*qb.z+qb.w*qb.w
              + qc.x*qc.x+qc.y*qc.y+qc.z*qc.z+qc.w*qc.w
              + qd.x*qd.x+qd.y*qd.y+qd.z*qd.z+qd.w*qd.w;
    ssl += __shfl_xor(ssl, 16); ssl += __shfl_xor(ssl, 32);
    float dg = ssl * 0.5f;
    bf16x8 kh0,kl0,kh1,kl1;
    mkfrag(qa,qb,kh0,kl0); mkfrag(qc,qd,kh1,kl1);
    #pragma unroll
    for (int mf3 = 0; mf3 < 3; ++mf3){
      int mf = mc*3 + mf3;
      int f0 = ((mf*8 + hg)*16 + li)*8, f1 = ((mf*8 + 4 + hg)*16 + li)*8;
      bf16x8 ph0 = ldb(PH + f0), ph1 = ldb(PH + f1);
      bf16x8 pl0 = ldb(PL + f0), pl1 = ldb(PL + f1);
      f32x4 x = {0.f,0.f,0.f,0.f};
      x = mfma16(ph0, kh0, x); x = mfma16(ph1, kh1, x);
      x = mfma16(ph0, kl0, x); x = mfma16(ph1, kl1, x);
      x = mfma16(pl0, kh0, x); x = mfma16(pl1, kh1, x);
      #pragma unroll
      for (int i=0;i<4;++i){
        int m = mf*16 + hg*4 + i;
        float kp = 0.f;
        if (m < Mc){
          float arg = fminf(x[i] - dg - kmax, 8.f);
          kp = __expf(arg) + EPSc;
        }
        int rr = mf3*16 + hg*4 + i;
        sKH[rr*72 + wv*16 + li] = f2b(kp);
      }
    }
    __syncthreads();
    #pragma unroll
    for (int j = 0; j < 4; ++j){
      int p = wv + 4*j;
      if (p < 15){
        int mfl = p / 5, df = p % 5;
        const u16* ar = sKH + (mfl*16 + li)*72 + hg*8;
        bf16x8 ah0 = ldb(ar), ah1 = ldb(ar + 32);
        int d = df*16 + li, sw = (d>>2)&3;
        const u16* br = sVH + d*72 + ((hg^sw)<<3);
        bf16x8 bh0 = ldb(br), bh1 = ldb(br + 32);
        f32x4 a = acc[j];
        a = mfma16(ah0, bh0, a); a = mfma16(ah1, bh1, a);
        acc[j] = a;
      }
    }
  }
  __syncthreads();
  #pragma unroll
  for (int j = 0; j < 4; ++j){
    int p = wv + 4*j;
    if (p < 15){
      int mfl = p / 5, df = p % 5;
      #pragma unroll
      for (int i=0;i<4;++i){
        int mloc = mfl*16 + hg*4 + i;
        if (df < 4) sT[(df*16 + li)*49 + mloc] = acc[j][i];
        else if (li == 0) sT[64*49 + mloc] = acc[j][i];
      }
    }
  }
  __syncthreads();
  size_t pbase = ((size_t)part*32 + bh) * 18720;
  for (int idx = t; idx < 780; idx += 256){
    int row = idx / 12, qq = idx % 12;
    float4 v4;
    v4.x = sT[row*49 + qq*4];     v4.y = sT[row*49 + qq*4 + 1];
    v4.z = sT[row*49 + qq*4 + 2]; v4.w = sT[row*49 + qq*4 + 3];
    *(float4*)(dout + pbase + (size_t)row*288 + mc*48 + qq*4) = v4;
  }
}

// ---------------- kc1: reduce partials -> swizzled bf16 ctx (+ f32 ksum) ----------------
__global__ __launch_bounds__(256) void kc1(float* dout){
  int tid = blockIdx.x * 256 + threadIdx.x;
  int bh = tid / 4680, r4 = tid % 4680;
  int p = r4 * 4;
  int d = p / 288, m = p % 288;
  int which = (bh < 16) ? 0 : 2, h = bh & 15;
  if (d == 64){
    f32x4 s = {0.f,0.f,0.f,0.f};
    for (int p8 = 0; p8 < 8; ++p8)
      s += *(const f32x4*)(dout + ((size_t)p8 * 32 + bh) * 18720 + p);
    *(f32x4*)(dout + sc_fidx(which, h, p)) = s;
    return;
  }
  f32x4 s = {0.f,0.f,0.f,0.f};
  if (m < 272){
    for (int p8 = 0; p8 < 8; ++p8)
      s += *(const f32x4*)(dout + ((size_t)p8 * 32 + bh) * 18720 + p);
  }
  int c = m/96, r = m%96, ks = r>>5, hgs = (r&31)>>3, e = m&7;
  int df = d>>4, li = d&15;
  int i2 = ((((c*3+ks)*4+df)*4+hgs)*16+li)*8 + e;
  int jH = i2 >> 1;
  u16 h0=f2b(s[0]), h1=f2b(s[1]), h2=f2b(s[2]), h3=f2b(s[3]);
  u16 l0=f2b(s[0]-b2f(h0)), l1=f2b(s[1]-b2f(h1)), l2=f2b(s[2]-b2f(h2)), l3=f2b(s[3]-b2f(h3));
  uint2 H; H.x = (u32)h0 | ((u32)h1<<16); H.y = (u32)h2 | ((u32)h3<<16);
  uint2 L; L.x = (u32)l0 | ((u32)l1<<16); L.y = (u32)l2 | ((u32)l3<<16);
  *(uint2*)(dout + sc_fidx(which, h, jH)) = H;
  *(uint2*)(dout + sc_fidx(which, h, 9216 + jH)) = L;
}

// ---------------- kc2: copy ctx-b1 staging -> b0 tops (bit copy) ----------------
__global__ __launch_bounds__(256) void kc2(float* dout){
  int tid = blockIdx.x * 256 + threadIdx.x;
  if (tid >= 74880) return;
  int h = tid / 4680, j = (tid % 4680) * 4;
  f32x4 v = *(const f32x4*)(dout + sc_fidx(2, h, j));
  *(f32x4*)(dout + sc_fidx(1, h, j)) = v;
}

// ---------------- MFMA tile engine v2: LDS-staged P chunks + ctx chunks, bf16 qp ----------------
DEV void tile_mfma(const float* q, const float* dof,
                   int bh, int l0, int t,
                   unsigned char* sm, const float* sks, float* sden,
                   f32x4 (&acc3)[4]){
  int wv = t >> 6, lane = t & 63, hg = lane >> 4, li = lane & 15;
  const uint4* PHg = (const uint4*)((const u16*)(dof + PSPH));
  const uint4* PLg = (const uint4*)((const u16*)(dof + PSPL));
  u16* sP  = (u16*)sm;                    // pass1: PH chunk[6144] + PL chunk[6144] = 24,576 B
  u16* sQh = (u16*)sm;                    // pass2: qp hi [64][104] = 13,312 B
  float* sCh = (float*)(sm + 13312);      // pass2: ctx hi chunk [3072] f32-slots
  float* sCl = (float*)(sm + 13312 + 12288);
  const float* qrow = q + ((size_t)bh * Lc + l0 + wv*16 + li) * Dc;
  float4 qa = *(const float4*)(qrow + hg*8);
  float4 qb = *(const float4*)(qrow + hg*8 + 4);
  float4 qc = *(const float4*)(qrow + 32 + hg*8);
  float4 qd = *(const float4*)(qrow + 32 + hg*8 + 4);
  qa.x*=NORM; qa.y*=NORM; qa.z*=NORM; qa.w*=NORM;
  qb.x*=NORM; qb.y*=NORM; qb.z*=NORM; qb.w*=NORM;
  qc.x*=NORM; qc.y*=NORM; qc.z*=NORM; qc.w*=NORM;
  qd.x*=NORM; qd.y*=NORM; qd.z*=NORM; qd.w*=NORM;
  float ssl = qa.x*qa.x+qa.y*qa.y+qa.z*qa.z+qa.w*qa.w
            + qb.x*qb.x+qb.y*qb.y+qb.z*qb.z+qb.w*qb.w
            + qc.x*qc.x+qc.y*qc.y+qc.z*qc.z+qc.w*qc.w
            + qd.x*qd.x+qd.y*qd.y+qd.z*qd.z+qd.w*qd.w;
  ssl += __shfl_xor(ssl, 16); ssl += __shfl_xor(ssl, 32);
  float dg = ssl * 0.5f;
  bf16x8 qh0,ql0,qh1,ql1;
  mkfrag(qa,qb,qh0,ql0); mkfrag(qc,qd,qh1,ql1);
  // pass 1: dd via LDS-staged P chunks
  f32x4 dd[18];
  for (int c=0;c<3;++c){
    __syncthreads();
    #pragma unroll
    for (int i=0;i<3;++i){
      int idx = i*256 + t;
      ((uint4*)sP)[idx]          = PHg[c*768 + idx];
      ((uint4*)(sP + 6144))[idx] = PLg[c*768 + idx];
    }
    __syncthreads();
    #pragma unroll
    for (int lf=0; lf<6; ++lf){
      int b0 = ((lf*8 + hg)*16 + li)*8, b1 = ((lf*8 + 4 + hg)*16 + li)*8;
      bf16x8 ph0 = ldb(sP + b0), ph1 = ldb(sP + b1);
      bf16x8 pl0 = ldb(sP + 6144 + b0), pl1 = ldb(sP + 6144 + b1);
      f32x4 x = {0.f,0.f,0.f,0.f};
      x = mfma16(ph0, qh0, x); x = mfma16(ph1, qh1, x);
      x = mfma16(ph0, ql0, x); x = mfma16(ph1, ql1, x);
      x = mfma16(pl0, qh0, x); x = mfma16(pl1, qh1, x);
      dd[c*6+lf] = x;
    }
  }
  float rm = -1e30f;
  #pragma unroll
  for (int mf=0; mf<18; ++mf)
    #pragma unroll
    for (int i=0;i<4;++i){
      int m = mf*16 + hg*4 + i;
      if (m < Mc) rm = fmaxf(rm, dd[mf][i]);
    }
  rm = fmaxf(rm, __shfl_xor(rm, 16));
  rm = fmaxf(rm, __shfl_xor(rm, 32));
  // pass 2: qp (bf16 hi) + out-GEMM with LDS-staged ctx chunks
  float den = 0.f;
  #pragma unroll
  for (int df=0; df<4; ++df){ f32x4 z = {0.f,0.f,0.f,0.f}; acc3[df] = z; }
  for (int c=0; c<3; ++c){
    __syncthreads();
    #pragma unroll
    for (int i=0;i<3;++i){
      int idx = i*256 + t;          // 768 f32x4 units
      int j = idx*4;
      *(f32x4*)(sCh + j) = *(const f32x4*)(dof + ctx_fidx(bh, c*3072 + j));
      *(f32x4*)(sCl + j) = *(const f32x4*)(dof + ctx_fidx(bh, 9216 + c*3072 + j));
    }
    #pragma unroll
    for (int mf6=0; mf6<6; ++mf6){
      int mf = c*6 + mf6;
      #pragma unroll
      for (int i=0;i<4;++i){
        int m = mf*16 + hg*4 + i;
        float qp = 0.f;
        if (m < Mc){
          float arg = fminf(dd[mf][i] - dg - rm, 8.f);
          qp = __expf(arg) + EPSc;
          den += qp * sks[m];
        }
        sQh[(wv*16+li)*104 + mf6*16 + hg*4 + i] = f2b(qp);
      }
    }
    __syncthreads();
    #pragma unroll
    for (int ks=0; ks<3; ++ks){
      bf16x8 A = ldb(sQh + (wv*16+li)*104 + ks*32 + hg*8);
      #pragma unroll
      for (int df=0; df<4; ++df){
        int jl = ((ks*4+df)*4+hg)*64 + li*4;
        bf16x8 chv = ldb((const u16*)(sCh + jl));
        bf16x8 clv = ldb((const u16*)(sCl + jl));
        acc3[df] = mfma16(A, chv, acc3[df]);
        acc3[df] = mfma16(A, clv, acc3[df]);
      }
    }
  }
  den += __shfl_xor(den, 16);
  den += __shfl_xor(den, 32);
  if (hg == 0) sden[wv*16 + li] = den;
  __syncthreads();
  #pragma unroll
  for (int i=0;i<4;++i){
    float dv = sden[wv*16 + hg*4 + i];
    float di = (dv > 1e-30f) ? 1.f/dv : -1.f;
    #pragma unroll
    for (int df=0; df<4; ++df){
      float o = (di > 0.f) ? acc3[df][i]*di : 3.0f;
      if (!(o == o && fabsf(o) < 1e30f)) o = 9.0f;
      acc3[df][i] = o;
    }
  }
}

// ---------------- kd: all 1728 non-tail tiles ----------------
__global__ __launch_bounds__(256) void kd(const float* q, float* dout){
  __shared__ __align__(16) unsigned char sm[37888];
  __shared__ float sks[288];
  __shared__ float sden[64];
  int wg = blockIdx.x, bh = wg / 54, lt = wg % 54;
  int t = threadIdx.x, wv = t >> 6, lane = t & 63, hg = lane >> 4, li = lane & 15;
  if (t < 72) *(f32x4*)(sks + t*4) = *(const f32x4*)(dout + ctx_fidx(bh, 18432 + t*4));
  f32x4 acc3[4];
  tile_mfma(q, dout, bh, lt*64, t, sm, sks, sden, acc3);
  int b = bh >> 4, hh = bh & 15;
  #pragma unroll
  for (int df=0; df<4; ++df)
    #pragma unroll
    for (int i=0;i<4;++i)
      dout[((size_t)b*Lc + lt*64 + wv*16 + hg*4 + i)*1024 + hh*64 + df*16 + li] = acc3[df][i];
}

// ---------------- kf_b1: b1 tail tiles -> bf16 temp ----------------
__global__ __launch_bounds__(256) void kf_b1(const float* q, float* dout){
  __shared__ __align__(16) unsigned char sm[37888];
  __shared__ float sks[288];
  __shared__ float sden[64];
  int wg = blockIdx.x, h = wg / 10, ti = wg % 10, bh = 16 + h;
  int t = threadIdx.x, wv = t >> 6, lane = t & 63, hg = lane >> 4, li = lane & 15;
  if (t < 72) *(f32x4*)(sks + t*4) = *(const f32x4*)(dout + ctx_fidx(bh, 18432 + t*4));
  f32x4 acc3[4];
  tile_mfma(q, dout, bh, (54 + ti)*64, t, sm, sks, sden, acc3);
  u32* tempu = (u32*)dout;
  #pragma unroll
  for (int df=0; df<4; ++df)
    #pragma unroll
    for (int i2=0; i2<2; ++i2){
      int p = wv*8 + hg*2 + i2;
      u32 u = (u32)f2b(acc3[df][i2*2]) | ((u32)f2b(acc3[df][i2*2+1]) << 16);
      tempu[B1 + (size_t)(3488 + ti*64 + p)*1024 + h*64 + df*16 + li] = u;
    }
}

// ---------------- kf_b0: b0 tail tiles -> final ----------------
__global__ __launch_bounds__(256) void kf_b0(const float* q, float* dout){
  __shared__ __align__(16) unsigned char sm[37888];
  __shared__ float sks[288];
  __shared__ float sden[64];
  int wg = blockIdx.x, h = wg / 10, ti = wg % 10, bh = h;
  int t = threadIdx.x, wv = t >> 6, lane = t & 63, hg = lane >> 4, li = lane & 15;
  if (t < 72) *(f32x4*)(sks + t*4) = *(const f32x4*)(dout + ctx_fidx(bh, 18432 + t*4));
  f32x4 acc3[4];
  tile_mfma(q, dout, bh, (54 + ti)*64, t, sm, sks, sden, acc3);
  #pragma unroll
  for (int df=0; df<4; ++df)
    #pragma unroll
    for (int i=0;i<4;++i)
      dout[((size_t)(3456 + ti*64 + wv*16 + hg*4 + i))*1024 + h*64 + df*16 + li] = acc3[df][i];
}

// ---------------- kg: per-tile temp -> final ----------------
__global__ __launch_bounds__(256) void kg(float* dout){
  int wg = blockIdx.x, h = wg / 10, ti = wg % 10;
  int t = threadIdx.x;
  const u32* tempu = (const u32*)dout;
  u32 st[8];
  #pragma unroll
  for (int i=0;i<8;++i){
    int idx = t + 256*i;
    st[i] = tempu[B1 + (size_t)(3488 + ti*64 + (idx>>6))*1024 + h*64 + (idx & 63)];
  }
  __syncthreads();
  #pragma unroll
  for (int i=0;i<8;++i){
    int idx = t + 256*i, p = idx >> 6, dcol = idx & 63;
    dout[B1 + (size_t)(3456 + ti*64 + 2*p)*1024 + h*64 + dcol]     = b2f((u16)(st[i] & 0xFFFF));
    dout[B1 + (size_t)(3456 + ti*64 + 2*p + 1)*1024 + h*64 + dcol] = b2f((u16)(st[i] >> 16));
  }
}

extern "C" void kernel_launch(void* const* d_in, const int* in_sizes, int n_in,
                              void* d_out, int out_size, void* d_ws, size_t ws_size,
                              hipStream_t stream){
  const float* q    = (const float*)d_in[0];
  const float* kk   = (const float*)d_in[1];
  const float* vv   = (const float*)d_in[2];
  const void*  mask = d_in[3];
  const float* P    = (const float*)d_in[4];
  float* dout = (float*)d_out;
  hipLaunchKernelGGL(kp0,   dim3(72),   dim3(256), 0, stream, P, dout);
  hipLaunchKernelGGL(ka,    dim3(2048), dim3(256), 0, stream, kk, dout);
  hipLaunchKernelGGL(kb,    dim3(1536), dim3(256), 0, stream, kk, vv, mask, dout);
  hipLaunchKernelGGL(kc1,   dim3(585),  dim3(256), 0, stream, dout);
  hipLaunchKernelGGL(kc2,   dim3(293),  dim3(256), 0, stream, dout);
  hipLaunchKernelGGL(kd,    dim3(1728), dim3(256), 0, stream, q, dout);
  hipLaunchKernelGGL(kf_b1, dim3(160),  dim3(256), 0, stream, q, dout);
  hipLaunchKernelGGL(kf_b0, dim3(160),  dim3(256), 0, stream, q, dout);
  hipLaunchKernelGGL(kg,    dim3(160),  dim3(256), 0, stream, dout);
}

// Round 17
// 186.764 us; speedup vs baseline: 9.5974x; 1.0511x over previous
//
#include <hip/hip_runtime.h>
#include <cstdint>

#define DEV static __device__ __forceinline__

typedef float f32x4 __attribute__((ext_vector_type(4)));
typedef __bf16 bf16x8 __attribute__((ext_vector_type(8)));
typedef unsigned short u16;
typedef unsigned int u32;

constexpr int Lc = 4096, Dc = 64, Mc = 266;
constexpr float NORM = 0.35355339059327373f;   // 64^-0.25
constexpr float EPSc = 1e-4f;

// ---- scratch DAG layout (all in d_out; d_ws unused) ----
constexpr size_t B1   = 4194304;
constexpr size_t PSPH = B1 + 4037ull*1024;
constexpr size_t PSPL = PSPH + 9216;
constexpr size_t BMAX = B1 + 4056ull*1024;

DEV size_t sc_fidx(int which, int h, int j){
  int tri = j >> 6, ti = tri >> 5, r = tri & 31, c = j & 63;
  size_t row = 3456 + (size_t)ti*64 + r + ((which == 2) ? 32 : 0);
  size_t base = (which == 1) ? 0 : B1;
  return base + row*1024 + (size_t)h*64 + c;
}
DEV size_t ctx_fidx(int bh, int j){ return sc_fidx(bh < 16 ? 0 : 1, bh & 15, j); }

DEV bool mget(const void* mp, int mode, int idx){
  if (mode == 0) return ((const unsigned char*)mp)[idx] != 0;
  if (mode == 1) return ((const int*)mp)[idx] != 0;
  return ((const float*)mp)[idx] != 0.f;
}
DEV u16 f2b(float f){ u32 u = __float_as_uint(f); return (u16)((u + 0x7FFFu + ((u>>16)&1u)) >> 16); }
DEV float b2f(u16 h){ return __uint_as_float(((u32)h) << 16); }
DEV f32x4 mfma16(bf16x8 a, bf16x8 b, f32x4 c){ return __builtin_amdgcn_mfma_f32_16x16x32_bf16(a, b, c, 0, 0, 0); }
DEV void mkfrag(float4 a, float4 b, bf16x8& fh, bf16x8& fl){
  union { u16 u[8]; bf16x8 v; } H, L;
  float x[8] = {a.x,a.y,a.z,a.w,b.x,b.y,b.z,b.w};
  #pragma unroll
  for (int j=0;j<8;++j){ u16 h = f2b(x[j]); H.u[j] = h; L.u[j] = f2b(x[j] - b2f(h)); }
  fh = H.v; fl = L.v;
}
DEV bf16x8 ldb(const u16* p){ return *(const bf16x8*)p; }

// ---------------- kp0: P hi/lo split table, fragment-swizzled ----------------
__global__ __launch_bounds__(256) void kp0(const float* P, float* dout){
  int idx = blockIdx.x * 256 + threadIdx.x;
  if (idx >= 288 * 64) return;
  int m = idx >> 6, d = idx & 63;
  float v = (m < Mc) ? P[idx] : 0.f;
  u16 h = f2b(v);
  int i2 = (((m>>4)*8 + (d>>3))*16 + (m&15))*8 + (d&7);
  ((u16*)(dout + PSPH))[i2] = h;
  ((u16*)(dout + PSPL))[i2] = f2b(v - b2f(h));
}

// ---------------- ka: per-block max of dd_k (LDS-staged P chunks) ----------------
__global__ __launch_bounds__(256) void ka(const float* kk, float* dout){
  __shared__ __align__(16) u16 sP[12288];   // PH chunk [6144] + PL chunk [6144]
  __shared__ float sred[4];
  int wg = blockIdx.x, bh = wg >> 6, l0 = (wg & 63) << 6, t = threadIdx.x;
  int wv = t >> 6, lane = t & 63, hg = lane >> 4, li = lane & 15;
  const uint4* PHg = (const uint4*)((const u16*)(dout + PSPH));
  const uint4* PLg = (const uint4*)((const u16*)(dout + PSPL));
  const float* krow = kk + ((size_t)bh * Lc + l0 + wv*16 + li) * Dc;
  float4 qa = *(const float4*)(krow + hg*8);
  float4 qb = *(const float4*)(krow + hg*8 + 4);
  float4 qc = *(const float4*)(krow + 32 + hg*8);
  float4 qd = *(const float4*)(krow + 32 + hg*8 + 4);
  qa.x*=NORM; qa.y*=NORM; qa.z*=NORM; qa.w*=NORM;
  qb.x*=NORM; qb.y*=NORM; qb.z*=NORM; qb.w*=NORM;
  qc.x*=NORM; qc.y*=NORM; qc.z*=NORM; qc.w*=NORM;
  qd.x*=NORM; qd.y*=NORM; qd.z*=NORM; qd.w*=NORM;
  bf16x8 qh0,ql0,qh1,ql1;
  mkfrag(qa,qb,qh0,ql0); mkfrag(qc,qd,qh1,ql1);
  float vmax = -1e30f;
  for (int c=0;c<3;++c){
    __syncthreads();
    #pragma unroll
    for (int i=0;i<3;++i){
      int idx = i*256 + t;
      ((uint4*)sP)[idx]          = PHg[c*768 + idx];
      ((uint4*)(sP + 6144))[idx] = PLg[c*768 + idx];
    }
    __syncthreads();
    #pragma unroll
    for (int lf=0; lf<6; ++lf){
      int b0 = ((lf*8 + hg)*16 + li)*8, b1 = ((lf*8 + 4 + hg)*16 + li)*8;
      bf16x8 ph0 = ldb(sP + b0), ph1 = ldb(sP + b1);
      bf16x8 pl0 = ldb(sP + 6144 + b0), pl1 = ldb(sP + 6144 + b1);
      f32x4 x = {0.f,0.f,0.f,0.f};
      x = mfma16(ph0, qh0, x); x = mfma16(ph1, qh1, x);
      x = mfma16(ph0, ql0, x); x = mfma16(ph1, ql1, x);
      x = mfma16(pl0, qh0, x); x = mfma16(pl1, qh1, x);
      #pragma unroll
      for (int i=0;i<4;++i){
        int m = (c*6 + lf)*16 + hg*4 + i;
        if (m < Mc) vmax = fmaxf(vmax, x[i]);
      }
    }
  }
  vmax = fmaxf(vmax, __shfl_xor(vmax, 1));
  vmax = fmaxf(vmax, __shfl_xor(vmax, 2));
  vmax = fmaxf(vmax, __shfl_xor(vmax, 4));
  vmax = fmaxf(vmax, __shfl_xor(vmax, 8));
  vmax = fmaxf(vmax, __shfl_xor(vmax, 16));
  vmax = fmaxf(vmax, __shfl_xor(vmax, 32));
  if (lane == 0) sred[wv] = vmax;
  __syncthreads();
  if (t == 0) dout[BMAX + wg] = fmaxf(fmaxf(sred[0],sred[1]), fmaxf(sred[2],sred[3]));
}

// ---------------- kb v5: mc-major block order (XCD-local k/v sharing) ----------------
__global__ __launch_bounds__(256) void kb(const float* kk, const float* vv, const void* mask,
                                          float* dout){
  __shared__ __align__(16) unsigned char smem[18432];
  __shared__ float sred[256];
  u16* sKH = (u16*)smem;
  u16* sVH = (u16*)(smem + 6912);
  float* sT = (float*)smem;
  int wg = blockIdx.x;                  // 1536 = 6 mc (MAJOR) x 256 groups
  int mc = wg >> 8;                     // slowest-varying -> siblings of a group are
  int g  = wg & 255;                    //   blockIdx = g mod 256 === g mod 8 -> same XCD
  int bh = g >> 3, part = g & 7;
  int b = bh >> 4;
  int t = threadIdx.x, wv = t >> 6, lane = t & 63, hg = lane >> 4, li = lane & 15;
  u32 w0 = *(const u32*)mask;
  int mode = (w0 == 0x01010101u) ? 0 : ((w0 == 0x3F800000u) ? 2 : 1);
  float bm = -1e30f;
  for (int i = 0; i < 8; ++i) bm = fmaxf(bm, dout[BMAX + t + 256 * i]);
  sred[t] = bm; __syncthreads();
  for (int s = 128; s > 0; s >>= 1){
    if (t < s) sred[t] = fmaxf(sred[t], sred[t + s]);
    __syncthreads();
  }
  float kmax = sred[0];
  for (int idx = t; idx < 16*72; idx += 256){
    int r = idx / 72, c = idx % 72;
    sVH[(64 + r)*72 + c] = (r == 0) ? (u16)0x3F80 : (u16)0;
  }
  const u16* PH = (const u16*)(dout + PSPH);
  const u16* PL = (const u16*)(dout + PSPL);
  f32x4 acc[4];
  #pragma unroll
  for (int j=0;j<4;++j){ f32x4 z = {0.f,0.f,0.f,0.f}; acc[j] = z; }
  for (int s8 = 0; s8 < 8; ++s8){
    int l0 = part*512 + s8*64;
    __syncthreads();
    const float4* vs4 = (const float4*)(vv + ((size_t)bh*Lc + l0)*Dc);
    #pragma unroll
    for (int p=0;p<4;++p){
      int idx = p*256 + t, row = idx >> 4, c4 = idx & 15;
      float4 u = vs4[idx];
      float kf = mget(mask, mode, b*Lc + l0 + row) ? 1.f : 0.f;
      int rs = row ^ ((c4&3)<<3);
      #pragma unroll
      for (int ii=0;ii<4;++ii){
        int d = c4*4 + ii;
        sVH[d*72 + rs] = f2b((&u.x)[ii] * kf);
      }
    }
    const float* krow = kk + ((size_t)bh*Lc + l0 + wv*16 + li)*Dc;
    float4 qa = *(const float4*)(krow + hg*8);
    float4 qb = *(const float4*)(krow + hg*8 + 4);
    float4 qc = *(const float4*)(krow + 32 + hg*8);
    float4 qd = *(const float4*)(krow + 32 + hg*8 + 4);
    qa.x*=NORM; qa.y*=NORM; qa.z*=NORM; qa.w*=NORM;
    qb.x*=NORM; qb.y*=NORM; qb.z*=NORM; qb.w*=NORM;
    qc.x*=NORM; qc.y*=NORM; qc.z*=NORM; qc.w*=NORM;
    qd.x*=NORM; qd.y*=NORM; qd.z*=NORM; qd.w*=NORM;
    float ssl = qa.x*qa.x+qa.y*qa.y+qa.z*qa.z+qa.w*qa.w
              + qb.x*qb.x+qb.y*qb.y+qb.z*qb.z+qb.w*qb.w
              + qc.x*qc.x+qc.y*qc.y+qc.z*qc.z+qc.w*qc.w
              + qd.x*qd.x+qd.y*qd.y+qd.z*qd.z+qd.w*qd.w;
    ssl += __shfl_xor(ssl, 16); ssl += __shfl_xor(ssl, 32);
    float dg = ssl * 0.5f;
    bf16x8 kh0,kl0,kh1,kl1;
    mkfrag(qa,qb,kh0,kl0); mkfrag(qc,qd,kh1,kl1);
    #pragma unroll
    for (int mf3 = 0; mf3 < 3; ++mf3){
      int mf = mc*3 + mf3;
      int f0 = ((mf*8 + hg)*16 + li)*8, f1 = ((mf*8 + 4 + hg)*16 + li)*8;
      bf16x8 ph0 = ldb(PH + f0), ph1 = ldb(PH + f1);
      bf16x8 pl0 = ldb(PL + f0), pl1 = ldb(PL + f1);
      f32x4 x = {0.f,0.f,0.f,0.f};
      x = mfma16(ph0, kh0, x); x = mfma16(ph1, kh1, x);
      x = mfma16(ph0, kl0, x); x = mfma16(ph1, kl1, x);
      x = mfma16(pl0, kh0, x); x = mfma16(pl1, kh1, x);
      #pragma unroll
      for (int i=0;i<4;++i){
        int m = mf*16 + hg*4 + i;
        float kp = 0.f;
        if (m < Mc){
          float arg = fminf(x[i] - dg - kmax, 8.f);
          kp = __expf(arg) + EPSc;
        }
        int rr = mf3*16 + hg*4 + i;
        sKH[rr*72 + wv*16 + li] = f2b(kp);
      }
    }
    __syncthreads();
    #pragma unroll
    for (int j = 0; j < 4; ++j){
      int p = wv + 4*j;
      if (p < 15){
        int mfl = p / 5, df = p % 5;
        const u16* ar = sKH + (mfl*16 + li)*72 + hg*8;
        bf16x8 ah0 = ldb(ar), ah1 = ldb(ar + 32);
        int d = df*16 + li, sw = (d>>2)&3;
        const u16* br = sVH + d*72 + ((hg^sw)<<3);
        bf16x8 bh0 = ldb(br), bh1 = ldb(br + 32);
        f32x4 a = acc[j];
        a = mfma16(ah0, bh0, a); a = mfma16(ah1, bh1, a);
        acc[j] = a;
      }
    }
  }
  __syncthreads();
  #pragma unroll
  for (int j = 0; j < 4; ++j){
    int p = wv + 4*j;
    if (p < 15){
      int mfl = p / 5, df = p % 5;
      #pragma unroll
      for (int i=0;i<4;++i){
        int mloc = mfl*16 + hg*4 + i;
        if (df < 4) sT[(df*16 + li)*49 + mloc] = acc[j][i];
        else if (li == 0) sT[64*49 + mloc] = acc[j][i];
      }
    }
  }
  __syncthreads();
  size_t pbase = ((size_t)part*32 + bh) * 18720;
  for (int idx = t; idx < 780; idx += 256){
    int row = idx / 12, qq = idx % 12;
    float4 v4;
    v4.x = sT[row*49 + qq*4];     v4.y = sT[row*49 + qq*4 + 1];
    v4.z = sT[row*49 + qq*4 + 2]; v4.w = sT[row*49 + qq*4 + 3];
    *(float4*)(dout + pbase + (size_t)row*288 + mc*48 + qq*4) = v4;
  }
}

// ---------------- kc1: reduce partials -> swizzled bf16 ctx (+ f32 ksum) ----------------
__global__ __launch_bounds__(256) void kc1(float* dout){
  int tid = blockIdx.x * 256 + threadIdx.x;
  int bh = tid / 4680, r4 = tid % 4680;
  int p = r4 * 4;
  int d = p / 288, m = p % 288;
  int which = (bh < 16) ? 0 : 2, h = bh & 15;
  if (d == 64){
    f32x4 s = {0.f,0.f,0.f,0.f};
    for (int p8 = 0; p8 < 8; ++p8)
      s += *(const f32x4*)(dout + ((size_t)p8 * 32 + bh) * 18720 + p);
    *(f32x4*)(dout + sc_fidx(which, h, p)) = s;
    return;
  }
  f32x4 s = {0.f,0.f,0.f,0.f};
  if (m < 272){
    for (int p8 = 0; p8 < 8; ++p8)
      s += *(const f32x4*)(dout + ((size_t)p8 * 32 + bh) * 18720 + p);
  }
  int c = m/96, r = m%96, ks = r>>5, hgs = (r&31)>>3, e = m&7;
  int df = d>>4, li = d&15;
  int i2 = ((((c*3+ks)*4+df)*4+hgs)*16+li)*8 + e;
  int jH = i2 >> 1;
  u16 h0=f2b(s[0]), h1=f2b(s[1]), h2=f2b(s[2]), h3=f2b(s[3]);
  u16 l0=f2b(s[0]-b2f(h0)), l1=f2b(s[1]-b2f(h1)), l2=f2b(s[2]-b2f(h2)), l3=f2b(s[3]-b2f(h3));
  uint2 H; H.x = (u32)h0 | ((u32)h1<<16); H.y = (u32)h2 | ((u32)h3<<16);
  uint2 L; L.x = (u32)l0 | ((u32)l1<<16); L.y = (u32)l2 | ((u32)l3<<16);
  *(uint2*)(dout + sc_fidx(which, h, jH)) = H;
  *(uint2*)(dout + sc_fidx(which, h, 9216 + jH)) = L;
}

// ---------------- kc2: copy ctx-b1 staging -> b0 tops (bit copy) ----------------
__global__ __launch_bounds__(256) void kc2(float* dout){
  int tid = blockIdx.x * 256 + threadIdx.x;
  if (tid >= 74880) return;
  int h = tid / 4680, j = (tid % 4680) * 4;
  f32x4 v = *(const f32x4*)(dout + sc_fidx(2, h, j));
  *(f32x4*)(dout + sc_fidx(1, h, j)) = v;
}

// ---------------- MFMA tile engine v2: LDS-staged P chunks + ctx chunks, bf16 qp ----------------
DEV void tile_mfma(const float* q, const float* dof,
                   int bh, int l0, int t,
                   unsigned char* sm, const float* sks, float* sden,
                   f32x4 (&acc3)[4]){
  int wv = t >> 6, lane = t & 63, hg = lane >> 4, li = lane & 15;
  const uint4* PHg = (const uint4*)((const u16*)(dof + PSPH));
  const uint4* PLg = (const uint4*)((const u16*)(dof + PSPL));
  u16* sP  = (u16*)sm;
  u16* sQh = (u16*)sm;
  float* sCh = (float*)(sm + 13312);
  float* sCl = (float*)(sm + 13312 + 12288);
  const float* qrow = q + ((size_t)bh * Lc + l0 + wv*16 + li) * Dc;
  float4 qa = *(const float4*)(qrow + hg*8);
  float4 qb = *(const float4*)(qrow + hg*8 + 4);
  float4 qc = *(const float4*)(qrow + 32 + hg*8);
  float4 qd = *(const float4*)(qrow + 32 + hg*8 + 4);
  qa.x*=NORM; qa.y*=NORM; qa.z*=NORM; qa.w*=NORM;
  qb.x*=NORM; qb.y*=NORM; qb.z*=NORM; qb.w*=NORM;
  qc.x*=NORM; qc.y*=NORM; qc.z*=NORM; qc.w*=NORM;
  qd.x*=NORM; qd.y*=NORM; qd.z*=NORM; qd.w*=NORM;
  float ssl = qa.x*qa.x+qa.y*qa.y+qa.z*qa.z+qa.w*qa.w
            + qb.x*qb.x+qb.y*qb.y+qb.z*qb.z+qb.w*qb.w
            + qc.x*qc.x+qc.y*qc.y+qc.z*qc.z+qc.w*qc.w
            + qd.x*qd.x+qd.y*qd.y+qd.z*qd.z+qd.w*qd.w;
  ssl += __shfl_xor(ssl, 16); ssl += __shfl_xor(ssl, 32);
  float dg = ssl * 0.5f;
  bf16x8 qh0,ql0,qh1,ql1;
  mkfrag(qa,qb,qh0,ql0); mkfrag(qc,qd,qh1,ql1);
  f32x4 dd[18];
  for (int c=0;c<3;++c){
    __syncthreads();
    #pragma unroll
    for (int i=0;i<3;++i){
      int idx = i*256 + t;
      ((uint4*)sP)[idx]          = PHg[c*768 + idx];
      ((uint4*)(sP + 6144))[idx] = PLg[c*768 + idx];
    }
    __syncthreads();
    #pragma unroll
    for (int lf=0; lf<6; ++lf){
      int b0 = ((lf*8 + hg)*16 + li)*8, b1 = ((lf*8 + 4 + hg)*16 + li)*8;
      bf16x8 ph0 = ldb(sP + b0), ph1 = ldb(sP + b1);
      bf16x8 pl0 = ldb(sP + 6144 + b0), pl1 = ldb(sP + 6144 + b1);
      f32x4 x = {0.f,0.f,0.f,0.f};
      x = mfma16(ph0, qh0, x); x = mfma16(ph1, qh1, x);
      x = mfma16(ph0, ql0, x); x = mfma16(ph1, ql1, x);
      x = mfma16(pl0, qh0, x); x = mfma16(pl1, qh1, x);
      dd[c*6+lf] = x;
    }
  }
  float rm = -1e30f;
  #pragma unroll
  for (int mf=0; mf<18; ++mf)
    #pragma unroll
    for (int i=0;i<4;++i){
      int m = mf*16 + hg*4 + i;
      if (m < Mc) rm = fmaxf(rm, dd[mf][i]);
    }
  rm = fmaxf(rm, __shfl_xor(rm, 16));
  rm = fmaxf(rm, __shfl_xor(rm, 32));
  float den = 0.f;
  #pragma unroll
  for (int df=0; df<4; ++df){ f32x4 z = {0.f,0.f,0.f,0.f}; acc3[df] = z; }
  for (int c=0; c<3; ++c){
    __syncthreads();
    #pragma unroll
    for (int i=0;i<3;++i){
      int idx = i*256 + t;
      int j = idx*4;
      *(f32x4*)(sCh + j) = *(const f32x4*)(dof + ctx_fidx(bh, c*3072 + j));
      *(f32x4*)(sCl + j) = *(const f32x4*)(dof + ctx_fidx(bh, 9216 + c*3072 + j));
    }
    #pragma unroll
    for (int mf6=0; mf6<6; ++mf6){
      int mf = c*6 + mf6;
      #pragma unroll
      for (int i=0;i<4;++i){
        int m = mf*16 + hg*4 + i;
        float qp = 0.f;
        if (m < Mc){
          float arg = fminf(dd[mf][i] - dg - rm, 8.f);
          qp = __expf(arg) + EPSc;
          den += qp * sks[m];
        }
        sQh[(wv*16+li)*104 + mf6*16 + hg*4 + i] = f2b(qp);
      }
    }
    __syncthreads();
    #pragma unroll
    for (int ks=0; ks<3; ++ks){
      bf16x8 A = ldb(sQh + (wv*16+li)*104 + ks*32 + hg*8);
      #pragma unroll
      for (int df=0; df<4; ++df){
        int jl = ((ks*4+df)*4+hg)*64 + li*4;
        bf16x8 chv = ldb((const u16*)(sCh + jl));
        bf16x8 clv = ldb((const u16*)(sCl + jl));
        acc3[df] = mfma16(A, chv, acc3[df]);
        acc3[df] = mfma16(A, clv, acc3[df]);
      }
    }
  }
  den += __shfl_xor(den, 16);
  den += __shfl_xor(den, 32);
  if (hg == 0) sden[wv*16 + li] = den;
  __syncthreads();
  #pragma unroll
  for (int i=0;i<4;++i){
    float dv = sden[wv*16 + hg*4 + i];
    float di = (dv > 1e-30f) ? 1.f/dv : -1.f;
    #pragma unroll
    for (int df=0; df<4; ++df){
      float o = (di > 0.f) ? acc3[df][i]*di : 3.0f;
      if (!(o == o && fabsf(o) < 1e30f)) o = 9.0f;
      acc3[df][i] = o;
    }
  }
}

// ---------------- kd: all 1728 non-tail tiles ----------------
__global__ __launch_bounds__(256) void kd(const float* q, float* dout){
  __shared__ __align__(16) unsigned char sm[37888];
  __shared__ float sks[288];
  __shared__ float sden[64];
  int wg = blockIdx.x, bh = wg / 54, lt = wg % 54;
  int t = threadIdx.x, wv = t >> 6, lane = t & 63, hg = lane >> 4, li = lane & 15;
  if (t < 72) *(f32x4*)(sks + t*4) = *(const f32x4*)(dout + ctx_fidx(bh, 18432 + t*4));
  f32x4 acc3[4];
  tile_mfma(q, dout, bh, lt*64, t, sm, sks, sden, acc3);
  int b = bh >> 4, hh = bh & 15;
  #pragma unroll
  for (int df=0; df<4; ++df)
    #pragma unroll
    for (int i=0;i<4;++i)
      dout[((size_t)b*Lc + lt*64 + wv*16 + hg*4 + i)*1024 + hh*64 + df*16 + li] = acc3[df][i];
}

// ---------------- kf_b1: b1 tail tiles -> bf16 temp ----------------
__global__ __launch_bounds__(256) void kf_b1(const float* q, float* dout){
  __shared__ __align__(16) unsigned char sm[37888];
  __shared__ float sks[288];
  __shared__ float sden[64];
  int wg = blockIdx.x, h = wg / 10, ti = wg % 10, bh = 16 + h;
  int t = threadIdx.x, wv = t >> 6, lane = t & 63, hg = lane >> 4, li = lane & 15;
  if (t < 72) *(f32x4*)(sks + t*4) = *(const f32x4*)(dout + ctx_fidx(bh, 18432 + t*4));
  f32x4 acc3[4];
  tile_mfma(q, dout, bh, (54 + ti)*64, t, sm, sks, sden, acc3);
  u32* tempu = (u32*)dout;
  #pragma unroll
  for (int df=0; df<4; ++df)
    #pragma unroll
    for (int i2=0; i2<2; ++i2){
      int p = wv*8 + hg*2 + i2;
      u32 u = (u32)f2b(acc3[df][i2*2]) | ((u32)f2b(acc3[df][i2*2+1]) << 16);
      tempu[B1 + (size_t)(3488 + ti*64 + p)*1024 + h*64 + df*16 + li] = u;
    }
}

// ---------------- kf_b0: b0 tail tiles -> final ----------------
__global__ __launch_bounds__(256) void kf_b0(const float* q, float* dout){
  __shared__ __align__(16) unsigned char sm[37888];
  __shared__ float sks[288];
  __shared__ float sden[64];
  int wg = blockIdx.x, h = wg / 10, ti = wg % 10, bh = h;
  int t = threadIdx.x, wv = t >> 6, lane = t & 63, hg = lane >> 4, li = lane & 15;
  if (t < 72) *(f32x4*)(sks + t*4) = *(const f32x4*)(dout + ctx_fidx(bh, 18432 + t*4));
  f32x4 acc3[4];
  tile_mfma(q, dout, bh, (54 + ti)*64, t, sm, sks, sden, acc3);
  #pragma unroll
  for (int df=0; df<4; ++df)
    #pragma unroll
    for (int i=0;i<4;++i)
      dout[((size_t)(3456 + ti*64 + wv*16 + hg*4 + i))*1024 + h*64 + df*16 + li] = acc3[df][i];
}

// ---------------- kg: per-tile temp -> final ----------------
__global__ __launch_bounds__(256) void kg(float* dout){
  int wg = blockIdx.x, h = wg / 10, ti = wg % 10;
  int t = threadIdx.x;
  const u32* tempu = (const u32*)dout;
  u32 st[8];
  #pragma unroll
  for (int i=0;i<8;++i){
    int idx = t + 256*i;
    st[i] = tempu[B1 + (size_t)(3488 + ti*64 + (idx>>6))*1024 + h*64 + (idx & 63)];
  }
  __syncthreads();
  #pragma unroll
  for (int i=0;i<8;++i){
    int idx = t + 256*i, p = idx >> 6, dcol = idx & 63;
    dout[B1 + (size_t)(3456 + ti*64 + 2*p)*1024 + h*64 + dcol]     = b2f((u16)(st[i] & 0xFFFF));
    dout[B1 + (size_t)(3456 + ti*64 + 2*p + 1)*1024 + h*64 + dcol] = b2f((u16)(st[i] >> 16));
  }
}

extern "C" void kernel_launch(void* const* d_in, const int* in_sizes, int n_in,
                              void* d_out, int out_size, void* d_ws, size_t ws_size,
                              hipStream_t stream){
  const float* q    = (const float*)d_in[0];
  const float* kk   = (const float*)d_in[1];
  const float* vv   = (const float*)d_in[2];
  const void*  mask = d_in[3];
  const float* P    = (const float*)d_in[4];
  float* dout = (float*)d_out;
  hipLaunchKernelGGL(kp0,   dim3(72),   dim3(256), 0, stream, P, dout);
  hipLaunchKernelGGL(ka,    dim3(2048), dim3(256), 0, stream, kk, dout);
  hipLaunchKernelGGL(kb,    dim3(1536), dim3(256), 0, stream, kk, vv, mask, dout);
  hipLaunchKernelGGL(kc1,   dim3(585),  dim3(256), 0, stream, dout);
  hipLaunchKernelGGL(kc2,   dim3(293),  dim3(256), 0, stream, dout);
  hipLaunchKernelGGL(kd,    dim3(1728), dim3(256), 0, stream, q, dout);
  hipLaunchKernelGGL(kf_b1, dim3(160),  dim3(256), 0, stream, q, dout);
  hipLaunchKernelGGL(kf_b0, dim3(160),  dim3(256), 0, stream, q, dout);
  hipLaunchKernelGGL(kg,    dim3(160),  dim3(256), 0, stream, dout);
}